// Round 7
// baseline (4729.455 us; speedup 1.0000x reference)
//
#include <hip/hip_runtime.h>

#define NATOM 10000
#define EG    120000
#define TT    600000

#define INV_SQRT2f 0.7071067811865476f

typedef unsigned short bf16t;
typedef __attribute__((ext_vector_type(8))) short s16x8;
typedef __attribute__((ext_vector_type(8))) unsigned short u16x8;
typedef __attribute__((ext_vector_type(4))) float f32x4;

__device__ __forceinline__ float ssilu(float x) {
    return x * (1.0f / (1.0f + __expf(-x))) * (1.0f / 0.6f);
}
__device__ __forceinline__ float bf2f(unsigned short u) {
    return __uint_as_float(((unsigned)u) << 16);
}
__device__ __forceinline__ unsigned short f2bf(float f) {
    unsigned b = __float_as_uint(f);
    unsigned r = (b + 0x7FFF + ((b >> 16) & 1)) >> 16;  // RNE
    return (unsigned short)r;
}
__device__ __forceinline__ u16x8 cvt8(const float4 va, const float4 vb) {
    u16x8 r{};
    r[0] = f2bf(va.x); r[1] = f2bf(va.y); r[2] = f2bf(va.z); r[3] = f2bf(va.w);
    r[4] = f2bf(vb.x); r[5] = f2bf(vb.y); r[6] = f2bf(vb.z); r[7] = f2bf(vb.w);
    return r;
}

template <typename T> struct VT;
template <> struct VT<float> {
    static __device__ __forceinline__ float4 load4(const float* p) { return *(const float4*)p; }
    static __device__ __forceinline__ void store4(float* p, float4 v) { *(float4*)p = v; }
    static __device__ __forceinline__ float load(const float* p) { return *p; }
    static __device__ __forceinline__ void store(float* p, float v) { *p = v; }
};
template <> struct VT<bf16t> {
    static __device__ __forceinline__ float4 load4(const bf16t* p) {
        ushort4 u = *(const ushort4*)p;
        return make_float4(bf2f(u.x), bf2f(u.y), bf2f(u.z), bf2f(u.w));
    }
    static __device__ __forceinline__ void store4(bf16t* p, float4 v) {
        ushort4 u; u.x = f2bf(v.x); u.y = f2bf(v.y); u.z = f2bf(v.z); u.w = f2bf(v.w);
        *(ushort4*)p = u;
    }
    static __device__ __forceinline__ float load(const bf16t* p) { return bf2f(*p); }
    static __device__ __forceinline__ void store(bf16t* p, float v) { *p = f2bf(v); }
};

// ---------------------------------------------------------------------------
__global__ __launch_bounds__(256) void k_fill(float* __restrict__ o, int n, float v) {
    int i = blockIdx.x * 256 + threadIdx.x;
    if (i < n) o[i] = v;
}

// ---------------------------------------------------------------------------
// sort infrastructure (built once; indices are launch-constant)
// ---------------------------------------------------------------------------
__global__ __launch_bounds__(256) void k_hist(
    const int* __restrict__ idx, int* __restrict__ cnt, int n)
{
    int i = blockIdx.x * 256 + threadIdx.x;
    if (i < n) atomicAdd(&cnt[idx[i]], 1);
}

// single-workgroup chunked exclusive scan: off[0..n-1] exclusive, off[n]=total
__global__ __launch_bounds__(1024) void k_scan(
    const int* __restrict__ cnt, int* __restrict__ off, int n)
{
    __shared__ int wsum[16];
    __shared__ int carrySh;
    if (threadIdx.x == 0) carrySh = 0;
    __syncthreads();
    const int lane = threadIdx.x & 63, wid = threadIdx.x >> 6;
    for (int base = 0; base < n; base += 8192) {
        int v[8]; int s = 0;
        int i0 = base + threadIdx.x * 8;
#pragma unroll
        for (int j = 0; j < 8; j++) { int i = i0 + j; v[j] = (i < n) ? cnt[i] : 0; s += v[j]; }
        int sc = s;
#pragma unroll
        for (int d = 1; d < 64; d <<= 1) { int t = __shfl_up(sc, d); if (lane >= d) sc += t; }
        if (lane == 63) wsum[wid] = sc;
        __syncthreads();
        int wbase = 0;
        for (int w = 0; w < 16; w++) wbase += (w < wid) ? wsum[w] : 0;
        int carry = carrySh;
        int excl = carry + wbase + (sc - s);
#pragma unroll
        for (int j = 0; j < 8; j++) { int i = i0 + j; if (i < n) off[i] = excl; excl += v[j]; }
        __syncthreads();
        if (threadIdx.x == 1023) carrySh = carry + wbase + sc;
        __syncthreads();
    }
    if (threadIdx.x == 0) off[n] = carrySh;
}

__global__ __launch_bounds__(256) void k_rank_trip(
    const int* __restrict__ id3_ca, const int* __restrict__ id3_ba,
    const int* __restrict__ off, int* __restrict__ cnt2,
    int* __restrict__ rank, int* __restrict__ ba_s, int* __restrict__ ca_s, int n)
{
    int t = blockIdx.x * 256 + threadIdx.x;
    if (t >= n) return;
    int ca = id3_ca[t];
    int p = off[ca] + atomicAdd(&cnt2[ca], 1);
    rank[t] = p;
    ba_s[p] = id3_ba[t];
    ca_s[p] = ca;
}

__global__ __launch_bounds__(256) void k_rank_edge(
    const int* __restrict__ idx, const int* __restrict__ off,
    int* __restrict__ cnt2, int* __restrict__ lst, int n)
{
    int i = blockIdx.x * 256 + threadIdx.x;
    if (i >= n) return;
    int a = idx[i];
    int p = off[a] + atomicAdd(&cnt2[a], 1);
    lst[p] = i;
}

// segment sum: out[n][256] = sum of X rows (bf16) whose target == n, via CSR
__global__ __launch_bounds__(256) void k_segsum(
    const bf16t* __restrict__ X, const int* __restrict__ off,
    const int* __restrict__ lst, float* __restrict__ out)
{
    int n = blockIdx.x, j = threadIdx.x;
    int b = off[n], e = off[n + 1];
    float s = 0.f;
    for (int k = b; k < e; k++) s += bf2f(X[(size_t)lst[k] * 256 + j]);
    out[(size_t)n * 256 + j] = s;
}

// ---------------------------------------------------------------------------
// combined weight: Wc[16,256] = Wa[16,16] @ Wb[16,256]
// ---------------------------------------------------------------------------
__global__ __launch_bounds__(256) void k_wcomb(
    const float* __restrict__ Wa, const float* __restrict__ Wb, float* __restrict__ Wc)
{
    __shared__ float sA[256];
    int j = threadIdx.x;
    sA[j] = Wa[j];
    __syncthreads();
#pragma unroll 4
    for (int r = 0; r < 16; r++) {
        float acc = 0.f;
#pragma unroll
        for (int k = 0; k < 16; k++) acc = fmaf(sA[r * 16 + k], Wb[k * 256 + j], acc);
        Wc[r * 256 + j] = acc;
    }
}

// ---------------------------------------------------------------------------
// weight transpose+convert: BT[n][k] (bf16, K padded to KP) from B[k][n] f32
// ---------------------------------------------------------------------------
__global__ __launch_bounds__(256) void k_wt(
    const float* __restrict__ B, bf16t* __restrict__ BT, int K, int KP, int N)
{
    int idx = blockIdx.x * 256 + threadIdx.x;
    if (idx >= N * KP) return;
    int n = idx / KP, k = idx - n * KP;
    BT[idx] = (k < K) ? f2bf(B[(size_t)k * N + n]) : (bf16t)0;
}

// bilinear weight: WT[i][o][c] bf16 from Wb[c][i][o] f32 (c=64,i=16,o=64)
__global__ __launch_bounds__(256) void k_wtb(
    const float* __restrict__ Wb, bf16t* __restrict__ WT)
{
    int idx = blockIdx.x * 256 + threadIdx.x;
    if (idx >= 16 * 64 * 64) return;
    int i = idx >> 12, o = (idx >> 6) & 63, c = idx & 63;
    WT[idx] = f2bf(Wb[((size_t)c * 16 + i) * 64 + o]);
}

// ---------------------------------------------------------------------------
// rbf basis + rbf_W1 (cbf down-projection)
// ---------------------------------------------------------------------------
template <typename T>
__global__ __launch_bounds__(256) void k_rbf(
    const float* __restrict__ D, const float* __restrict__ Wc,
    T* __restrict__ rbf, float* __restrict__ rbfW1)
{
    __shared__ float sW[1792];
    for (int i = threadIdx.x; i < 1792; i += 256) sW[i] = Wc[i];
    __syncthreads();
    int e = blockIdx.x * 256 + threadIdx.x;
    if (e >= EG) return;
    float d = D[e] * (1.0f / 6.0f);
    float d2 = d * d, d4 = d2 * d2, d5 = d4 * d, d6 = d5 * d, d7 = d6 * d;
    float env = 1.0f - 21.0f * d5 + 35.0f * d6 - 15.0f * d7;
    if (d >= 1.0f) env = 0.0f;
    float r[16];
#pragma unroll
    for (int i = 0; i < 16; i++) {
        float t = d - (float)i * (1.0f / 15.0f);
        r[i] = env * __expf(-112.5f * t * t);
    }
#pragma unroll
    for (int j = 0; j < 16; j++) VT<T>::store(rbf + (size_t)e * 16 + j, r[j]);
    for (int s = 0; s < 7; s++) {
#pragma unroll 4
        for (int i = 0; i < 16; i++) {
            float a = 0.f;
#pragma unroll
            for (int k = 0; k < 16; k++)
                a = fmaf(r[k], sW[(s * 16 + k) * 16 + i], a);
            rbfW1[(size_t)e * 112 + s * 16 + i] = a;
        }
    }
}

// ---------------------------------------------------------------------------
// spherical basis + cbf_t; OUTPUT PERMUTED: cbf[rank[t]] = value(t)
// ---------------------------------------------------------------------------
template <typename T>
__global__ __launch_bounds__(256) void k_cbf(
    const float* __restrict__ cosphi, const int* __restrict__ id3_ca,
    const float* __restrict__ rbfW1, const int* __restrict__ rank,
    T* __restrict__ cbf)
{
    int t = blockIdx.x * 256 + threadIdx.x;
    if (t >= TT) return;
    float c = cosphi[t];
    const float norm[7] = {0.28209479177387814f, 0.4886025119029199f, 0.6307831305050401f,
                           0.7463526651802308f, 0.8462843753216345f, 0.935414346693485f,
                           1.0171072362820548f};
    float y[7];
    float pm2 = 1.0f, pm1 = c;
    y[0] = norm[0];
    y[1] = norm[1] * c;
    for (int l = 2; l < 7; l++) {
        float p = ((2.0f * l - 1.0f) * c * pm1 - (l - 1.0f) * pm2) / (float)l;
        y[l] = norm[l] * p;
        pm2 = pm1; pm1 = p;
    }
    int e = id3_ca[t];
    const float* __restrict__ w = rbfW1 + (size_t)e * 112;
    float out[16];
#pragma unroll
    for (int i = 0; i < 16; i++) out[i] = 0.f;
#pragma unroll
    for (int s = 0; s < 7; s++) {
        float ys = y[s];
#pragma unroll
        for (int i = 0; i < 16; i++) out[i] = fmaf(ys, w[s * 16 + i], out[i]);
    }
    int p = rank[t];
#pragma unroll
    for (int i = 0; i < 16; i += 4)
        VT<T>::store4(cbf + (size_t)p * 16 + i, make_float4(out[i], out[i + 1], out[i + 2], out[i + 3]));
}

// ---------------------------------------------------------------------------
__global__ __launch_bounds__(256) void k_hgather(
    const float* __restrict__ emb, const int* __restrict__ Z, bf16t* __restrict__ h)
{
    int i = blockIdx.x * 256 + threadIdx.x;
    if (i < NATOM * 128) {
        int n = i >> 7, j = i & 127;
        h[i] = f2bf(emb[(size_t)Z[n] * 128 + j]);
    }
}

// ---------------------------------------------------------------------------
// mgemm2: barrier-free MFMA GEMM. C[M,N](bf16) = epi(A[M,K] @ BT^T)
// ---------------------------------------------------------------------------
template <typename TA, int FC, int EPI>
__global__ __launch_bounds__(256) void mgemm2(
    const TA* __restrict__ A, const bf16t* __restrict__ BT,
    bf16t* __restrict__ C, const bf16t* __restrict__ skip,
    int M, int N, int K, const int* __restrict__ swp)
{
    const int tid = threadIdx.x, wave = tid >> 6, lane = tid & 63;
    const int rowBase = blockIdx.y * 128, colBase = blockIdx.x * (FC * 16);
    const int kd = (lane >> 4) << 3;
    const int r0 = rowBase + wave * 32 + (lane & 15);
    const int r0c = r0 < M ? r0 : (M - 1);
    const int r1c = (r0 + 16) < M ? (r0 + 16) : (M - 1);
    const int colF = colBase + (lane & 15);

    f32x4 zv = {0.f, 0.f, 0.f, 0.f};
    f32x4 acc[2][FC];
#pragma unroll
    for (int p = 0; p < 2; p++)
#pragma unroll
        for (int q = 0; q < FC; q++) acc[p][q] = zv;

    for (int k0 = 0; k0 < K; k0 += 32) {
        u16x8 a0, a1;
        if constexpr (sizeof(TA) == 2) {
            a0 = *(const u16x8*)((const bf16t*)A + (size_t)r0c * K + k0 + kd);
            a1 = *(const u16x8*)((const bf16t*)A + (size_t)r1c * K + k0 + kd);
        } else {
            const float4* s0 = (const float4*)((const float*)A + (size_t)r0c * K + k0 + kd);
            const float4* s1 = (const float4*)((const float*)A + (size_t)r1c * K + k0 + kd);
            a0 = cvt8(s0[0], s0[1]);
            a1 = cvt8(s1[0], s1[1]);
        }
#pragma unroll
        for (int fc = 0; fc < FC; fc++) {
            u16x8 b = *(const u16x8*)(BT + (size_t)(colF + fc * 16) * K + k0 + kd);
            acc[0][fc] = __builtin_amdgcn_mfma_f32_16x16x32_bf16(
                *(s16x8*)&a0, *(s16x8*)&b, acc[0][fc], 0, 0, 0);
            acc[1][fc] = __builtin_amdgcn_mfma_f32_16x16x32_bf16(
                *(s16x8*)&a1, *(s16x8*)&b, acc[1][fc], 0, 0, 0);
        }
    }

    const int rB = rowBase + wave * 32 + ((lane >> 4) << 2);
#pragma unroll
    for (int fr = 0; fr < 2; fr++) {
#pragma unroll
        for (int r = 0; r < 4; r++) {
            int row = rB + fr * 16 + r;
            if (row >= M) continue;
#pragma unroll
            for (int fc = 0; fc < FC; fc++) {
                int col = colF + fc * 16;
                float v = acc[fr][fc][r];
                if (EPI == 1) {
                    C[(size_t)row * N + col] = f2bf(ssilu(v));
                } else if (EPI == 2) {
                    float sk = bf2f(skip[(size_t)row * N + col]);
                    C[(size_t)row * N + col] = f2bf((sk + ssilu(v)) * INV_SQRT2f);
                } else {
                    int tr = swp[row];
                    bf16t* cp = &C[(size_t)tr * N + col];
                    *cp = f2bf((bf2f(*cp) + ssilu(v)) * INV_SQRT2f);
                }
            }
        }
    }
}

// ---------------------------------------------------------------------------
// MFMA GEMM with concat-gather A: row r = concat(hA[gS[r]],hA[gT[r]],X[r,:w2])
// hA is bf16 now.
// ---------------------------------------------------------------------------
__global__ __launch_bounds__(256) void mgemmA1(
    const bf16t* __restrict__ BT,
    bf16t* __restrict__ C,
    int M, int N, int K, int KP,
    const bf16t* __restrict__ hA, const int* __restrict__ gS,
    const int* __restrict__ gT, const bf16t* __restrict__ X, int w2)
{
    __shared__ __align__(16) ushort As[128][40];
    __shared__ __align__(16) ushort Bs[64][40];
    const int tid = threadIdx.x;
    const int wave = tid >> 6, lane = tid & 63;
    const int rowBase = blockIdx.y * 128, colBase = blockIdx.x * 64;

    const int ar = tid >> 1;
    const int ah = (tid & 1) << 4;
    const int arow = rowBase + ar;
    const int arowC = arow < M ? arow : (M - 1);
    const int ia = gS[arowC], ibx = gT[arowC];

    const int bcol = tid & 63;
    const int bk0 = (tid >> 6) << 3;

    f32x4 zv = {0.f, 0.f, 0.f, 0.f};
    f32x4 acc[2][4];
#pragma unroll
    for (int p = 0; p < 2; p++)
#pragma unroll
        for (int q = 0; q < 4; q++) acc[p][q] = zv;

    const ushort* asBase = &As[0][0];
    const ushort* bsBase = &Bs[0][0];
    const int aoff = (wave * 32 + (lane & 15)) * 40 + ((lane >> 4) << 3);
    const int boff = (lane & 15) * 40 + ((lane >> 4) << 3);

    for (int k0 = 0; k0 < K; k0 += 32) {
        u16x8 a0{}, a1{};
        const int kk = k0 + ah;
        if (kk < 128) {
            const u16x8* s = (const u16x8*)(hA + (size_t)ia * 128 + kk);
            a0 = s[0]; a1 = s[1];
        } else if (kk < 256) {
            const u16x8* s = (const u16x8*)(hA + (size_t)ibx * 128 + (kk - 128));
            a0 = s[0]; a1 = s[1];
        } else if (kk < K && kk - 256 < w2) {
            const u16x8* s = (const u16x8*)(X + (size_t)arowC * w2 + (kk - 256));
            a0 = s[0]; a1 = s[1];
        }
        u16x8 bv = *(const u16x8*)(BT + (size_t)(colBase + bcol) * KP + k0 + bk0);
        __syncthreads();
        *(u16x8*)&As[ar][ah] = a0;
        *(u16x8*)&As[ar][ah + 8] = a1;
        *(u16x8*)&Bs[bcol][bk0] = bv;
        __syncthreads();

        u16x8 af0 = *(const u16x8*)(asBase + aoff);
        u16x8 af1 = *(const u16x8*)(asBase + aoff + 16 * 40);
#pragma unroll
        for (int fc = 0; fc < 4; fc++) {
            u16x8 bf = *(const u16x8*)(bsBase + boff + fc * 16 * 40);
            acc[0][fc] = __builtin_amdgcn_mfma_f32_16x16x32_bf16(
                *(s16x8*)&af0, *(s16x8*)&bf, acc[0][fc], 0, 0, 0);
            acc[1][fc] = __builtin_amdgcn_mfma_f32_16x16x32_bf16(
                *(s16x8*)&af1, *(s16x8*)&bf, acc[1][fc], 0, 0, 0);
        }
    }

    const int rBase = rowBase + wave * 32 + ((lane >> 4) << 2);
    const int cBase = colBase + (lane & 15);
#pragma unroll
    for (int fr = 0; fr < 2; fr++) {
#pragma unroll
        for (int r = 0; r < 4; r++) {
            int row = rBase + fr * 16 + r;
            if (row >= M) continue;
#pragma unroll
            for (int fc = 0; fc < 4; fc++) {
                int col = cBase + fc * 16;
                C[(size_t)row * N + col] = f2bf(ssilu(acc[fr][fc][r]));
            }
        }
    }
}

// ---------------------------------------------------------------------------
// MFMA bilinear v3 (sorted triplets): per block 64 sorted triplets; in-block
// segment reduce in LDS; ~1 atomic per (run,col) instead of per (triplet,col).
// ---------------------------------------------------------------------------
__global__ __launch_bounds__(256) void k_bilinear_m(
    const bf16t* __restrict__ xtrip, const bf16t* __restrict__ cbf,
    const bf16t* __restrict__ WT,
    const int* __restrict__ ba_s, const int* __restrict__ ca_s,
    float* __restrict__ seg)
{
    __shared__ __align__(16) ushort xs[64][72];
    __shared__ ushort cbs[64][16];
    __shared__ int cas[64];
    __shared__ __align__(16) float ts[64][65];
    const int tid = threadIdx.x, wave = tid >> 6, lane = tid & 63;
    const int t0 = blockIdx.x * 64;
    {
        int r = tid >> 2, q = (tid & 3) << 4;
        int ba = ba_s[t0 + r];
        const u16x8* src = (const u16x8*)(xtrip + (size_t)ba * 64 + q);
        *(u16x8*)&xs[r][q] = src[0];
        *(u16x8*)&xs[r][q + 8] = src[1];
    }
    if (tid < 64) cas[tid] = ca_s[t0 + tid];
    {
        int e = tid << 2; int r = e >> 4, c = e & 15;
        *(ushort4*)&cbs[r][c] = *(const ushort4*)(cbf + (size_t)(t0 + r) * 16 + c);
    }
    __syncthreads();
    const int kd = (lane >> 4) << 3;
    u16x8 a0 = *(const u16x8*)(&xs[wave * 16 + (lane & 15)][kd]);
    u16x8 a1 = *(const u16x8*)(&xs[wave * 16 + (lane & 15)][32 + kd]);
    const int rowo = wave * 16 + ((lane >> 4) << 2);

    float tot[4][4];
#pragma unroll
    for (int a = 0; a < 4; a++)
#pragma unroll
        for (int b = 0; b < 4; b++) tot[a][b] = 0.f;

    for (int i = 0; i < 16; i++) {
        f32x4 zv = {0.f, 0.f, 0.f, 0.f};
        f32x4 p[4] = {zv, zv, zv, zv};
        const bf16t* w = WT + ((size_t)i * 64 + (lane & 15)) * 64 + kd;
#pragma unroll
        for (int fc = 0; fc < 4; fc++) {
            u16x8 b0 = *(const u16x8*)(w + fc * 16 * 64);
            u16x8 b1 = *(const u16x8*)(w + fc * 16 * 64 + 32);
            p[fc] = __builtin_amdgcn_mfma_f32_16x16x32_bf16(
                *(s16x8*)&a0, *(s16x8*)&b0, p[fc], 0, 0, 0);
            p[fc] = __builtin_amdgcn_mfma_f32_16x16x32_bf16(
                *(s16x8*)&a1, *(s16x8*)&b1, p[fc], 0, 0, 0);
        }
#pragma unroll
        for (int r = 0; r < 4; r++) {
            float s = bf2f(cbs[rowo + r][i]);
#pragma unroll
            for (int fc = 0; fc < 4; fc++) tot[fc][r] += s * p[fc][r];
        }
    }
    // write per-triplet rows to LDS, then segment-reduce (cas is sorted)
#pragma unroll
    for (int r = 0; r < 4; r++)
#pragma unroll
        for (int fc = 0; fc < 4; fc++)
            ts[rowo + r][fc * 16 + (lane & 15)] = tot[fc][r];
    __syncthreads();
    {
        int q = tid >> 6, c = tid & 63;
        float s = 0.f;
        int cur = cas[q * 16];
#pragma unroll 1
        for (int r = q * 16; r < q * 16 + 16; r++) {
            int ca = cas[r];
            if (ca != cur) {
                atomicAdd(&seg[(size_t)cur * 64 + c], s);
                s = 0.f; cur = ca;
            }
            s += ts[r][c];
        }
        atomicAdd(&seg[(size_t)cur * 64 + c], s);
    }
}

// ---------------------------------------------------------------------------
// f32 VALU GEMM (NATOM-sized output path)
// ---------------------------------------------------------------------------
template <int EPI>
__global__ __launch_bounds__(256) void gemm64(
    const float* __restrict__ A, const float* __restrict__ B,
    float* __restrict__ C, const float* __restrict__ skip,
    int M, int N, int K)
{
    __shared__ __align__(16) float As[16][64];
    __shared__ __align__(16) float Bs[16][64];
    const int tid = threadIdx.x;
    const int tx = tid & 15, ty = tid >> 4;
    const int rowBase = blockIdx.y * 64;
    const int colBase = blockIdx.x * 64;
    const int lr = tid >> 2;
    const int lk = (tid & 3) * 4;
    const int bk = tid >> 4;
    const int bc = (tid & 15) * 4;
    int arow = rowBase + lr;
    int arowC = arow < M ? arow : (M - 1);

    float acc[4][4];
#pragma unroll
    for (int i = 0; i < 4; i++)
#pragma unroll
        for (int j = 0; j < 4; j++) acc[i][j] = 0.f;

    for (int k0 = 0; k0 < K; k0 += 16) {
        float4 a4 = *(const float4*)(A + (size_t)arowC * K + k0 + lk);
        float4 b4 = *(const float4*)(B + (size_t)(k0 + bk) * N + colBase + bc);
        __syncthreads();
        As[lk + 0][lr] = a4.x;
        As[lk + 1][lr] = a4.y;
        As[lk + 2][lr] = a4.z;
        As[lk + 3][lr] = a4.w;
        *(float4*)(&Bs[bk][bc]) = b4;
        __syncthreads();
#pragma unroll
        for (int kk = 0; kk < 16; kk++) {
            float4 av = *(const float4*)(&As[kk][ty * 4]);
            float4 bv = *(const float4*)(&Bs[kk][tx * 4]);
            float a[4] = {av.x, av.y, av.z, av.w};
            float b[4] = {bv.x, bv.y, bv.z, bv.w};
#pragma unroll
            for (int i = 0; i < 4; i++)
#pragma unroll
                for (int j = 0; j < 4; j++)
                    acc[i][j] = fmaf(a[i], b[j], acc[i][j]);
        }
    }
    const int col0 = colBase + tx * 4;
#pragma unroll
    for (int ri = 0; ri < 4; ri++) {
        int row = rowBase + ty * 4 + ri;
        if (row >= M) break;
        float* cp = C + (size_t)row * N + col0;
#pragma unroll
        for (int ci = 0; ci < 4; ci++) {
            float v = acc[ri][ci];
            if (EPI == 1) v = ssilu(v);
            if (EPI == 2) v = (skip[(size_t)row * N + col0 + ci] + ssilu(v)) * INV_SQRT2f;
            cp[ci] = v;
        }
    }
}

// ---------------------------------------------------------------------------
// per-edge multiply by (rbf[e,16] @ Wc[16,256]) -> bf16 row (no atomics)
// ---------------------------------------------------------------------------
__global__ __launch_bounds__(256) void k_mulproj(
    const bf16t* __restrict__ in, const bf16t* __restrict__ rvec,
    const float* __restrict__ Wp, bf16t* __restrict__ out)
{
    int e = blockIdx.x;
    int j = threadIdx.x;
    __shared__ float r16[16];
    if (j < 16) r16[j] = bf2f(rvec[(size_t)e * 16 + j]);
    __syncthreads();
    float p = 0.f;
#pragma unroll
    for (int k = 0; k < 16; k++) p = fmaf(r16[k], Wp[k * 256 + j], p);
    float v = bf2f(in[(size_t)e * 256 + j]) * p;
    out[(size_t)e * 256 + j] = f2bf(v);
}

// ---------------------------------------------------------------------------
// LN(m row) * (rbf[e,16] @ Wc[16,256]) -> bf16 row (no atomics)
// ---------------------------------------------------------------------------
__global__ __launch_bounds__(256) void k_ln_proj(
    const bf16t* __restrict__ m, const float* __restrict__ lnw,
    const float* __restrict__ lnb, const bf16t* __restrict__ rvec,
    const float* __restrict__ Wp, bf16t* __restrict__ out)
{
    int e = blockIdx.x;
    int j = threadIdx.x;
    __shared__ float red[8];
    __shared__ float r16[16];
    if (j < 16) r16[j] = bf2f(rvec[(size_t)e * 16 + j]);
    float v = bf2f(m[(size_t)e * 256 + j]);
    float s = v, s2 = v * v;
#pragma unroll
    for (int off = 32; off > 0; off >>= 1) {
        s += __shfl_xor(s, off);
        s2 += __shfl_xor(s2, off);
    }
    int wid = j >> 6, lane = j & 63;
    if (lane == 0) { red[wid] = s; red[4 + wid] = s2; }
    __syncthreads();
    float tot = red[0] + red[1] + red[2] + red[3];
    float tot2 = red[4] + red[5] + red[6] + red[7];
    float mu = tot * (1.f / 256.f);
    float var = tot2 * (1.f / 256.f) - mu * mu;
    float ln = (v - mu) * rsqrtf(var + 1e-5f) * lnw[j] + lnb[j];
    float p = 0.f;
#pragma unroll
    for (int k = 0; k < 16; k++) p = fmaf(r16[k], Wp[k * 256 + j], p);
    out[(size_t)e * 256 + j] = f2bf(ln * p);
}

// ---------------------------------------------------------------------------
__global__ __launch_bounds__(128) void k_ln_acc(
    const float* __restrict__ x, const float* __restrict__ w,
    const float* __restrict__ b, float* __restrict__ out)
{
    int n = blockIdx.x;
    int j = threadIdx.x;
    __shared__ float red[4];
    float v = x[(size_t)n * 128 + j];
    float s = v, s2 = v * v;
#pragma unroll
    for (int off = 32; off > 0; off >>= 1) {
        s += __shfl_xor(s, off);
        s2 += __shfl_xor(s2, off);
    }
    int wid = j >> 6, lane = j & 63;
    if (lane == 0) { red[wid] = s; red[2 + wid] = s2; }
    __syncthreads();
    float tot = red[0] + red[1];
    float tot2 = red[2] + red[3];
    float mu = tot * (1.f / 128.f);
    float var = tot2 * (1.f / 128.f) - mu * mu;
    out[(size_t)n * 128 + j] += (v - mu) * rsqrtf(var + 1e-5f) * w[j] + b[j];
}

// ---------------------------------------------------------------------------
template <typename T>
__global__ __launch_bounds__(256) void k_addscale(
    const T* __restrict__ a, const T* __restrict__ b, T* __restrict__ y, int n4)
{
    int i = blockIdx.x * 256 + threadIdx.x;
    if (i < n4) {
        float4 av = VT<T>::load4(a + (size_t)i * 4);
        float4 bv = VT<T>::load4(b + (size_t)i * 4);
        VT<T>::store4(y + (size_t)i * 4,
                      make_float4((av.x + bv.x) * INV_SQRT2f, (av.y + bv.y) * INV_SQRT2f,
                                  (av.z + bv.z) * INV_SQRT2f, (av.w + bv.w) * INV_SQRT2f));
    }
}

// h(bf16) = (h + a(f32)) * inv2
__global__ __launch_bounds__(256) void k_addscale_hf(
    bf16t* __restrict__ h, const float* __restrict__ a, int n4)
{
    int i = blockIdx.x * 256 + threadIdx.x;
    if (i < n4) {
        float4 hv = VT<bf16t>::load4(h + (size_t)i * 4);
        float4 av = *(const float4*)(a + (size_t)i * 4);
        VT<bf16t>::store4(h + (size_t)i * 4,
                          make_float4((hv.x + av.x) * INV_SQRT2f, (hv.y + av.y) * INV_SQRT2f,
                                      (hv.z + av.z) * INV_SQRT2f, (hv.w + av.w) * INV_SQRT2f));
    }
}

// ---------------------------------------------------------------------------
typedef bf16t T;
static bool try_run(void* const* d_in, void* d_out, void* d_ws, size_t ws_size, hipStream_t stream)
{
    const float* D            = (const float*)d_in[0];
    const float* cosphi       = (const float*)d_in[1];
    const float* atom_emb     = (const float*)d_in[2];
    const float* W_rbf3       = (const float*)d_in[3];
    const float* W_rbf_h      = (const float*)d_in[4];
    const float* W_rbf_out    = (const float*)d_in[5];
    const float* W_cbf_down   = (const float*)d_in[6];
    const float* W_edge_emb   = (const float*)d_in[7];
    const float* ib_dense_ca  = (const float*)d_in[8];
    const float* ib_trip_dense_ba = (const float*)d_in[9];
    const float* ib_trip_mlp_rbf  = (const float*)d_in[10];
    const float* ib_trip_down     = (const float*)d_in[11];
    const float* ib_trip_bilinear = (const float*)d_in[12];
    const float* ib_trip_up_ca    = (const float*)d_in[13];
    const float* ib_trip_up_ac    = (const float*)d_in[14];
    const float* ib_res_before    = (const float*)d_in[15];
    const float* ib_res_after     = (const float*)d_in[16];
    const float* ib_atom_dense_rbf = (const float*)d_in[17];
    const float* ib_atom_dense1    = (const float*)d_in[18];
    const float* ib_atom_res       = (const float*)d_in[19];
    const float* ib_concat_dense   = (const float*)d_in[20];
    const float* ib_res_m          = (const float*)d_in[21];
    const float* ob_dense_rbf      = (const float*)d_in[22];
    const float* ob_dense1         = (const float*)d_in[23];
    const float* ob_res            = (const float*)d_in[24];
    const float* ln_m_w            = (const float*)d_in[25];
    const float* ln_m_b            = (const float*)d_in[26];
    const float* ln_E_w            = (const float*)d_in[27];
    const float* ln_E_b            = (const float*)d_in[28];
    const int* Z       = (const int*)d_in[29];
    const int* idx_s   = (const int*)d_in[30];
    const int* idx_t   = (const int*)d_in[31];
    const int* id3_ba  = (const int*)d_in[32];
    const int* id3_ca  = (const int*)d_in[33];
    const int* id_swap = (const int*)d_in[34];

    char* base = (char*)d_ws;
    size_t off = 0;
    auto alloc = [&](size_t bytes) -> char* {
        off = (off + 255) & ~(size_t)255;
        char* p = base + off;
        off += bytes;
        return p;
    };
    T* m      = (T*)alloc((size_t)EG * 256 * 2);
    T* B1     = (T*)alloc((size_t)EG * 256 * 2);
    T* B2     = (T*)alloc((size_t)EG * 256 * 2);
    float* rbfW1 = (float*)B1;                 // alias: dead before B1 first written
    int* rank    = (int*)B2;                   // alias: dead before B2 first written
    T* rbf    = (T*)alloc((size_t)EG * 16 * 2);
    T* cbf    = (T*)alloc((size_t)TT * 16 * 2);
    bf16t* h  = (bf16t*)alloc((size_t)NATOM * 128 * 2);
    T* xtrip  = (T*)alloc((size_t)EG * 64 * 2);
    // union: seg64 (bilinear) | segN/At1/At2 (atom/out) | sort counters (setup)
    char* ub  = alloc((size_t)EG * 64 * 4);
    float* seg64 = (float*)ub;
    float* segN  = (float*)ub;
    float* At1   = (float*)(ub + (size_t)NATOM * 256 * 4);
    float* At2   = (float*)(ub + (size_t)NATOM * 256 * 4 + (size_t)NATOM * 128 * 4);
    int* cntT    = (int*)ub;                         // EG ints (setup only)
    int* cnt2T   = (int*)(ub + (size_t)EG * 4);      // EG ints (setup only)
    float* wc_mlp  = (float*)alloc(16 * 256 * 4);
    float* wc_atom = (float*)alloc(16 * 256 * 4);
    float* wc_ob   = (float*)alloc(16 * 256 * 4);
    T* wt   = (T*)alloc((size_t)288 * 256 * 2);
    T* wtb  = (T*)alloc((size_t)16 * 64 * 64 * 2);
    int* off_ca   = (int*)alloc((size_t)(EG + 1) * 4);
    int* off_atom = (int*)alloc((size_t)(NATOM + 1) * 4);
    int* ba_s     = (int*)alloc((size_t)TT * 4);
    int* ca_s     = (int*)alloc((size_t)TT * 4);
    int* csr_edges = (int*)alloc((size_t)EG * 4);
    if (off > ws_size) return false;
    float* out = (float*)d_out;

    auto cw = [&](const float* W, int K, int N) {
        int KP = (K + 31) & ~31;
        k_wt<<<(N * KP + 255) / 256, 256, 0, stream>>>(W, wt, K, KP, N);
        return KP;
    };
    auto m256 = [&](int epi, const T* A, const float* W, T* C, const T* skip, int Kk) {
        cw(W, Kk, 256);
        dim3 grid(2, (EG + 127) / 128);
        if (epi == 1)
            mgemm2<T, 8, 1><<<grid, 256, 0, stream>>>(A, wt, C, skip, EG, 256, Kk, nullptr);
        else
            mgemm2<T, 8, 2><<<grid, 256, 0, stream>>>(A, wt, C, skip, EG, 256, Kk, nullptr);
    };
    auto out_block = [&](int i) {
        k_wcomb<<<1, 256, 0, stream>>>(W_rbf_out, ob_dense_rbf + (size_t)i * 16 * 256, wc_ob);
        k_ln_proj<<<EG, 256, 0, stream>>>(m, ln_m_w + (size_t)i * 256, ln_m_b + (size_t)i * 256,
                                          rbf, wc_ob, B2);
        k_segsum<<<NATOM, 256, 0, stream>>>(B2, off_atom, csr_edges, segN);
        {
            dim3 g(2, (NATOM + 63) / 64);
            gemm64<1><<<g, 256, 0, stream>>>(segN, ob_dense1 + (size_t)i * 256 * 128, At1, nullptr, NATOM, 128, 256);
        }
        for (int r = 0; r < 2; r++) {
            const float* W0 = ob_res + ((size_t)i * 2 + r) * 2 * 128 * 128;
            const float* W1 = W0 + 128 * 128;
            dim3 g(2, (NATOM + 63) / 64);
            gemm64<1><<<g, 256, 0, stream>>>(At1, W0, At2, nullptr, NATOM, 128, 128);
            gemm64<2><<<g, 256, 0, stream>>>(At2, W1, At1, At1, NATOM, 128, 128);
        }
        k_ln_acc<<<NATOM, 128, 0, stream>>>(At1, ln_E_w + (size_t)i * 128, ln_E_b + (size_t)i * 128, out);
    };

    // ---- sort setup (once; indices are launch-constant) ----
    hipMemsetAsync(cntT, 0, (size_t)EG * 4, stream);
    k_hist<<<(TT + 255) / 256, 256, 0, stream>>>(id3_ca, cntT, TT);
    k_scan<<<1, 1024, 0, stream>>>(cntT, off_ca, EG);
    hipMemsetAsync(cnt2T, 0, (size_t)EG * 4, stream);
    k_rank_trip<<<(TT + 255) / 256, 256, 0, stream>>>(id3_ca, id3_ba, off_ca, cnt2T,
                                                      rank, ba_s, ca_s, TT);
    hipMemsetAsync(cntT, 0, (size_t)NATOM * 4, stream);
    k_hist<<<(EG + 255) / 256, 256, 0, stream>>>(idx_t, cntT, EG);
    k_scan<<<1, 1024, 0, stream>>>(cntT, off_atom, NATOM);
    hipMemsetAsync(cnt2T, 0, (size_t)NATOM * 4, stream);
    k_rank_edge<<<(EG + 255) / 256, 256, 0, stream>>>(idx_t, off_atom, cnt2T, csr_edges, EG);

    hipMemsetAsync(out, 0, (size_t)NATOM * 128 * 4, stream);
    k_rbf<T><<<(EG + 255) / 256, 256, 0, stream>>>(D, W_cbf_down, rbf, rbfW1);
    k_cbf<T><<<(TT + 255) / 256, 256, 0, stream>>>(cosphi, id3_ca, rbfW1, rank, cbf);
    k_hgather<<<(NATOM * 128 + 255) / 256, 256, 0, stream>>>(atom_emb, Z, h);
    {
        int KP = cw(W_edge_emb, 272, 256);
        dim3 grid(4, (EG + 127) / 128);
        mgemmA1<<<grid, 256, 0, stream>>>(wt, m, EG, 256, 272, KP, h, idx_s, idx_t, rbf, 16);
    }

    out_block(0);

    for (int i = 0; i < 2; i++) {
        // ---- triplet interaction ----
        m256(1, m, ib_dense_ca + (size_t)i * 256 * 256, B1, nullptr, 256);      // x_ca_skip
        m256(1, m, ib_trip_dense_ba + (size_t)i * 256 * 256, B2, nullptr, 256); // x_ba
        k_wcomb<<<1, 256, 0, stream>>>(W_rbf3, ib_trip_mlp_rbf + (size_t)i * 16 * 256, wc_mlp);
        k_mulproj<<<EG, 256, 0, stream>>>(B2, rbf, wc_mlp, B2);
        {
            cw(ib_trip_down + (size_t)i * 256 * 64, 256, 64);
            dim3 grid(1, (EG + 127) / 128);
            mgemm2<T, 4, 1><<<grid, 256, 0, stream>>>(B2, wt, xtrip, nullptr, EG, 64, 256, nullptr);
        }
        hipMemsetAsync(seg64, 0, (size_t)EG * 64 * 4, stream);
        k_wtb<<<(16 * 64 * 64 + 255) / 256, 256, 0, stream>>>(ib_trip_bilinear + (size_t)i * 64 * 16 * 64, wtb);
        k_bilinear_m<<<TT / 64, 256, 0, stream>>>(xtrip, cbf, wtb, ba_s, ca_s, seg64);
        {
            cw(ib_trip_up_ca + (size_t)i * 64 * 256, 64, 256);
            dim3 grid(2, (EG + 127) / 128);
            mgemm2<float, 8, 1><<<grid, 256, 0, stream>>>(seg64, wt, B2, nullptr, EG, 256, 64, nullptr);
            cw(ib_trip_up_ac + (size_t)i * 64 * 256, 64, 256);
            mgemm2<float, 8, 3><<<grid, 256, 0, stream>>>(seg64, wt, B2, nullptr, EG, 256, 64, id_swap);
        }
        k_addscale<T><<<(EG * 256 / 4 + 255) / 256, 256, 0, stream>>>(B1, B2, B1, EG * 256 / 4);
        // ---- edge update ----
        {
            const float* W0 = ib_res_before + (size_t)i * 2 * 256 * 256;
            const float* W1 = W0 + 256 * 256;
            m256(1, B1, W0, B2, nullptr, 256);
            m256(2, B2, W1, B1, B1, 256);
        }
        k_addscale<T><<<(EG * 256 / 4 + 255) / 256, 256, 0, stream>>>(B1, m, B1, EG * 256 / 4);
        {
            const float* W0 = ib_res_after + (size_t)i * 2 * 256 * 256;
            const float* W1 = W0 + 256 * 256;
            m256(1, B1, W0, B2, nullptr, 256);
            m256(2, B2, W1, B1, B1, 256);
        }
        // ---- atom update ----
        k_wcomb<<<1, 256, 0, stream>>>(W_rbf_h, ib_atom_dense_rbf + (size_t)i * 16 * 256, wc_atom);
        k_mulproj<<<EG, 256, 0, stream>>>(B1, rbf, wc_atom, B2);
        k_segsum<<<NATOM, 256, 0, stream>>>(B2, off_atom, csr_edges, segN);
        {
            dim3 g(2, (NATOM + 63) / 64);
            gemm64<1><<<g, 256, 0, stream>>>(segN, ib_atom_dense1 + (size_t)i * 256 * 128, At1, nullptr, NATOM, 128, 256);
            for (int r = 0; r < 2; r++) {
                const float* W0 = ib_atom_res + ((size_t)i * 2 + r) * 2 * 128 * 128;
                const float* W1 = W0 + 128 * 128;
                gemm64<1><<<g, 256, 0, stream>>>(At1, W0, At2, nullptr, NATOM, 128, 128);
                gemm64<2><<<g, 256, 0, stream>>>(At2, W1, At1, At1, NATOM, 128, 128);
            }
        }
        k_addscale_hf<<<(NATOM * 128 / 4 + 255) / 256, 256, 0, stream>>>(h, At1, NATOM * 128 / 4);
        // ---- edge embedding refresh ----
        {
            int KP = cw(ib_concat_dense + (size_t)i * 512 * 256, 512, 256);
            dim3 grid(4, (EG + 127) / 128);
            mgemmA1<<<grid, 256, 0, stream>>>(wt, B2, EG, 256, 512, KP, h, idx_s, idx_t, B1, 256);
        }
        {
            const float* W0 = ib_res_m + (size_t)i * 2 * 256 * 256;
            const float* W1 = W0 + 256 * 256;
            m256(1, B2, W0, B1, nullptr, 256);
            m256(2, B1, W1, B2, B2, 256);
        }
        k_addscale<T><<<(EG * 256 / 4 + 255) / 256, 256, 0, stream>>>(m, B2, m, EG * 256 / 4);

        out_block(i + 1);
    }
    return true;
}

extern "C" void kernel_launch(void* const* d_in, const int* in_sizes, int n_in,
                              void* d_out, int out_size, void* d_ws, size_t ws_size,
                              hipStream_t stream)
{
    if (try_run(d_in, d_out, d_ws, ws_size, stream)) return;
    float v = 3000.0f + (float)(ws_size >> 20);
    k_fill<<<(NATOM * 128 + 255) / 256, 256, 0, stream>>>((float*)d_out, NATOM * 128, v);
}

// Round 8
// 3213.361 us; speedup vs baseline: 1.4718x; 1.4718x over previous
//
#include <hip/hip_runtime.h>

#define NATOM 10000
#define EG    120000
#define TT    600000

#define INV_SQRT2f 0.7071067811865476f

typedef unsigned short bf16t;
typedef __attribute__((ext_vector_type(8))) short s16x8;
typedef __attribute__((ext_vector_type(8))) unsigned short u16x8;
typedef __attribute__((ext_vector_type(4))) float f32x4;

__device__ __forceinline__ float ssilu(float x) {
    return x * (1.0f / (1.0f + __expf(-x))) * (1.0f / 0.6f);
}
__device__ __forceinline__ float bf2f(unsigned short u) {
    return __uint_as_float(((unsigned)u) << 16);
}
__device__ __forceinline__ unsigned short f2bf(float f) {
    unsigned b = __float_as_uint(f);
    unsigned r = (b + 0x7FFF + ((b >> 16) & 1)) >> 16;  // RNE
    return (unsigned short)r;
}
__device__ __forceinline__ u16x8 cvt8(const float4 va, const float4 vb) {
    u16x8 r{};
    r[0] = f2bf(va.x); r[1] = f2bf(va.y); r[2] = f2bf(va.z); r[3] = f2bf(va.w);
    r[4] = f2bf(vb.x); r[5] = f2bf(vb.y); r[6] = f2bf(vb.z); r[7] = f2bf(vb.w);
    return r;
}

template <typename T> struct VT;
template <> struct VT<float> {
    static __device__ __forceinline__ float4 load4(const float* p) { return *(const float4*)p; }
    static __device__ __forceinline__ void store4(float* p, float4 v) { *(float4*)p = v; }
    static __device__ __forceinline__ float load(const float* p) { return *p; }
    static __device__ __forceinline__ void store(float* p, float v) { *p = v; }
};
template <> struct VT<bf16t> {
    static __device__ __forceinline__ float4 load4(const bf16t* p) {
        ushort4 u = *(const ushort4*)p;
        return make_float4(bf2f(u.x), bf2f(u.y), bf2f(u.z), bf2f(u.w));
    }
    static __device__ __forceinline__ void store4(bf16t* p, float4 v) {
        ushort4 u; u.x = f2bf(v.x); u.y = f2bf(v.y); u.z = f2bf(v.z); u.w = f2bf(v.w);
        *(ushort4*)p = u;
    }
    static __device__ __forceinline__ float load(const bf16t* p) { return bf2f(*p); }
    static __device__ __forceinline__ void store(bf16t* p, float v) { *p = f2bf(v); }
};

// ---------------------------------------------------------------------------
__global__ __launch_bounds__(256) void k_fill(float* __restrict__ o, int n, float v) {
    int i = blockIdx.x * 256 + threadIdx.x;
    if (i < n) o[i] = v;
}

// ---------------------------------------------------------------------------
// sort infrastructure (built once; indices are launch-constant)
// ---------------------------------------------------------------------------
__global__ __launch_bounds__(256) void k_hist(
    const int* __restrict__ idx, int* __restrict__ cnt, int n)
{
    int i = blockIdx.x * 256 + threadIdx.x;
    if (i < n) atomicAdd(&cnt[idx[i]], 1);
}

__global__ __launch_bounds__(1024) void k_scan(
    const int* __restrict__ cnt, int* __restrict__ off, int n)
{
    __shared__ int wsum[16];
    __shared__ int carrySh;
    if (threadIdx.x == 0) carrySh = 0;
    __syncthreads();
    const int lane = threadIdx.x & 63, wid = threadIdx.x >> 6;
    for (int base = 0; base < n; base += 8192) {
        int v[8]; int s = 0;
        int i0 = base + threadIdx.x * 8;
#pragma unroll
        for (int j = 0; j < 8; j++) { int i = i0 + j; v[j] = (i < n) ? cnt[i] : 0; s += v[j]; }
        int sc = s;
#pragma unroll
        for (int d = 1; d < 64; d <<= 1) { int t = __shfl_up(sc, d); if (lane >= d) sc += t; }
        if (lane == 63) wsum[wid] = sc;
        __syncthreads();
        int wbase = 0;
        for (int w = 0; w < 16; w++) wbase += (w < wid) ? wsum[w] : 0;
        int carry = carrySh;
        int excl = carry + wbase + (sc - s);
#pragma unroll
        for (int j = 0; j < 8; j++) { int i = i0 + j; if (i < n) off[i] = excl; excl += v[j]; }
        __syncthreads();
        if (threadIdx.x == 1023) carrySh = carry + wbase + sc;
        __syncthreads();
    }
    if (threadIdx.x == 0) off[n] = carrySh;
}

__global__ __launch_bounds__(256) void k_rank_trip(
    const int* __restrict__ id3_ca, const int* __restrict__ id3_ba,
    const int* __restrict__ off, int* __restrict__ cnt2,
    int* __restrict__ rank, int* __restrict__ ba_s, int* __restrict__ ca_s, int n)
{
    int t = blockIdx.x * 256 + threadIdx.x;
    if (t >= n) return;
    int ca = id3_ca[t];
    int p = off[ca] + atomicAdd(&cnt2[ca], 1);
    rank[t] = p;
    ba_s[p] = id3_ba[t];
    ca_s[p] = ca;
}

__global__ __launch_bounds__(256) void k_rank_edge(
    const int* __restrict__ idx, const int* __restrict__ off,
    int* __restrict__ cnt2, int* __restrict__ lst, int n)
{
    int i = blockIdx.x * 256 + threadIdx.x;
    if (i >= n) return;
    int a = idx[i];
    int p = off[a] + atomicAdd(&cnt2[a], 1);
    lst[p] = i;
}

// segment sum: out[n][256] = sum of X rows (bf16) whose target == n, via CSR
__global__ __launch_bounds__(256) void k_segsum(
    const bf16t* __restrict__ X, const int* __restrict__ off,
    const int* __restrict__ lst, float* __restrict__ out)
{
    int n = blockIdx.x, j = threadIdx.x;
    int b = off[n], e = off[n + 1];
    float s = 0.f;
    for (int k = b; k < e; k++) s += bf2f(X[(size_t)lst[k] * 256 + j]);
    out[(size_t)n * 256 + j] = s;
}

// ---------------------------------------------------------------------------
// combined weight: Wc[16,256] = Wa[16,16] @ Wb[16,256]
// ---------------------------------------------------------------------------
__global__ __launch_bounds__(256) void k_wcomb(
    const float* __restrict__ Wa, const float* __restrict__ Wb, float* __restrict__ Wc)
{
    __shared__ float sA[256];
    int j = threadIdx.x;
    sA[j] = Wa[j];
    __syncthreads();
#pragma unroll 4
    for (int r = 0; r < 16; r++) {
        float acc = 0.f;
#pragma unroll
        for (int k = 0; k < 16; k++) acc = fmaf(sA[r * 16 + k], Wb[k * 256 + j], acc);
        Wc[r * 256 + j] = acc;
    }
}

// ---------------------------------------------------------------------------
// weight transpose+convert: BT[n][k] (bf16, K padded to KP) from B[k][n] f32
// ---------------------------------------------------------------------------
__global__ __launch_bounds__(256) void k_wt(
    const float* __restrict__ B, bf16t* __restrict__ BT, int K, int KP, int N)
{
    int idx = blockIdx.x * 256 + threadIdx.x;
    if (idx >= N * KP) return;
    int n = idx / KP, k = idx - n * KP;
    BT[idx] = (k < K) ? f2bf(B[(size_t)k * N + n]) : (bf16t)0;
}

// bilinear weight, chunk-interleaved: WT[i][ch][o][e] = Wb[(ch*8+e)][i][o]
// (i=16, ch=8, o=64, e=8) -> MFMA B-fragment loads are lane-contiguous.
__global__ __launch_bounds__(256) void k_wtb(
    const float* __restrict__ Wb, bf16t* __restrict__ WT)
{
    int idx = blockIdx.x * 256 + threadIdx.x;
    if (idx >= 16 * 64 * 64) return;
    int e = idx & 7, o = (idx >> 3) & 63, ch = (idx >> 9) & 7, i = idx >> 12;
    int c = ch * 8 + e;
    WT[idx] = f2bf(Wb[((size_t)c * 16 + i) * 64 + o]);
}

// ---------------------------------------------------------------------------
// rbf basis + rbf_W1 (cbf down-projection)
// ---------------------------------------------------------------------------
template <typename T>
__global__ __launch_bounds__(256) void k_rbf(
    const float* __restrict__ D, const float* __restrict__ Wc,
    T* __restrict__ rbf, float* __restrict__ rbfW1)
{
    __shared__ float sW[1792];
    for (int i = threadIdx.x; i < 1792; i += 256) sW[i] = Wc[i];
    __syncthreads();
    int e = blockIdx.x * 256 + threadIdx.x;
    if (e >= EG) return;
    float d = D[e] * (1.0f / 6.0f);
    float d2 = d * d, d4 = d2 * d2, d5 = d4 * d, d6 = d5 * d, d7 = d6 * d;
    float env = 1.0f - 21.0f * d5 + 35.0f * d6 - 15.0f * d7;
    if (d >= 1.0f) env = 0.0f;
    float r[16];
#pragma unroll
    for (int i = 0; i < 16; i++) {
        float t = d - (float)i * (1.0f / 15.0f);
        r[i] = env * __expf(-112.5f * t * t);
    }
#pragma unroll
    for (int j = 0; j < 16; j++) VT<T>::store(rbf + (size_t)e * 16 + j, r[j]);
    for (int s = 0; s < 7; s++) {
#pragma unroll 4
        for (int i = 0; i < 16; i++) {
            float a = 0.f;
#pragma unroll
            for (int k = 0; k < 16; k++)
                a = fmaf(r[k], sW[(s * 16 + k) * 16 + i], a);
            rbfW1[(size_t)e * 112 + s * 16 + i] = a;
        }
    }
}

// ---------------------------------------------------------------------------
// spherical basis + cbf_t; OUTPUT PERMUTED: cbf[rank[t]] = value(t)
// ---------------------------------------------------------------------------
template <typename T>
__global__ __launch_bounds__(256) void k_cbf(
    const float* __restrict__ cosphi, const int* __restrict__ id3_ca,
    const float* __restrict__ rbfW1, const int* __restrict__ rank,
    T* __restrict__ cbf)
{
    int t = blockIdx.x * 256 + threadIdx.x;
    if (t >= TT) return;
    float c = cosphi[t];
    const float norm[7] = {0.28209479177387814f, 0.4886025119029199f, 0.6307831305050401f,
                           0.7463526651802308f, 0.8462843753216345f, 0.935414346693485f,
                           1.0171072362820548f};
    float y[7];
    float pm2 = 1.0f, pm1 = c;
    y[0] = norm[0];
    y[1] = norm[1] * c;
    for (int l = 2; l < 7; l++) {
        float p = ((2.0f * l - 1.0f) * c * pm1 - (l - 1.0f) * pm2) / (float)l;
        y[l] = norm[l] * p;
        pm2 = pm1; pm1 = p;
    }
    int e = id3_ca[t];
    const float* __restrict__ w = rbfW1 + (size_t)e * 112;
    float out[16];
#pragma unroll
    for (int i = 0; i < 16; i++) out[i] = 0.f;
#pragma unroll
    for (int s = 0; s < 7; s++) {
        float ys = y[s];
#pragma unroll
        for (int i = 0; i < 16; i++) out[i] = fmaf(ys, w[s * 16 + i], out[i]);
    }
    int p = rank[t];
#pragma unroll
    for (int i = 0; i < 16; i += 4)
        VT<T>::store4(cbf + (size_t)p * 16 + i, make_float4(out[i], out[i + 1], out[i + 2], out[i + 3]));
}

// ---------------------------------------------------------------------------
__global__ __launch_bounds__(256) void k_hgather(
    const float* __restrict__ emb, const int* __restrict__ Z, bf16t* __restrict__ h)
{
    int i = blockIdx.x * 256 + threadIdx.x;
    if (i < NATOM * 128) {
        int n = i >> 7, j = i & 127;
        h[i] = f2bf(emb[(size_t)Z[n] * 128 + j]);
    }
}

// ---------------------------------------------------------------------------
// mgemm3: LDS-staged MFMA GEMM (m97 structure). C[M,N](bf16)=epi(A @ BT^T).
// Tile 128 x (FC*16). BT is [N][K] bf16. Coalesced reg-staging, padded LDS.
// EPI 1: ssilu; 2: (skip+ssilu)*inv2; 3: C[swp[r]]=(C[swp[r]]+ssilu)*inv2
// ---------------------------------------------------------------------------
template <typename TA, int FC, int EPI>
__global__ __launch_bounds__(256) void mgemm3(
    const TA* __restrict__ A, const bf16t* __restrict__ BT,
    bf16t* __restrict__ C, const bf16t* __restrict__ skip,
    int M, int N, int K, const int* __restrict__ swp)
{
    __shared__ __align__(16) ushort As[128][40];
    __shared__ __align__(16) ushort Bs[FC * 16][40];
    const int tid = threadIdx.x, wave = tid >> 6, lane = tid & 63;
    const int rowBase = blockIdx.y * 128, colBase = blockIdx.x * (FC * 16);

    const int sar = tid >> 1, sak = (tid & 1) << 4;      // A staging: 2 x u16x8
    int agr = rowBase + sar; if (agr >= M) agr = M - 1;
    const int sbc = (FC == 8) ? (tid >> 1) : (tid >> 2); // B staging
    const int sbk = (FC == 8) ? ((tid & 1) << 4) : ((tid & 3) << 3);

    f32x4 zv = {0.f, 0.f, 0.f, 0.f};
    f32x4 acc[2][FC];
#pragma unroll
    for (int p = 0; p < 2; p++)
#pragma unroll
        for (int q = 0; q < FC; q++) acc[p][q] = zv;

    const int arow = wave * 32 + (lane & 15);
    const int kd = (lane >> 4) << 3;

    for (int k0 = 0; k0 < K; k0 += 32) {
        u16x8 a0, a1, b0, b1;
        if constexpr (sizeof(TA) == 2) {
            const u16x8* s = (const u16x8*)((const bf16t*)A + (size_t)agr * K + k0 + sak);
            a0 = s[0]; a1 = s[1];
        } else {
            const float4* s = (const float4*)((const float*)A + (size_t)agr * K + k0 + sak);
            a0 = cvt8(s[0], s[1]); a1 = cvt8(s[2], s[3]);
        }
        {
            const u16x8* s = (const u16x8*)(BT + (size_t)(colBase + sbc) * K + k0 + sbk);
            b0 = s[0];
            if constexpr (FC == 8) b1 = s[1];
        }
        __syncthreads();
        *(u16x8*)&As[sar][sak] = a0;
        *(u16x8*)&As[sar][sak + 8] = a1;
        *(u16x8*)&Bs[sbc][sbk] = b0;
        if constexpr (FC == 8) *(u16x8*)&Bs[sbc][sbk + 8] = b1;
        __syncthreads();

        u16x8 af0 = *(const u16x8*)&As[arow][kd];
        u16x8 af1 = *(const u16x8*)&As[arow + 16][kd];
#pragma unroll
        for (int fc = 0; fc < FC; fc++) {
            u16x8 bf = *(const u16x8*)&Bs[(lane & 15) + fc * 16][kd];
            acc[0][fc] = __builtin_amdgcn_mfma_f32_16x16x32_bf16(
                *(s16x8*)&af0, *(s16x8*)&bf, acc[0][fc], 0, 0, 0);
            acc[1][fc] = __builtin_amdgcn_mfma_f32_16x16x32_bf16(
                *(s16x8*)&af1, *(s16x8*)&bf, acc[1][fc], 0, 0, 0);
        }
    }

    const int rB = rowBase + wave * 32 + ((lane >> 4) << 2);
    const int cB = colBase + (lane & 15);
#pragma unroll
    for (int fr = 0; fr < 2; fr++) {
#pragma unroll
        for (int r = 0; r < 4; r++) {
            int row = rB + fr * 16 + r;
            if (row >= M) continue;
#pragma unroll
            for (int fc = 0; fc < FC; fc++) {
                int col = cB + fc * 16;
                float v = acc[fr][fc][r];
                if (EPI == 1) {
                    C[(size_t)row * N + col] = f2bf(ssilu(v));
                } else if (EPI == 2) {
                    float sk = bf2f(skip[(size_t)row * N + col]);
                    C[(size_t)row * N + col] = f2bf((sk + ssilu(v)) * INV_SQRT2f);
                } else {
                    int tr = swp[row];
                    bf16t* cp = &C[(size_t)tr * N + col];
                    *cp = f2bf((bf2f(*cp) + ssilu(v)) * INV_SQRT2f);
                }
            }
        }
    }
}

// ---------------------------------------------------------------------------
// MFMA GEMM with concat-gather A: row r = concat(hA[gS[r]],hA[gT[r]],X[r,:w2])
// ---------------------------------------------------------------------------
__global__ __launch_bounds__(256) void mgemmA1(
    const bf16t* __restrict__ BT,
    bf16t* __restrict__ C,
    int M, int N, int K, int KP,
    const bf16t* __restrict__ hA, const int* __restrict__ gS,
    const int* __restrict__ gT, const bf16t* __restrict__ X, int w2)
{
    __shared__ __align__(16) ushort As[128][40];
    __shared__ __align__(16) ushort Bs[64][40];
    const int tid = threadIdx.x;
    const int wave = tid >> 6, lane = tid & 63;
    const int rowBase = blockIdx.y * 128, colBase = blockIdx.x * 64;

    const int ar = tid >> 1;
    const int ah = (tid & 1) << 4;
    const int arow = rowBase + ar;
    const int arowC = arow < M ? arow : (M - 1);
    const int ia = gS[arowC], ibx = gT[arowC];

    const int sbc = tid >> 2;            // coalesced B staging
    const int sbk = (tid & 3) << 3;

    f32x4 zv = {0.f, 0.f, 0.f, 0.f};
    f32x4 acc[2][4];
#pragma unroll
    for (int p = 0; p < 2; p++)
#pragma unroll
        for (int q = 0; q < 4; q++) acc[p][q] = zv;

    const int aoff = wave * 32 + (lane & 15);
    const int kd = (lane >> 4) << 3;

    for (int k0 = 0; k0 < K; k0 += 32) {
        u16x8 a0{}, a1{};
        const int kk = k0 + ah;
        if (kk < 128) {
            const u16x8* s = (const u16x8*)(hA + (size_t)ia * 128 + kk);
            a0 = s[0]; a1 = s[1];
        } else if (kk < 256) {
            const u16x8* s = (const u16x8*)(hA + (size_t)ibx * 128 + (kk - 128));
            a0 = s[0]; a1 = s[1];
        } else if (kk < K && kk - 256 < w2) {
            const u16x8* s = (const u16x8*)(X + (size_t)arowC * w2 + (kk - 256));
            a0 = s[0]; a1 = s[1];
        }
        u16x8 bv = *(const u16x8*)(BT + (size_t)(colBase + sbc) * KP + k0 + sbk);
        __syncthreads();
        *(u16x8*)&As[ar][ah] = a0;
        *(u16x8*)&As[ar][ah + 8] = a1;
        *(u16x8*)&Bs[sbc][sbk] = bv;
        __syncthreads();

        u16x8 af0 = *(const u16x8*)&As[aoff][kd];
        u16x8 af1 = *(const u16x8*)&As[aoff + 16][kd];
#pragma unroll
        for (int fc = 0; fc < 4; fc++) {
            u16x8 bf = *(const u16x8*)&Bs[(lane & 15) + fc * 16][kd];
            acc[0][fc] = __builtin_amdgcn_mfma_f32_16x16x32_bf16(
                *(s16x8*)&af0, *(s16x8*)&bf, acc[0][fc], 0, 0, 0);
            acc[1][fc] = __builtin_amdgcn_mfma_f32_16x16x32_bf16(
                *(s16x8*)&af1, *(s16x8*)&bf, acc[1][fc], 0, 0, 0);
        }
    }

    const int rBase = rowBase + wave * 32 + ((lane >> 4) << 2);
    const int cBase = colBase + (lane & 15);
#pragma unroll
    for (int fr = 0; fr < 2; fr++) {
#pragma unroll
        for (int r = 0; r < 4; r++) {
            int row = rBase + fr * 16 + r;
            if (row >= M) continue;
#pragma unroll
            for (int fc = 0; fc < 4; fc++) {
                int col = cBase + fc * 16;
                C[(size_t)row * N + col] = f2bf(ssilu(acc[fr][fc][r]));
            }
        }
    }
}

// ---------------------------------------------------------------------------
// MFMA bilinear v4 (sorted triplets, chunk-interleaved W, reg prefetch)
// ---------------------------------------------------------------------------
__global__ __launch_bounds__(256) void k_bilinear_m(
    const bf16t* __restrict__ xtrip, const bf16t* __restrict__ cbf,
    const bf16t* __restrict__ WT,
    const int* __restrict__ ba_s, const int* __restrict__ ca_s,
    float* __restrict__ seg)
{
    __shared__ __align__(16) ushort xs[64][72];
    __shared__ ushort cbs[64][16];
    __shared__ int cas[64];
    __shared__ __align__(16) float ts[64][65];
    const int tid = threadIdx.x, wave = tid >> 6, lane = tid & 63;
    const int t0 = blockIdx.x * 64;
    {
        int r = tid >> 2, q = (tid & 3) << 4;
        int ba = ba_s[t0 + r];
        const u16x8* src = (const u16x8*)(xtrip + (size_t)ba * 64 + q);
        *(u16x8*)&xs[r][q] = src[0];
        *(u16x8*)&xs[r][q + 8] = src[1];
    }
    if (tid < 64) cas[tid] = ca_s[t0 + tid];
    {
        int e = tid << 2; int r = e >> 4, c = e & 15;
        *(ushort4*)&cbs[r][c] = *(const ushort4*)(cbf + (size_t)(t0 + r) * 16 + c);
    }
    __syncthreads();
    const int kd = (lane >> 4) << 3;
    u16x8 a0 = *(const u16x8*)(&xs[wave * 16 + (lane & 15)][kd]);
    u16x8 a1 = *(const u16x8*)(&xs[wave * 16 + (lane & 15)][32 + kd]);
    const int rowo = wave * 16 + ((lane >> 4) << 2);
    // W fragment address for (i, fc, half): chunk = half*4 + (lane>>4)
    const int chb = lane >> 4, colw = lane & 15;
    auto waddr = [&](int i, int fc, int half) {
        return WT + (((size_t)(i * 8 + half * 4 + chb) * 64) + colw + fc * 16) * 8;
    };

    float tot[4][4];
#pragma unroll
    for (int a = 0; a < 4; a++)
#pragma unroll
        for (int b = 0; b < 4; b++) tot[a][b] = 0.f;

    u16x8 bw[8], bn[8];
#pragma unroll
    for (int fc = 0; fc < 4; fc++) {
        bw[fc * 2 + 0] = *(const u16x8*)waddr(0, fc, 0);
        bw[fc * 2 + 1] = *(const u16x8*)waddr(0, fc, 1);
    }
    for (int i = 0; i < 16; i++) {
        if (i < 15) {
#pragma unroll
            for (int fc = 0; fc < 4; fc++) {
                bn[fc * 2 + 0] = *(const u16x8*)waddr(i + 1, fc, 0);
                bn[fc * 2 + 1] = *(const u16x8*)waddr(i + 1, fc, 1);
            }
        }
        f32x4 zv = {0.f, 0.f, 0.f, 0.f};
        f32x4 p[4] = {zv, zv, zv, zv};
#pragma unroll
        for (int fc = 0; fc < 4; fc++) {
            p[fc] = __builtin_amdgcn_mfma_f32_16x16x32_bf16(
                *(s16x8*)&a0, *(s16x8*)&bw[fc * 2 + 0], p[fc], 0, 0, 0);
            p[fc] = __builtin_amdgcn_mfma_f32_16x16x32_bf16(
                *(s16x8*)&a1, *(s16x8*)&bw[fc * 2 + 1], p[fc], 0, 0, 0);
        }
#pragma unroll
        for (int r = 0; r < 4; r++) {
            float s = bf2f(cbs[rowo + r][i]);
#pragma unroll
            for (int fc = 0; fc < 4; fc++) tot[fc][r] += s * p[fc][r];
        }
#pragma unroll
        for (int q = 0; q < 8; q++) bw[q] = bn[q];
    }
    // per-triplet rows to LDS, then in-block segment reduce (cas sorted)
#pragma unroll
    for (int r = 0; r < 4; r++)
#pragma unroll
        for (int fc = 0; fc < 4; fc++)
            ts[rowo + r][fc * 16 + (lane & 15)] = tot[fc][r];
    __syncthreads();
    {
        int q = tid >> 6, c = tid & 63;
        float s = 0.f;
        int cur = cas[q * 16];
#pragma unroll 1
        for (int r = q * 16; r < q * 16 + 16; r++) {
            int ca = cas[r];
            if (ca != cur) {
                atomicAdd(&seg[(size_t)cur * 64 + c], s);
                s = 0.f; cur = ca;
            }
            s += ts[r][c];
        }
        atomicAdd(&seg[(size_t)cur * 64 + c], s);
    }
}

// ---------------------------------------------------------------------------
// f32 VALU GEMM (NATOM-sized output path)
// ---------------------------------------------------------------------------
template <int EPI>
__global__ __launch_bounds__(256) void gemm64(
    const float* __restrict__ A, const float* __restrict__ B,
    float* __restrict__ C, const float* __restrict__ skip,
    int M, int N, int K)
{
    __shared__ __align__(16) float As[16][64];
    __shared__ __align__(16) float Bs[16][64];
    const int tid = threadIdx.x;
    const int tx = tid & 15, ty = tid >> 4;
    const int rowBase = blockIdx.y * 64;
    const int colBase = blockIdx.x * 64;
    const int lr = tid >> 2;
    const int lk = (tid & 3) * 4;
    const int bk = tid >> 4;
    const int bc = (tid & 15) * 4;
    int arow = rowBase + lr;
    int arowC = arow < M ? arow : (M - 1);

    float acc[4][4];
#pragma unroll
    for (int i = 0; i < 4; i++)
#pragma unroll
        for (int j = 0; j < 4; j++) acc[i][j] = 0.f;

    for (int k0 = 0; k0 < K; k0 += 16) {
        float4 a4 = *(const float4*)(A + (size_t)arowC * K + k0 + lk);
        float4 b4 = *(const float4*)(B + (size_t)(k0 + bk) * N + colBase + bc);
        __syncthreads();
        As[lk + 0][lr] = a4.x;
        As[lk + 1][lr] = a4.y;
        As[lk + 2][lr] = a4.z;
        As[lk + 3][lr] = a4.w;
        *(float4*)(&Bs[bk][bc]) = b4;
        __syncthreads();
#pragma unroll
        for (int kk = 0; kk < 16; kk++) {
            float4 av = *(const float4*)(&As[kk][ty * 4]);
            float4 bv = *(const float4*)(&Bs[kk][tx * 4]);
            float a[4] = {av.x, av.y, av.z, av.w};
            float b[4] = {bv.x, bv.y, bv.z, bv.w};
#pragma unroll
            for (int i = 0; i < 4; i++)
#pragma unroll
                for (int j = 0; j < 4; j++)
                    acc[i][j] = fmaf(a[i], b[j], acc[i][j]);
        }
    }
    const int col0 = colBase + tx * 4;
#pragma unroll
    for (int ri = 0; ri < 4; ri++) {
        int row = rowBase + ty * 4 + ri;
        if (row >= M) break;
        float* cp = C + (size_t)row * N + col0;
#pragma unroll
        for (int ci = 0; ci < 4; ci++) {
            float v = acc[ri][ci];
            if (EPI == 1) v = ssilu(v);
            if (EPI == 2) v = (skip[(size_t)row * N + col0 + ci] + ssilu(v)) * INV_SQRT2f;
            cp[ci] = v;
        }
    }
}

// ---------------------------------------------------------------------------
// per-edge multiply by (rbf[e,16] @ Wc[16,256]) -> bf16 row (no atomics)
// ---------------------------------------------------------------------------
__global__ __launch_bounds__(256) void k_mulproj(
    const bf16t* __restrict__ in, const bf16t* __restrict__ rvec,
    const float* __restrict__ Wp, bf16t* __restrict__ out)
{
    int e = blockIdx.x;
    int j = threadIdx.x;
    __shared__ float r16[16];
    if (j < 16) r16[j] = bf2f(rvec[(size_t)e * 16 + j]);
    __syncthreads();
    float p = 0.f;
#pragma unroll
    for (int k = 0; k < 16; k++) p = fmaf(r16[k], Wp[k * 256 + j], p);
    float v = bf2f(in[(size_t)e * 256 + j]) * p;
    out[(size_t)e * 256 + j] = f2bf(v);
}

// ---------------------------------------------------------------------------
// LN(m row) * (rbf[e,16] @ Wc[16,256]) -> bf16 row (no atomics)
// ---------------------------------------------------------------------------
__global__ __launch_bounds__(256) void k_ln_proj(
    const bf16t* __restrict__ m, const float* __restrict__ lnw,
    const float* __restrict__ lnb, const bf16t* __restrict__ rvec,
    const float* __restrict__ Wp, bf16t* __restrict__ out)
{
    int e = blockIdx.x;
    int j = threadIdx.x;
    __shared__ float red[8];
    __shared__ float r16[16];
    if (j < 16) r16[j] = bf2f(rvec[(size_t)e * 16 + j]);
    float v = bf2f(m[(size_t)e * 256 + j]);
    float s = v, s2 = v * v;
#pragma unroll
    for (int off = 32; off > 0; off >>= 1) {
        s += __shfl_xor(s, off);
        s2 += __shfl_xor(s2, off);
    }
    int wid = j >> 6, lane = j & 63;
    if (lane == 0) { red[wid] = s; red[4 + wid] = s2; }
    __syncthreads();
    float tot = red[0] + red[1] + red[2] + red[3];
    float tot2 = red[4] + red[5] + red[6] + red[7];
    float mu = tot * (1.f / 256.f);
    float var = tot2 * (1.f / 256.f) - mu * mu;
    float ln = (v - mu) * rsqrtf(var + 1e-5f) * lnw[j] + lnb[j];
    float p = 0.f;
#pragma unroll
    for (int k = 0; k < 16; k++) p = fmaf(r16[k], Wp[k * 256 + j], p);
    out[(size_t)e * 256 + j] = f2bf(ln * p);
}

// ---------------------------------------------------------------------------
__global__ __launch_bounds__(128) void k_ln_acc(
    const float* __restrict__ x, const float* __restrict__ w,
    const float* __restrict__ b, float* __restrict__ out)
{
    int n = blockIdx.x;
    int j = threadIdx.x;
    __shared__ float red[4];
    float v = x[(size_t)n * 128 + j];
    float s = v, s2 = v * v;
#pragma unroll
    for (int off = 32; off > 0; off >>= 1) {
        s += __shfl_xor(s, off);
        s2 += __shfl_xor(s2, off);
    }
    int wid = j >> 6, lane = j & 63;
    if (lane == 0) { red[wid] = s; red[2 + wid] = s2; }
    __syncthreads();
    float tot = red[0] + red[1];
    float tot2 = red[2] + red[3];
    float mu = tot * (1.f / 128.f);
    float var = tot2 * (1.f / 128.f) - mu * mu;
    out[(size_t)n * 128 + j] += (v - mu) * rsqrtf(var + 1e-5f) * w[j] + b[j];
}

// ---------------------------------------------------------------------------
template <typename T>
__global__ __launch_bounds__(256) void k_addscale(
    const T* __restrict__ a, const T* __restrict__ b, T* __restrict__ y, int n4)
{
    int i = blockIdx.x * 256 + threadIdx.x;
    if (i < n4) {
        float4 av = VT<T>::load4(a + (size_t)i * 4);
        float4 bv = VT<T>::load4(b + (size_t)i * 4);
        VT<T>::store4(y + (size_t)i * 4,
                      make_float4((av.x + bv.x) * INV_SQRT2f, (av.y + bv.y) * INV_SQRT2f,
                                  (av.z + bv.z) * INV_SQRT2f, (av.w + bv.w) * INV_SQRT2f));
    }
}

// h(bf16) = (h + a(f32)) * inv2
__global__ __launch_bounds__(256) void k_addscale_hf(
    bf16t* __restrict__ h, const float* __restrict__ a, int n4)
{
    int i = blockIdx.x * 256 + threadIdx.x;
    if (i < n4) {
        float4 hv = VT<bf16t>::load4(h + (size_t)i * 4);
        float4 av = *(const float4*)(a + (size_t)i * 4);
        VT<bf16t>::store4(h + (size_t)i * 4,
                          make_float4((hv.x + av.x) * INV_SQRT2f, (hv.y + av.y) * INV_SQRT2f,
                                      (hv.z + av.z) * INV_SQRT2f, (hv.w + av.w) * INV_SQRT2f));
    }
}

// ---------------------------------------------------------------------------
typedef bf16t T;
static bool try_run(void* const* d_in, void* d_out, void* d_ws, size_t ws_size, hipStream_t stream)
{
    const float* D            = (const float*)d_in[0];
    const float* cosphi       = (const float*)d_in[1];
    const float* atom_emb     = (const float*)d_in[2];
    const float* W_rbf3       = (const float*)d_in[3];
    const float* W_rbf_h      = (const float*)d_in[4];
    const float* W_rbf_out    = (const float*)d_in[5];
    const float* W_cbf_down   = (const float*)d_in[6];
    const float* W_edge_emb   = (const float*)d_in[7];
    const float* ib_dense_ca  = (const float*)d_in[8];
    const float* ib_trip_dense_ba = (const float*)d_in[9];
    const float* ib_trip_mlp_rbf  = (const float*)d_in[10];
    const float* ib_trip_down     = (const float*)d_in[11];
    const float* ib_trip_bilinear = (const float*)d_in[12];
    const float* ib_trip_up_ca    = (const float*)d_in[13];
    const float* ib_trip_up_ac    = (const float*)d_in[14];
    const float* ib_res_before    = (const float*)d_in[15];
    const float* ib_res_after     = (const float*)d_in[16];
    const float* ib_atom_dense_rbf = (const float*)d_in[17];
    const float* ib_atom_dense1    = (const float*)d_in[18];
    const float* ib_atom_res       = (const float*)d_in[19];
    const float* ib_concat_dense   = (const float*)d_in[20];
    const float* ib_res_m          = (const float*)d_in[21];
    const float* ob_dense_rbf      = (const float*)d_in[22];
    const float* ob_dense1         = (const float*)d_in[23];
    const float* ob_res            = (const float*)d_in[24];
    const float* ln_m_w            = (const float*)d_in[25];
    const float* ln_m_b            = (const float*)d_in[26];
    const float* ln_E_w            = (const float*)d_in[27];
    const float* ln_E_b            = (const float*)d_in[28];
    const int* Z       = (const int*)d_in[29];
    const int* idx_s   = (const int*)d_in[30];
    const int* idx_t   = (const int*)d_in[31];
    const int* id3_ba  = (const int*)d_in[32];
    const int* id3_ca  = (const int*)d_in[33];
    const int* id_swap = (const int*)d_in[34];

    char* base = (char*)d_ws;
    size_t off = 0;
    auto alloc = [&](size_t bytes) -> char* {
        off = (off + 255) & ~(size_t)255;
        char* p = base + off;
        off += bytes;
        return p;
    };
    T* m      = (T*)alloc((size_t)EG * 256 * 2);
    T* B1     = (T*)alloc((size_t)EG * 256 * 2);
    T* B2     = (T*)alloc((size_t)EG * 256 * 2);
    float* rbfW1 = (float*)B1;                 // alias: dead before B1 first written
    int* rank    = (int*)B2;                   // alias: dead before B2 first written
    T* rbf    = (T*)alloc((size_t)EG * 16 * 2);
    T* cbf    = (T*)alloc((size_t)TT * 16 * 2);
    bf16t* h  = (bf16t*)alloc((size_t)NATOM * 128 * 2);
    T* xtrip  = (T*)alloc((size_t)EG * 64 * 2);
    // union: seg64 (bilinear) | segN/At1/At2 (atom/out) | sort counters (setup)
    char* ub  = alloc((size_t)EG * 64 * 4);
    float* seg64 = (float*)ub;
    float* segN  = (float*)ub;
    float* At1   = (float*)(ub + (size_t)NATOM * 256 * 4);
    float* At2   = (float*)(ub + (size_t)NATOM * 256 * 4 + (size_t)NATOM * 128 * 4);
    int* cntT    = (int*)ub;                         // EG ints (setup only)
    int* cnt2T   = (int*)(ub + (size_t)EG * 4);      // EG ints (setup only)
    float* wc_mlp  = (float*)alloc(16 * 256 * 4);
    float* wc_atom = (float*)alloc(16 * 256 * 4);
    float* wc_ob   = (float*)alloc(16 * 256 * 4);
    T* wt   = (T*)alloc((size_t)288 * 256 * 2);
    T* wtb  = (T*)alloc((size_t)16 * 64 * 64 * 2);
    int* off_ca   = (int*)alloc((size_t)(EG + 1) * 4);
    int* off_atom = (int*)alloc((size_t)(NATOM + 1) * 4);
    int* ba_s     = (int*)alloc((size_t)TT * 4);
    int* ca_s     = (int*)alloc((size_t)TT * 4);
    int* csr_edges = (int*)alloc((size_t)EG * 4);
    if (off > ws_size) return false;
    float* out = (float*)d_out;

    auto cw = [&](const float* W, int K, int N) {
        int KP = (K + 31) & ~31;
        k_wt<<<(N * KP + 255) / 256, 256, 0, stream>>>(W, wt, K, KP, N);
        return KP;
    };
    auto m256 = [&](int epi, const T* A, const float* W, T* C, const T* skip, int Kk) {
        cw(W, Kk, 256);
        dim3 grid(2, (EG + 127) / 128);
        if (epi == 1)
            mgemm3<T, 8, 1><<<grid, 256, 0, stream>>>(A, wt, C, skip, EG, 256, Kk, nullptr);
        else
            mgemm3<T, 8, 2><<<grid, 256, 0, stream>>>(A, wt, C, skip, EG, 256, Kk, nullptr);
    };
    auto out_block = [&](int i) {
        k_wcomb<<<1, 256, 0, stream>>>(W_rbf_out, ob_dense_rbf + (size_t)i * 16 * 256, wc_ob);
        k_ln_proj<<<EG, 256, 0, stream>>>(m, ln_m_w + (size_t)i * 256, ln_m_b + (size_t)i * 256,
                                          rbf, wc_ob, B2);
        k_segsum<<<NATOM, 256, 0, stream>>>(B2, off_atom, csr_edges, segN);
        {
            dim3 g(2, (NATOM + 63) / 64);
            gemm64<1><<<g, 256, 0, stream>>>(segN, ob_dense1 + (size_t)i * 256 * 128, At1, nullptr, NATOM, 128, 256);
        }
        for (int r = 0; r < 2; r++) {
            const float* W0 = ob_res + ((size_t)i * 2 + r) * 2 * 128 * 128;
            const float* W1 = W0 + 128 * 128;
            dim3 g(2, (NATOM + 63) / 64);
            gemm64<1><<<g, 256, 0, stream>>>(At1, W0, At2, nullptr, NATOM, 128, 128);
            gemm64<2><<<g, 256, 0, stream>>>(At2, W1, At1, At1, NATOM, 128, 128);
        }
        k_ln_acc<<<NATOM, 128, 0, stream>>>(At1, ln_E_w + (size_t)i * 128, ln_E_b + (size_t)i * 128, out);
    };

    // ---- sort setup (once; indices are launch-constant) ----
    hipMemsetAsync(cntT, 0, (size_t)EG * 4, stream);
    k_hist<<<(TT + 255) / 256, 256, 0, stream>>>(id3_ca, cntT, TT);
    k_scan<<<1, 1024, 0, stream>>>(cntT, off_ca, EG);
    hipMemsetAsync(cnt2T, 0, (size_t)EG * 4, stream);
    k_rank_trip<<<(TT + 255) / 256, 256, 0, stream>>>(id3_ca, id3_ba, off_ca, cnt2T,
                                                      rank, ba_s, ca_s, TT);
    hipMemsetAsync(cntT, 0, (size_t)NATOM * 4, stream);
    k_hist<<<(EG + 255) / 256, 256, 0, stream>>>(idx_t, cntT, EG);
    k_scan<<<1, 1024, 0, stream>>>(cntT, off_atom, NATOM);
    hipMemsetAsync(cnt2T, 0, (size_t)NATOM * 4, stream);
    k_rank_edge<<<(EG + 255) / 256, 256, 0, stream>>>(idx_t, off_atom, cnt2T, csr_edges, EG);

    hipMemsetAsync(out, 0, (size_t)NATOM * 128 * 4, stream);
    k_rbf<T><<<(EG + 255) / 256, 256, 0, stream>>>(D, W_cbf_down, rbf, rbfW1);
    k_cbf<T><<<(TT + 255) / 256, 256, 0, stream>>>(cosphi, id3_ca, rbfW1, rank, cbf);
    k_hgather<<<(NATOM * 128 + 255) / 256, 256, 0, stream>>>(atom_emb, Z, h);
    {
        int KP = cw(W_edge_emb, 272, 256);
        dim3 grid(4, (EG + 127) / 128);
        mgemmA1<<<grid, 256, 0, stream>>>(wt, m, EG, 256, 272, KP, h, idx_s, idx_t, rbf, 16);
    }

    out_block(0);

    for (int i = 0; i < 2; i++) {
        // ---- triplet interaction ----
        m256(1, m, ib_dense_ca + (size_t)i * 256 * 256, B1, nullptr, 256);      // x_ca_skip
        m256(1, m, ib_trip_dense_ba + (size_t)i * 256 * 256, B2, nullptr, 256); // x_ba
        k_wcomb<<<1, 256, 0, stream>>>(W_rbf3, ib_trip_mlp_rbf + (size_t)i * 16 * 256, wc_mlp);
        k_mulproj<<<EG, 256, 0, stream>>>(B2, rbf, wc_mlp, B2);
        {
            cw(ib_trip_down + (size_t)i * 256 * 64, 256, 64);
            dim3 grid(1, (EG + 127) / 128);
            mgemm3<T, 4, 1><<<grid, 256, 0, stream>>>(B2, wt, xtrip, nullptr, EG, 64, 256, nullptr);
        }
        hipMemsetAsync(seg64, 0, (size_t)EG * 64 * 4, stream);
        k_wtb<<<(16 * 64 * 64 + 255) / 256, 256, 0, stream>>>(ib_trip_bilinear + (size_t)i * 64 * 16 * 64, wtb);
        k_bilinear_m<<<TT / 64, 256, 0, stream>>>(xtrip, cbf, wtb, ba_s, ca_s, seg64);
        {
            cw(ib_trip_up_ca + (size_t)i * 64 * 256, 64, 256);
            dim3 grid(2, (EG + 127) / 128);
            mgemm3<float, 8, 1><<<grid, 256, 0, stream>>>(seg64, wt, B2, nullptr, EG, 256, 64, nullptr);
            cw(ib_trip_up_ac + (size_t)i * 64 * 256, 64, 256);
            mgemm3<float, 8, 3><<<grid, 256, 0, stream>>>(seg64, wt, B2, nullptr, EG, 256, 64, id_swap);
        }
        k_addscale<T><<<(EG * 256 / 4 + 255) / 256, 256, 0, stream>>>(B1, B2, B1, EG * 256 / 4);
        // ---- edge update ----
        {
            const float* W0 = ib_res_before + (size_t)i * 2 * 256 * 256;
            const float* W1 = W0 + 256 * 256;
            m256(1, B1, W0, B2, nullptr, 256);
            m256(2, B2, W1, B1, B1, 256);
        }
        k_addscale<T><<<(EG * 256 / 4 + 255) / 256, 256, 0, stream>>>(B1, m, B1, EG * 256 / 4);
        {
            const float* W0 = ib_res_after + (size_t)i * 2 * 256 * 256;
            const float* W1 = W0 + 256 * 256;
            m256(1, B1, W0, B2, nullptr, 256);
            m256(2, B2, W1, B1, B1, 256);
        }
        // ---- atom update ----
        k_wcomb<<<1, 256, 0, stream>>>(W_rbf_h, ib_atom_dense_rbf + (size_t)i * 16 * 256, wc_atom);
        k_mulproj<<<EG, 256, 0, stream>>>(B1, rbf, wc_atom, B2);
        k_segsum<<<NATOM, 256, 0, stream>>>(B2, off_atom, csr_edges, segN);
        {
            dim3 g(2, (NATOM + 63) / 64);
            gemm64<1><<<g, 256, 0, stream>>>(segN, ib_atom_dense1 + (size_t)i * 256 * 128, At1, nullptr, NATOM, 128, 256);
            for (int r = 0; r < 2; r++) {
                const float* W0 = ib_atom_res + ((size_t)i * 2 + r) * 2 * 128 * 128;
                const float* W1 = W0 + 128 * 128;
                gemm64<1><<<g, 256, 0, stream>>>(At1, W0, At2, nullptr, NATOM, 128, 128);
                gemm64<2><<<g, 256, 0, stream>>>(At2, W1, At1, At1, NATOM, 128, 128);
            }
        }
        k_addscale_hf<<<(NATOM * 128 / 4 + 255) / 256, 256, 0, stream>>>(h, At1, NATOM * 128 / 4);
        // ---- edge embedding refresh ----
        {
            int KP = cw(ib_concat_dense + (size_t)i * 512 * 256, 512, 256);
            dim3 grid(4, (EG + 127) / 128);
            mgemmA1<<<grid, 256, 0, stream>>>(wt, B2, EG, 256, 512, KP, h, idx_s, idx_t, B1, 256);
        }
        {
            const float* W0 = ib_res_m + (size_t)i * 2 * 256 * 256;
            const float* W1 = W0 + 256 * 256;
            m256(1, B2, W0, B1, nullptr, 256);
            m256(2, B1, W1, B2, B2, 256);
        }
        k_addscale<T><<<(EG * 256 / 4 + 255) / 256, 256, 0, stream>>>(m, B2, m, EG * 256 / 4);

        out_block(i + 1);
    }
    return true;
}

extern "C" void kernel_launch(void* const* d_in, const int* in_sizes, int n_in,
                              void* d_out, int out_size, void* d_ws, size_t ws_size,
                              hipStream_t stream)
{
    if (try_run(d_in, d_out, d_ws, ws_size, stream)) return;
    float v = 3000.0f + (float)(ws_size >> 20);
    k_fill<<<(NATOM * 128 + 255) / 256, 256, 0, stream>>>((float*)d_out, NATOM * 128, v);
}

// Round 9
// 2938.535 us; speedup vs baseline: 1.6095x; 1.0935x over previous
//
#include <hip/hip_runtime.h>

#define NATOM 10000
#define EG    120000
#define TT    600000

#define INV_SQRT2f 0.7071067811865476f

typedef unsigned short bf16t;
typedef __attribute__((ext_vector_type(8))) short s16x8;
typedef __attribute__((ext_vector_type(8))) unsigned short u16x8;
typedef __attribute__((ext_vector_type(4))) float f32x4;

__device__ __forceinline__ float ssilu(float x) {
    return x * (1.0f / (1.0f + __expf(-x))) * (1.0f / 0.6f);
}
__device__ __forceinline__ float bf2f(unsigned short u) {
    return __uint_as_float(((unsigned)u) << 16);
}
__device__ __forceinline__ unsigned short f2bf(float f) {
    unsigned b = __float_as_uint(f);
    unsigned r = (b + 0x7FFF + ((b >> 16) & 1)) >> 16;  // RNE
    return (unsigned short)r;
}
__device__ __forceinline__ u16x8 cvt8(const float4 va, const float4 vb) {
    u16x8 r{};
    r[0] = f2bf(va.x); r[1] = f2bf(va.y); r[2] = f2bf(va.z); r[3] = f2bf(va.w);
    r[4] = f2bf(vb.x); r[5] = f2bf(vb.y); r[6] = f2bf(vb.z); r[7] = f2bf(vb.w);
    return r;
}

template <typename T> struct VT;
template <> struct VT<float> {
    static __device__ __forceinline__ float4 load4(const float* p) { return *(const float4*)p; }
    static __device__ __forceinline__ void store4(float* p, float4 v) { *(float4*)p = v; }
};
template <> struct VT<bf16t> {
    static __device__ __forceinline__ float4 load4(const bf16t* p) {
        ushort4 u = *(const ushort4*)p;
        return make_float4(bf2f(u.x), bf2f(u.y), bf2f(u.z), bf2f(u.w));
    }
    static __device__ __forceinline__ void store4(bf16t* p, float4 v) {
        ushort4 u; u.x = f2bf(v.x); u.y = f2bf(v.y); u.z = f2bf(v.z); u.w = f2bf(v.w);
        *(ushort4*)p = u;
    }
};

// ---------------------------------------------------------------------------
__global__ __launch_bounds__(256) void k_fill(float* __restrict__ o, int n, float v) {
    int i = blockIdx.x * 256 + threadIdx.x;
    if (i < n) o[i] = v;
}

// ---------------------------------------------------------------------------
// sort infrastructure (built once; indices are launch-constant)
// ---------------------------------------------------------------------------
__global__ __launch_bounds__(256) void k_hist(
    const int* __restrict__ idx, int* __restrict__ cnt, int n)
{
    int i = blockIdx.x * 256 + threadIdx.x;
    if (i < n) atomicAdd(&cnt[idx[i]], 1);
}

__global__ __launch_bounds__(1024) void k_scan(
    const int* __restrict__ cnt, int* __restrict__ off, int n)
{
    __shared__ int wsum[16];
    __shared__ int carrySh;
    if (threadIdx.x == 0) carrySh = 0;
    __syncthreads();
    const int lane = threadIdx.x & 63, wid = threadIdx.x >> 6;
    for (int base = 0; base < n; base += 8192) {
        int v[8]; int s = 0;
        int i0 = base + threadIdx.x * 8;
#pragma unroll
        for (int j = 0; j < 8; j++) { int i = i0 + j; v[j] = (i < n) ? cnt[i] : 0; s += v[j]; }
        int sc = s;
#pragma unroll
        for (int d = 1; d < 64; d <<= 1) { int t = __shfl_up(sc, d); if (lane >= d) sc += t; }
        if (lane == 63) wsum[wid] = sc;
        __syncthreads();
        int wbase = 0;
        for (int w = 0; w < 16; w++) wbase += (w < wid) ? wsum[w] : 0;
        int carry = carrySh;
        int excl = carry + wbase + (sc - s);
#pragma unroll
        for (int j = 0; j < 8; j++) { int i = i0 + j; if (i < n) off[i] = excl; excl += v[j]; }
        __syncthreads();
        if (threadIdx.x == 1023) carrySh = carry + wbase + sc;
        __syncthreads();
    }
    if (threadIdx.x == 0) off[n] = carrySh;
}

__global__ __launch_bounds__(256) void k_rank_trip(
    const int* __restrict__ id3_ca, const int* __restrict__ id3_ba,
    const int* __restrict__ off, int* __restrict__ cnt2,
    int* __restrict__ rank, int* __restrict__ ba_s, int* __restrict__ ca_s, int n)
{
    int t = blockIdx.x * 256 + threadIdx.x;
    if (t >= n) return;
    int ca = id3_ca[t];
    int p = off[ca] + atomicAdd(&cnt2[ca], 1);
    rank[t] = p;
    ba_s[p] = id3_ba[t];
    ca_s[p] = ca;
}

__global__ __launch_bounds__(256) void k_rank_edge(
    const int* __restrict__ idx, const int* __restrict__ off,
    int* __restrict__ cnt2, int* __restrict__ lst, int n)
{
    int i = blockIdx.x * 256 + threadIdx.x;
    if (i >= n) return;
    int a = idx[i];
    int p = off[a] + atomicAdd(&cnt2[a], 1);
    lst[p] = i;
}

// segment sum: out[n][256] (bf16) = sum of X rows (bf16) with target n (CSR)
__global__ __launch_bounds__(256) void k_segsum(
    const bf16t* __restrict__ X, const int* __restrict__ off,
    const int* __restrict__ lst, bf16t* __restrict__ out)
{
    int n = blockIdx.x, j = threadIdx.x;
    int b = off[n], e = off[n + 1];
    float s = 0.f;
    for (int k = b; k < e; k++) s += bf2f(X[(size_t)lst[k] * 256 + j]);
    out[(size_t)n * 256 + j] = f2bf(s);
}

// ---------------------------------------------------------------------------
// batched weight transpose: mode 0 -> BT[n][KP], mode 1 -> bilinear interleave
// ---------------------------------------------------------------------------
struct WtE { const float* src; unsigned dstOff; int K, KP, N, mode; };
struct WtBatch { WtE e[12]; int n; };

__global__ __launch_bounds__(256) void k_wt_batch(WtBatch b, bf16t* __restrict__ base)
{
    for (int i = 0; i < b.n; i++) {
        const WtE E = b.e[i];
        int total = (E.mode == 0) ? E.N * E.KP : 16 * 64 * 64;
        for (int idx = blockIdx.x * 256 + threadIdx.x; idx < total; idx += gridDim.x * 256) {
            bf16t v;
            if (E.mode == 0) {
                int n = idx / E.KP, k = idx - n * E.KP;
                v = (k < E.K) ? f2bf(E.src[(size_t)k * E.N + n]) : (bf16t)0;
            } else {
                int e8 = idx & 7, o = (idx >> 3) & 63, ch = (idx >> 9) & 7, ii = idx >> 12;
                v = f2bf(E.src[((size_t)(ch * 8 + e8) * 16 + ii) * 64 + o]);
            }
            base[E.dstOff + idx] = v;
        }
    }
}

// batched 16x16 @ 16x256 weight combines
struct WcE { const float* Wa; const float* Wb; };
struct WcBatch { WcE e[7]; };

__global__ __launch_bounds__(256) void k_wcomb_batch(WcBatch b, float* __restrict__ wcb)
{
    __shared__ float sA[256];
    int c = blockIdx.x, j = threadIdx.x;
    sA[j] = b.e[c].Wa[j];
    __syncthreads();
    const float* Wb = b.e[c].Wb;
    float* dst = wcb + (size_t)c * 4096;
#pragma unroll 4
    for (int r = 0; r < 16; r++) {
        float acc = 0.f;
#pragma unroll
        for (int k = 0; k < 16; k++) acc = fmaf(sA[r * 16 + k], Wb[k * 256 + j], acc);
        dst[r * 256 + j] = acc;
    }
}

// ---------------------------------------------------------------------------
// rbf basis + rbf_W1 (cbf down-projection)
// ---------------------------------------------------------------------------
__global__ __launch_bounds__(256) void k_rbf(
    const float* __restrict__ D, const float* __restrict__ Wc,
    bf16t* __restrict__ rbf, float* __restrict__ rbfW1)
{
    __shared__ float sW[1792];
    for (int i = threadIdx.x; i < 1792; i += 256) sW[i] = Wc[i];
    __syncthreads();
    int e = blockIdx.x * 256 + threadIdx.x;
    if (e >= EG) return;
    float d = D[e] * (1.0f / 6.0f);
    float d2 = d * d, d4 = d2 * d2, d5 = d4 * d, d6 = d5 * d, d7 = d6 * d;
    float env = 1.0f - 21.0f * d5 + 35.0f * d6 - 15.0f * d7;
    if (d >= 1.0f) env = 0.0f;
    float r[16];
#pragma unroll
    for (int i = 0; i < 16; i++) {
        float t = d - (float)i * (1.0f / 15.0f);
        r[i] = env * __expf(-112.5f * t * t);
    }
#pragma unroll
    for (int j = 0; j < 16; j++) rbf[(size_t)e * 16 + j] = f2bf(r[j]);
    for (int s = 0; s < 7; s++) {
#pragma unroll 4
        for (int i = 0; i < 16; i++) {
            float a = 0.f;
#pragma unroll
            for (int k = 0; k < 16; k++)
                a = fmaf(r[k], sW[(s * 16 + k) * 16 + i], a);
            rbfW1[(size_t)e * 112 + s * 16 + i] = a;
        }
    }
}

// ---------------------------------------------------------------------------
// spherical basis + cbf_t; OUTPUT PERMUTED: cbf[rank[t]] = value(t)
// ---------------------------------------------------------------------------
__global__ __launch_bounds__(256) void k_cbf(
    const float* __restrict__ cosphi, const int* __restrict__ id3_ca,
    const float* __restrict__ rbfW1, const int* __restrict__ rank,
    bf16t* __restrict__ cbf)
{
    int t = blockIdx.x * 256 + threadIdx.x;
    if (t >= TT) return;
    float c = cosphi[t];
    const float norm[7] = {0.28209479177387814f, 0.4886025119029199f, 0.6307831305050401f,
                           0.7463526651802308f, 0.8462843753216345f, 0.935414346693485f,
                           1.0171072362820548f};
    float y[7];
    float pm2 = 1.0f, pm1 = c;
    y[0] = norm[0];
    y[1] = norm[1] * c;
    for (int l = 2; l < 7; l++) {
        float p = ((2.0f * l - 1.0f) * c * pm1 - (l - 1.0f) * pm2) / (float)l;
        y[l] = norm[l] * p;
        pm2 = pm1; pm1 = p;
    }
    int e = id3_ca[t];
    const float* __restrict__ w = rbfW1 + (size_t)e * 112;
    float out[16];
#pragma unroll
    for (int i = 0; i < 16; i++) out[i] = 0.f;
#pragma unroll
    for (int s = 0; s < 7; s++) {
        float ys = y[s];
#pragma unroll
        for (int i = 0; i < 16; i++) out[i] = fmaf(ys, w[s * 16 + i], out[i]);
    }
    int p = rank[t];
#pragma unroll
    for (int i = 0; i < 16; i++) cbf[(size_t)p * 16 + i] = f2bf(out[i]);
}

// ---------------------------------------------------------------------------
__global__ __launch_bounds__(256) void k_hgather(
    const float* __restrict__ emb, const int* __restrict__ Z, bf16t* __restrict__ h)
{
    int i = blockIdx.x * 256 + threadIdx.x;
    if (i < NATOM * 128) {
        int n = i >> 7, j = i & 127;
        h[i] = f2bf(emb[(size_t)Z[n] * 128 + j]);
    }
}

// ---------------------------------------------------------------------------
// mgemm3: LDS-staged MFMA GEMM, 2x2 wave grid, FRxFC frags/wave, prefetch.
// C[M,N](bf16) = epi(A[M,K] @ BT^T), BT = [N][K] bf16.
// EPI 1: ssilu; 2: (skip+ssilu)*inv2
// ---------------------------------------------------------------------------
template <typename TA, int FR, int FC, int EPI>
__global__ __launch_bounds__(256) void mgemm3(
    const TA* __restrict__ A, const bf16t* __restrict__ BT,
    bf16t* __restrict__ C, const bf16t* __restrict__ skip,
    int M, int N, int K)
{
    constexpr int ROWS = 2 * FR * 16;
    constexpr int COLS = 2 * FC * 16;
    __shared__ __align__(16) ushort As[ROWS][40];
    __shared__ __align__(16) ushort Bs[COLS][40];
    const int tid = threadIdx.x, wave = tid >> 6, lane = tid & 63;
    const int waveR = wave >> 1, waveC = wave & 1;
    const int rowBase = blockIdx.y * ROWS, colBase = blockIdx.x * COLS;

    const int sar = tid >> 1, sak = (tid & 1) << 4;
    int agr = rowBase + sar; if (agr >= M) agr = M - 1;
    int sbc, sbk;
    if constexpr (COLS == 128) { sbc = tid >> 1; sbk = (tid & 1) << 4; }
    else                       { sbc = tid >> 2; sbk = (tid & 3) << 3; }

    f32x4 zv = {0.f, 0.f, 0.f, 0.f};
    f32x4 acc[FR][FC];
#pragma unroll
    for (int f = 0; f < FR; f++)
#pragma unroll
        for (int q = 0; q < FC; q++) acc[f][q] = zv;

    const int arow0 = waveR * FR * 16 + (lane & 15);
    const int bcol0 = waveC * FC * 16 + (lane & 15);
    const int kd = (lane >> 4) << 3;

    u16x8 a0, a1, b0, b1;
    auto loadA = [&](int k0) {
        if constexpr (sizeof(TA) == 2) {
            const u16x8* s = (const u16x8*)((const bf16t*)A + (size_t)agr * K + k0 + sak);
            a0 = s[0]; a1 = s[1];
        } else {
            const float4* s = (const float4*)((const float*)A + (size_t)agr * K + k0 + sak);
            a0 = cvt8(s[0], s[1]); a1 = cvt8(s[2], s[3]);
        }
    };
    auto loadB = [&](int k0) {
        const u16x8* s = (const u16x8*)(BT + (size_t)(colBase + sbc) * K + k0 + sbk);
        b0 = s[0];
        if constexpr (COLS == 128) b1 = s[1];
    };
    loadA(0); loadB(0);
    for (int k0 = 0; k0 < K; k0 += 32) {
        __syncthreads();
        *(u16x8*)&As[sar][sak] = a0;
        *(u16x8*)&As[sar][sak + 8] = a1;
        *(u16x8*)&Bs[sbc][sbk] = b0;
        if constexpr (COLS == 128) *(u16x8*)&Bs[sbc][sbk + 8] = b1;
        __syncthreads();
        if (k0 + 32 < K) { loadA(k0 + 32); loadB(k0 + 32); }
        u16x8 af[FR], bf[FC];
#pragma unroll
        for (int f = 0; f < FR; f++) af[f] = *(const u16x8*)&As[arow0 + f * 16][kd];
#pragma unroll
        for (int q = 0; q < FC; q++) bf[q] = *(const u16x8*)&Bs[bcol0 + q * 16][kd];
#pragma unroll
        for (int f = 0; f < FR; f++)
#pragma unroll
            for (int q = 0; q < FC; q++)
                acc[f][q] = __builtin_amdgcn_mfma_f32_16x16x32_bf16(
                    *(s16x8*)&af[f], *(s16x8*)&bf[q], acc[f][q], 0, 0, 0);
    }

    const int rB = rowBase + waveR * FR * 16 + ((lane >> 4) << 2);
    const int cB = colBase + waveC * FC * 16 + (lane & 15);
#pragma unroll
    for (int f = 0; f < FR; f++) {
#pragma unroll
        for (int r = 0; r < 4; r++) {
            int row = rB + f * 16 + r;
            if (row >= M) continue;
#pragma unroll
            for (int q = 0; q < FC; q++) {
                int col = cB + q * 16;
                float v = acc[f][q][r];
                if (EPI == 1) {
                    C[(size_t)row * N + col] = f2bf(ssilu(v));
                } else {
                    float sk = bf2f(skip[(size_t)row * N + col]);
                    C[(size_t)row * N + col] = f2bf((sk + ssilu(v)) * INV_SQRT2f);
                }
            }
        }
    }
}

// ---------------------------------------------------------------------------
// mgemmA1: concat-gather A MFMA GEMM (tile 128x64), prefetch.
// A row r = concat(hA[gS[r]], hA[gT[r]], X[r,:w2]); BT = [N? cols][KP]
// ---------------------------------------------------------------------------
__global__ __launch_bounds__(256) void mgemmA1(
    const bf16t* __restrict__ BT, bf16t* __restrict__ C,
    int M, int N, int K, int KP,
    const bf16t* __restrict__ hA, const int* __restrict__ gS,
    const int* __restrict__ gT, const bf16t* __restrict__ X, int w2)
{
    __shared__ __align__(16) ushort As[128][40];
    __shared__ __align__(16) ushort Bs[64][40];
    const int tid = threadIdx.x, wave = tid >> 6, lane = tid & 63;
    const int waveR = wave >> 1, waveC = wave & 1;
    const int rowBase = blockIdx.y * 128, colBase = blockIdx.x * 64;

    const int sar = tid >> 1, sak = (tid & 1) << 4;
    const int arow = rowBase + sar;
    const int arowC = arow < M ? arow : (M - 1);
    const int ia = gS[arowC], ibx = gT[arowC];
    const int sbc = tid >> 2, sbk = (tid & 3) << 3;

    f32x4 zv = {0.f, 0.f, 0.f, 0.f};
    f32x4 acc[4][2];
#pragma unroll
    for (int f = 0; f < 4; f++)
#pragma unroll
        for (int q = 0; q < 2; q++) acc[f][q] = zv;

    const int arow0 = waveR * 64 + (lane & 15);
    const int bcol0 = waveC * 32 + (lane & 15);
    const int kd = (lane >> 4) << 3;

    u16x8 a0, a1, b0;
    auto loadA = [&](int k0) {
        a0 = u16x8{}; a1 = u16x8{};
        const int kk = k0 + sak;
        if (kk < 128) {
            const u16x8* s = (const u16x8*)(hA + (size_t)ia * 128 + kk);
            a0 = s[0]; a1 = s[1];
        } else if (kk < 256) {
            const u16x8* s = (const u16x8*)(hA + (size_t)ibx * 128 + (kk - 128));
            a0 = s[0]; a1 = s[1];
        } else if (kk < K && kk - 256 < w2) {
            const u16x8* s = (const u16x8*)(X + (size_t)arowC * w2 + (kk - 256));
            a0 = s[0]; a1 = s[1];
        }
    };
    auto loadB = [&](int k0) {
        b0 = *(const u16x8*)(BT + (size_t)(colBase + sbc) * KP + k0 + sbk);
    };
    loadA(0); loadB(0);
    for (int k0 = 0; k0 < K; k0 += 32) {
        __syncthreads();
        *(u16x8*)&As[sar][sak] = a0;
        *(u16x8*)&As[sar][sak + 8] = a1;
        *(u16x8*)&Bs[sbc][sbk] = b0;
        __syncthreads();
        if (k0 + 32 < K) { loadA(k0 + 32); loadB(k0 + 32); }
        u16x8 af[4], bf[2];
#pragma unroll
        for (int f = 0; f < 4; f++) af[f] = *(const u16x8*)&As[arow0 + f * 16][kd];
#pragma unroll
        for (int q = 0; q < 2; q++) bf[q] = *(const u16x8*)&Bs[bcol0 + q * 16][kd];
#pragma unroll
        for (int f = 0; f < 4; f++)
#pragma unroll
            for (int q = 0; q < 2; q++)
                acc[f][q] = __builtin_amdgcn_mfma_f32_16x16x32_bf16(
                    *(s16x8*)&af[f], *(s16x8*)&bf[q], acc[f][q], 0, 0, 0);
    }

    const int rB = rowBase + waveR * 64 + ((lane >> 4) << 2);
    const int cB = colBase + waveC * 32 + (lane & 15);
#pragma unroll
    for (int f = 0; f < 4; f++) {
#pragma unroll
        for (int r = 0; r < 4; r++) {
            int row = rB + f * 16 + r;
            if (row >= M) continue;
#pragma unroll
            for (int q = 0; q < 2; q++)
                C[(size_t)row * N + cB + q * 16] = f2bf(ssilu(acc[f][q][r]));
        }
    }
}

// ---------------------------------------------------------------------------
// fused up-projection: C[r] = (ssilu(A@Wca)[r] + ssilu(A@Wac)[r^1]) * inv2
// A = seg64 (f32, EG x 64), K=64; tile 128x64, N=256 via grid.x=4.
// row^1 swap is register-local (rows 4g..4g+3 in one accumulator group).
// ---------------------------------------------------------------------------
__global__ __launch_bounds__(256) void mgemm_up(
    const float* __restrict__ A, const bf16t* __restrict__ BTca,
    const bf16t* __restrict__ BTac, bf16t* __restrict__ C, int M)
{
    constexpr int K = 64, N = 256;
    __shared__ __align__(16) ushort As[128][40];
    __shared__ __align__(16) ushort Bs[2][64][40];
    const int tid = threadIdx.x, wave = tid >> 6, lane = tid & 63;
    const int waveR = wave >> 1, waveC = wave & 1;
    const int rowBase = blockIdx.y * 128, colBase = blockIdx.x * 64;

    const int sar = tid >> 1, sak = (tid & 1) << 4;
    int agr = rowBase + sar; if (agr >= M) agr = M - 1;
    const int sbc = tid >> 2, sbk = (tid & 3) << 3;

    f32x4 zv = {0.f, 0.f, 0.f, 0.f};
    f32x4 accA[4][2], accB[4][2];
#pragma unroll
    for (int f = 0; f < 4; f++)
#pragma unroll
        for (int q = 0; q < 2; q++) { accA[f][q] = zv; accB[f][q] = zv; }

    const int arow0 = waveR * 64 + (lane & 15);
    const int bcol0 = waveC * 32 + (lane & 15);
    const int kd = (lane >> 4) << 3;

    u16x8 a0, a1, bA, bB;
    auto loadA = [&](int k0) {
        const float4* s = (const float4*)(A + (size_t)agr * K + k0 + sak);
        a0 = cvt8(s[0], s[1]); a1 = cvt8(s[2], s[3]);
    };
    auto loadB = [&](int k0) {
        bA = *(const u16x8*)(BTca + (size_t)(colBase + sbc) * K + k0 + sbk);
        bB = *(const u16x8*)(BTac + (size_t)(colBase + sbc) * K + k0 + sbk);
    };
    loadA(0); loadB(0);
    for (int k0 = 0; k0 < K; k0 += 32) {
        __syncthreads();
        *(u16x8*)&As[sar][sak] = a0;
        *(u16x8*)&As[sar][sak + 8] = a1;
        *(u16x8*)&Bs[0][sbc][sbk] = bA;
        *(u16x8*)&Bs[1][sbc][sbk] = bB;
        __syncthreads();
        if (k0 + 32 < K) { loadA(k0 + 32); loadB(k0 + 32); }
        u16x8 af[4], bfA[2], bfB[2];
#pragma unroll
        for (int f = 0; f < 4; f++) af[f] = *(const u16x8*)&As[arow0 + f * 16][kd];
#pragma unroll
        for (int q = 0; q < 2; q++) {
            bfA[q] = *(const u16x8*)&Bs[0][bcol0 + q * 16][kd];
            bfB[q] = *(const u16x8*)&Bs[1][bcol0 + q * 16][kd];
        }
#pragma unroll
        for (int f = 0; f < 4; f++)
#pragma unroll
            for (int q = 0; q < 2; q++) {
                accA[f][q] = __builtin_amdgcn_mfma_f32_16x16x32_bf16(
                    *(s16x8*)&af[f], *(s16x8*)&bfA[q], accA[f][q], 0, 0, 0);
                accB[f][q] = __builtin_amdgcn_mfma_f32_16x16x32_bf16(
                    *(s16x8*)&af[f], *(s16x8*)&bfB[q], accB[f][q], 0, 0, 0);
            }
    }

    const int rB = rowBase + waveR * 64 + ((lane >> 4) << 2);
    const int cB = colBase + waveC * 32 + (lane & 15);
#pragma unroll
    for (int f = 0; f < 4; f++) {
#pragma unroll
        for (int r = 0; r < 4; r++) {
            int row = rB + f * 16 + r;
            if (row >= M) continue;
#pragma unroll
            for (int q = 0; q < 2; q++) {
                float v = (ssilu(accA[f][q][r]) + ssilu(accB[f][q][r ^ 1])) * INV_SQRT2f;
                C[(size_t)row * N + cB + q * 16] = f2bf(v);
            }
        }
    }
}

// ---------------------------------------------------------------------------
// MFMA bilinear (sorted triplets, chunk-interleaved W, reg prefetch)
// ---------------------------------------------------------------------------
__global__ __launch_bounds__(256) void k_bilinear_m(
    const bf16t* __restrict__ xtrip, const bf16t* __restrict__ cbf,
    const bf16t* __restrict__ WT,
    const int* __restrict__ ba_s, const int* __restrict__ ca_s,
    float* __restrict__ seg)
{
    __shared__ __align__(16) ushort xs[64][72];
    __shared__ ushort cbs[64][16];
    __shared__ int cas[64];
    __shared__ __align__(16) float ts[64][65];
    const int tid = threadIdx.x, wave = tid >> 6, lane = tid & 63;
    const int t0 = blockIdx.x * 64;
    {
        int r = tid >> 2, q = (tid & 3) << 4;
        int ba = ba_s[t0 + r];
        const u16x8* src = (const u16x8*)(xtrip + (size_t)ba * 64 + q);
        *(u16x8*)&xs[r][q] = src[0];
        *(u16x8*)&xs[r][q + 8] = src[1];
    }
    if (tid < 64) cas[tid] = ca_s[t0 + tid];
    {
        int e = tid << 2; int r = e >> 4, c = e & 15;
        *(ushort4*)&cbs[r][c] = *(const ushort4*)(cbf + (size_t)(t0 + r) * 16 + c);
    }
    __syncthreads();
    const int kd = (lane >> 4) << 3;
    u16x8 a0 = *(const u16x8*)(&xs[wave * 16 + (lane & 15)][kd]);
    u16x8 a1 = *(const u16x8*)(&xs[wave * 16 + (lane & 15)][32 + kd]);
    const int rowo = wave * 16 + ((lane >> 4) << 2);
    const int chb = lane >> 4, colw = lane & 15;
    auto waddr = [&](int i, int fc, int half) {
        return WT + (((size_t)(i * 8 + half * 4 + chb) * 64) + colw + fc * 16) * 8;
    };

    float tot[4][4];
#pragma unroll
    for (int a = 0; a < 4; a++)
#pragma unroll
        for (int b = 0; b < 4; b++) tot[a][b] = 0.f;

    u16x8 bw[8], bn[8];
#pragma unroll
    for (int fc = 0; fc < 4; fc++) {
        bw[fc * 2 + 0] = *(const u16x8*)waddr(0, fc, 0);
        bw[fc * 2 + 1] = *(const u16x8*)waddr(0, fc, 1);
    }
    for (int i = 0; i < 16; i++) {
        if (i < 15) {
#pragma unroll
            for (int fc = 0; fc < 4; fc++) {
                bn[fc * 2 + 0] = *(const u16x8*)waddr(i + 1, fc, 0);
                bn[fc * 2 + 1] = *(const u16x8*)waddr(i + 1, fc, 1);
            }
        }
        f32x4 zv = {0.f, 0.f, 0.f, 0.f};
        f32x4 p[4] = {zv, zv, zv, zv};
#pragma unroll
        for (int fc = 0; fc < 4; fc++) {
            p[fc] = __builtin_amdgcn_mfma_f32_16x16x32_bf16(
                *(s16x8*)&a0, *(s16x8*)&bw[fc * 2 + 0], p[fc], 0, 0, 0);
            p[fc] = __builtin_amdgcn_mfma_f32_16x16x32_bf16(
                *(s16x8*)&a1, *(s16x8*)&bw[fc * 2 + 1], p[fc], 0, 0, 0);
        }
#pragma unroll
        for (int r = 0; r < 4; r++) {
            float s = bf2f(cbs[rowo + r][i]);
#pragma unroll
            for (int fc = 0; fc < 4; fc++) tot[fc][r] += s * p[fc][r];
        }
#pragma unroll
        for (int q = 0; q < 8; q++) bw[q] = bn[q];
    }
#pragma unroll
    for (int r = 0; r < 4; r++)
#pragma unroll
        for (int fc = 0; fc < 4; fc++)
            ts[rowo + r][fc * 16 + (lane & 15)] = tot[fc][r];
    __syncthreads();
    {
        int q = tid >> 6, c = tid & 63;
        float s = 0.f;
        int cur = cas[q * 16];
#pragma unroll 1
        for (int r = q * 16; r < q * 16 + 16; r++) {
            int ca = cas[r];
            if (ca != cur) {
                atomicAdd(&seg[(size_t)cur * 64 + c], s);
                s = 0.f; cur = ca;
            }
            s += ts[r][c];
        }
        atomicAdd(&seg[(size_t)cur * 64 + c], s);
    }
}

// ---------------------------------------------------------------------------
// per-edge multiply by (rbf[e,16] @ Wc[16,256]) -> bf16 row
// ---------------------------------------------------------------------------
__global__ __launch_bounds__(256) void k_mulproj(
    const bf16t* __restrict__ in, const bf16t* __restrict__ rvec,
    const float* __restrict__ Wp, bf16t* __restrict__ out)
{
    int e = blockIdx.x;
    int j = threadIdx.x;
    __shared__ float r16[16];
    if (j < 16) r16[j] = bf2f(rvec[(size_t)e * 16 + j]);
    __syncthreads();
    float p = 0.f;
#pragma unroll
    for (int k = 0; k < 16; k++) p = fmaf(r16[k], Wp[k * 256 + j], p);
    out[(size_t)e * 256 + j] = f2bf(bf2f(in[(size_t)e * 256 + j]) * p);
}

// ---------------------------------------------------------------------------
// LN(m row) * (rbf[e,16] @ Wc[16,256]) -> bf16 row
// ---------------------------------------------------------------------------
__global__ __launch_bounds__(256) void k_ln_proj(
    const bf16t* __restrict__ m, const float* __restrict__ lnw,
    const float* __restrict__ lnb, const bf16t* __restrict__ rvec,
    const float* __restrict__ Wp, bf16t* __restrict__ out)
{
    int e = blockIdx.x;
    int j = threadIdx.x;
    __shared__ float red[8];
    __shared__ float r16[16];
    if (j < 16) r16[j] = bf2f(rvec[(size_t)e * 16 + j]);
    float v = bf2f(m[(size_t)e * 256 + j]);
    float s = v, s2 = v * v;
#pragma unroll
    for (int off = 32; off > 0; off >>= 1) {
        s += __shfl_xor(s, off);
        s2 += __shfl_xor(s2, off);
    }
    int wid = j >> 6, lane = j & 63;
    if (lane == 0) { red[wid] = s; red[4 + wid] = s2; }
    __syncthreads();
    float tot = red[0] + red[1] + red[2] + red[3];
    float tot2 = red[4] + red[5] + red[6] + red[7];
    float mu = tot * (1.f / 256.f);
    float var = tot2 * (1.f / 256.f) - mu * mu;
    float ln = (v - mu) * rsqrtf(var + 1e-5f) * lnw[j] + lnb[j];
    float p = 0.f;
#pragma unroll
    for (int k = 0; k < 16; k++) p = fmaf(r16[k], Wp[k * 256 + j], p);
    out[(size_t)e * 256 + j] = f2bf(ln * p);
}

// ---------------------------------------------------------------------------
__global__ __launch_bounds__(128) void k_ln_acc(
    const bf16t* __restrict__ x, const float* __restrict__ w,
    const float* __restrict__ b, float* __restrict__ out)
{
    int n = blockIdx.x;
    int j = threadIdx.x;
    __shared__ float red[4];
    float v = bf2f(x[(size_t)n * 128 + j]);
    float s = v, s2 = v * v;
#pragma unroll
    for (int off = 32; off > 0; off >>= 1) {
        s += __shfl_xor(s, off);
        s2 += __shfl_xor(s2, off);
    }
    int wid = j >> 6, lane = j & 63;
    if (lane == 0) { red[wid] = s; red[2 + wid] = s2; }
    __syncthreads();
    float tot = red[0] + red[1];
    float tot2 = red[2] + red[3];
    float mu = tot * (1.f / 128.f);
    float var = tot2 * (1.f / 128.f) - mu * mu;
    out[(size_t)n * 128 + j] += (v - mu) * rsqrtf(var + 1e-5f) * w[j] + b[j];
}

// ---------------------------------------------------------------------------
template <typename T>
__global__ __launch_bounds__(256) void k_addscale(
    const T* __restrict__ a, const T* __restrict__ b, T* __restrict__ y, int n4)
{
    int i = blockIdx.x * 256 + threadIdx.x;
    if (i < n4) {
        float4 av = VT<T>::load4(a + (size_t)i * 4);
        float4 bv = VT<T>::load4(b + (size_t)i * 4);
        VT<T>::store4(y + (size_t)i * 4,
                      make_float4((av.x + bv.x) * INV_SQRT2f, (av.y + bv.y) * INV_SQRT2f,
                                  (av.z + bv.z) * INV_SQRT2f, (av.w + bv.w) * INV_SQRT2f));
    }
}

// ---------------------------------------------------------------------------
typedef bf16t T;
static bool try_run(void* const* d_in, void* d_out, void* d_ws, size_t ws_size, hipStream_t stream)
{
    const float* D            = (const float*)d_in[0];
    const float* cosphi       = (const float*)d_in[1];
    const float* atom_emb     = (const float*)d_in[2];
    const float* W_rbf3       = (const float*)d_in[3];
    const float* W_rbf_h      = (const float*)d_in[4];
    const float* W_rbf_out    = (const float*)d_in[5];
    const float* W_cbf_down   = (const float*)d_in[6];
    const float* W_edge_emb   = (const float*)d_in[7];
    const float* ib_dense_ca  = (const float*)d_in[8];
    const float* ib_trip_dense_ba = (const float*)d_in[9];
    const float* ib_trip_mlp_rbf  = (const float*)d_in[10];
    const float* ib_trip_down     = (const float*)d_in[11];
    const float* ib_trip_bilinear = (const float*)d_in[12];
    const float* ib_trip_up_ca    = (const float*)d_in[13];
    const float* ib_trip_up_ac    = (const float*)d_in[14];
    const float* ib_res_before    = (const float*)d_in[15];
    const float* ib_res_after     = (const float*)d_in[16];
    const float* ib_atom_dense_rbf = (const float*)d_in[17];
    const float* ib_atom_dense1    = (const float*)d_in[18];
    const float* ib_atom_res       = (const float*)d_in[19];
    const float* ib_concat_dense   = (const float*)d_in[20];
    const float* ib_res_m          = (const float*)d_in[21];
    const float* ob_dense_rbf      = (const float*)d_in[22];
    const float* ob_dense1         = (const float*)d_in[23];
    const float* ob_res            = (const float*)d_in[24];
    const float* ln_m_w            = (const float*)d_in[25];
    const float* ln_m_b            = (const float*)d_in[26];
    const float* ln_E_w            = (const float*)d_in[27];
    const float* ln_E_b            = (const float*)d_in[28];
    const int* Z       = (const int*)d_in[29];
    const int* idx_s   = (const int*)d_in[30];
    const int* idx_t   = (const int*)d_in[31];
    const int* id3_ba  = (const int*)d_in[32];
    const int* id3_ca  = (const int*)d_in[33];

    char* base = (char*)d_ws;
    size_t off = 0;
    auto alloc = [&](size_t bytes) -> char* {
        off = (off + 255) & ~(size_t)255;
        char* p = base + off;
        off += bytes;
        return p;
    };
    T* m      = (T*)alloc((size_t)EG * 256 * 2);
    T* B1     = (T*)alloc((size_t)EG * 256 * 2);
    T* B2     = (T*)alloc((size_t)EG * 256 * 2);
    float* rbfW1 = (float*)B1;                 // alias: dead before B1 first written
    int* rank    = (int*)B2;                   // alias: dead before B2 first written
    T* rbf    = (T*)alloc((size_t)EG * 16 * 2);
    T* cbf    = (T*)alloc((size_t)TT * 16 * 2);
    bf16t* h  = (bf16t*)alloc((size_t)NATOM * 128 * 2);
    T* xtrip  = (T*)alloc((size_t)EG * 64 * 2);
    // union: seg64 f32 (bilinear) | {segN_b, At1b, At2b} bf16 | setup counters
    char* ub  = alloc((size_t)EG * 64 * 4);
    float* seg64  = (float*)ub;
    bf16t* segN_b = (bf16t*)ub;
    bf16t* At1b   = (bf16t*)(ub + (size_t)NATOM * 256 * 2);
    bf16t* At2b   = (bf16t*)(ub + (size_t)NATOM * 256 * 2 + (size_t)NATOM * 128 * 2);
    int* cntT  = (int*)ub;
    int* cnt2T = (int*)(ub + (size_t)EG * 4);
    int* off_ca = (int*)(ub + (size_t)2 * EG * 4);
    float* wcb = (float*)alloc((size_t)7 * 4096 * 4);
    bf16t* ar  = (bf16t*)alloc((size_t)507904 * 2);
    int* off_atom  = (int*)alloc((size_t)(NATOM + 1) * 4);
    int* ba_s      = (int*)alloc((size_t)TT * 4);
    int* ca_s      = (int*)alloc((size_t)TT * 4);
    int* csr_edges = (int*)alloc((size_t)EG * 4);
    if (off > ws_size) return false;
    float* out = (float*)d_out;

    // ---- launch helpers ----
    auto g256 = [&](int epi, const T* A, unsigned wOff, T* C, const T* skip, int K) {
        dim3 grid(2, (EG + 127) / 128);
        if (epi == 1) mgemm3<T, 4, 4, 1><<<grid, 256, 0, stream>>>(A, ar + wOff, C, skip, EG, 256, K);
        else          mgemm3<T, 4, 4, 2><<<grid, 256, 0, stream>>>(A, ar + wOff, C, skip, EG, 256, K);
    };
    auto gatom = [&](int epi, const bf16t* A, unsigned wOff, bf16t* C, const bf16t* skip, int K) {
        dim3 grid(1, (NATOM + 127) / 128);
        if (epi == 1) mgemm3<bf16t, 4, 4, 1><<<grid, 256, 0, stream>>>(A, ar + wOff, C, skip, NATOM, 128, K);
        else          mgemm3<bf16t, 4, 4, 2><<<grid, 256, 0, stream>>>(A, ar + wOff, C, skip, NATOM, 128, K);
    };
    auto out_block = [&](int i, unsigned offD1, unsigned offRes) {
        k_ln_proj<<<EG, 256, 0, stream>>>(m, ln_m_w + (size_t)i * 256, ln_m_b + (size_t)i * 256,
                                          rbf, wcb + (size_t)(4 + i) * 4096, B2);
        k_segsum<<<NATOM, 256, 0, stream>>>(B2, off_atom, csr_edges, segN_b);
        gatom(1, segN_b, offD1, At1b, nullptr, 256);
        for (int r = 0; r < 2; r++) {
            gatom(1, At1b, offRes + (r * 2 + 0) * 16384, At2b, nullptr, 128);
            gatom(2, At2b, offRes + (r * 2 + 1) * 16384, At1b, At1b, 128);
        }
        k_ln_acc<<<NATOM, 128, 0, stream>>>(At1b, ln_E_w + (size_t)i * 128, ln_E_b + (size_t)i * 128, out);
    };

    // ---- sort setup (once) ----
    hipMemsetAsync(cntT, 0, (size_t)EG * 4, stream);
    k_hist<<<(TT + 255) / 256, 256, 0, stream>>>(id3_ca, cntT, TT);
    k_scan<<<1, 1024, 0, stream>>>(cntT, off_ca, EG);
    hipMemsetAsync(cnt2T, 0, (size_t)EG * 4, stream);
    k_rank_trip<<<(TT + 255) / 256, 256, 0, stream>>>(id3_ca, id3_ba, off_ca, cnt2T,
                                                      rank, ba_s, ca_s, TT);
    hipMemsetAsync(cntT, 0, (size_t)NATOM * 4, stream);
    k_hist<<<(EG + 255) / 256, 256, 0, stream>>>(idx_t, cntT, EG);
    k_scan<<<1, 1024, 0, stream>>>(cntT, off_atom, NATOM);
    hipMemsetAsync(cnt2T, 0, (size_t)NATOM * 4, stream);
    k_rank_edge<<<(EG + 255) / 256, 256, 0, stream>>>(idx_t, off_atom, cnt2T, csr_edges, EG);

    // ---- weight combines (all 7, once) ----
    {
        WcBatch wb;
        wb.e[0] = {W_rbf3, ib_trip_mlp_rbf};
        wb.e[1] = {W_rbf3, ib_trip_mlp_rbf + 4096};
        wb.e[2] = {W_rbf_h, ib_atom_dense_rbf};
        wb.e[3] = {W_rbf_h, ib_atom_dense_rbf + 4096};
        wb.e[4] = {W_rbf_out, ob_dense_rbf};
        wb.e[5] = {W_rbf_out, ob_dense_rbf + 4096};
        wb.e[6] = {W_rbf_out, ob_dense_rbf + 8192};
        k_wcomb_batch<<<7, 256, 0, stream>>>(wb, wcb);
    }
    // ---- setup weight batch: edge_emb + out_block(0) ----
    {
        WtBatch wt{};
        wt.e[0] = {W_edge_emb, 0u, 272, 288, 256, 0};
        wt.e[1] = {ob_dense1, 73728u, 256, 256, 128, 0};
        for (int j = 0; j < 4; j++)
            wt.e[2 + j] = {ob_res + (size_t)j * 16384, 106496u + j * 16384u, 128, 128, 128, 0};
        wt.n = 6;
        k_wt_batch<<<512, 256, 0, stream>>>(wt, ar);
    }

    hipMemsetAsync(out, 0, (size_t)NATOM * 128 * 4, stream);
    k_rbf<<<(EG + 255) / 256, 256, 0, stream>>>(D, W_cbf_down, rbf, rbfW1);
    k_cbf<<<(TT + 255) / 256, 256, 0, stream>>>(cosphi, id3_ca, rbfW1, rank, cbf);
    k_hgather<<<(NATOM * 128 + 255) / 256, 256, 0, stream>>>(atom_emb, Z, h);
    {
        dim3 grid(4, (EG + 127) / 128);
        mgemmA1<<<grid, 256, 0, stream>>>(ar, m, EG, 256, 272, 288, h, idx_s, idx_t, rbf, 16);
    }
    out_block(0, 73728u, 106496u);

    for (int i = 0; i < 2; i++) {
        // ---- L1 weight batch ----
        {
            WtBatch wt{};
            wt.e[0] = {ib_dense_ca + (size_t)i * 65536, 0u, 256, 256, 256, 0};
            wt.e[1] = {ib_trip_dense_ba + (size_t)i * 65536, 65536u, 256, 256, 256, 0};
            wt.e[2] = {ib_trip_down + (size_t)i * 16384, 131072u, 256, 256, 64, 0};
            wt.e[3] = {ib_trip_bilinear + (size_t)i * 65536, 147456u, 0, 0, 0, 1};
            wt.e[4] = {ib_trip_up_ca + (size_t)i * 16384, 212992u, 64, 64, 256, 0};
            wt.e[5] = {ib_trip_up_ac + (size_t)i * 16384, 229376u, 64, 64, 256, 0};
            wt.e[6] = {ib_res_before + (size_t)i * 131072, 245760u, 256, 256, 256, 0};
            wt.e[7] = {ib_res_before + (size_t)i * 131072 + 65536, 311296u, 256, 256, 256, 0};
            wt.e[8] = {ib_res_after + (size_t)i * 131072, 376832u, 256, 256, 256, 0};
            wt.e[9] = {ib_res_after + (size_t)i * 131072 + 65536, 442368u, 256, 256, 256, 0};
            wt.n = 10;
            k_wt_batch<<<512, 256, 0, stream>>>(wt, ar);
        }
        // ---- triplet interaction ----
        g256(1, m, 0u, B1, nullptr, 256);        // x_ca_skip
        g256(1, m, 65536u, B2, nullptr, 256);    // x_ba
        k_mulproj<<<EG, 256, 0, stream>>>(B2, rbf, wcb + (size_t)i * 4096, B2);
        {
            dim3 grid(1, (EG + 127) / 128);
            mgemm3<T, 4, 2, 1><<<grid, 256, 0, stream>>>(B2, ar + 131072, xtrip, nullptr, EG, 64, 256);
        }
        hipMemsetAsync(seg64, 0, (size_t)EG * 64 * 4, stream);
        k_bilinear_m<<<TT / 64, 256, 0, stream>>>(xtrip, cbf, ar + 147456, ba_s, ca_s, seg64);
        {
            dim3 grid(4, (EG + 127) / 128);
            mgemm_up<<<grid, 256, 0, stream>>>(seg64, ar + 212992, ar + 229376, B2, EG);
        }
        k_addscale<T><<<(EG * 256 / 4 + 255) / 256, 256, 0, stream>>>(B1, B2, B1, EG * 256 / 4);
        // ---- edge update ----
        g256(1, B1, 245760u, B2, nullptr, 256);
        g256(2, B2, 311296u, B1, B1, 256);
        k_addscale<T><<<(EG * 256 / 4 + 255) / 256, 256, 0, stream>>>(B1, m, B1, EG * 256 / 4);
        g256(1, B1, 376832u, B2, nullptr, 256);
        g256(2, B2, 442368u, B1, B1, 256);
        // ---- L2 weight batch ----
        {
            WtBatch wt{};
            wt.e[0] = {ib_atom_dense1 + (size_t)i * 32768, 0u, 256, 256, 128, 0};
            for (int j = 0; j < 4; j++)
                wt.e[1 + j] = {ib_atom_res + (size_t)i * 65536 + (size_t)j * 16384,
                               32768u + j * 16384u, 128, 128, 128, 0};
            wt.e[5] = {ib_concat_dense + (size_t)i * 131072, 98304u, 512, 512, 256, 0};
            wt.e[6] = {ib_res_m + (size_t)i * 131072, 229376u, 256, 256, 256, 0};
            wt.e[7] = {ib_res_m + (size_t)i * 131072 + 65536, 294912u, 256, 256, 256, 0};
            wt.e[8] = {ob_dense1 + (size_t)(i + 1) * 32768, 360448u, 256, 256, 128, 0};
            for (int j = 0; j < 4; j++)
                wt.e[9 + j] = {ob_res + (size_t)(i + 1) * 65536 + (size_t)j * 16384,
                               393216u + j * 16384u, 128, 128, 128, 0};
            wt.n = 13 <= 12 ? 13 : 12;  // 13 entries won't fit; split below
            wt.n = 9;
            k_wt_batch<<<512, 256, 0, stream>>>(wt, ar);
            WtBatch wt2{};
            wt2.e[0] = {ob_dense1 + (size_t)(i + 1) * 32768, 360448u, 256, 256, 128, 0};
            for (int j = 0; j < 4; j++)
                wt2.e[1 + j] = {ob_res + (size_t)(i + 1) * 65536 + (size_t)j * 16384,
                                393216u + j * 16384u, 128, 128, 128, 0};
            wt2.n = 5;
            k_wt_batch<<<512, 256, 0, stream>>>(wt2, ar);
        }
        // ---- atom update ----
        k_mulproj<<<EG, 256, 0, stream>>>(B1, rbf, wcb + (size_t)(2 + i) * 4096, B2);
        k_segsum<<<NATOM, 256, 0, stream>>>(B2, off_atom, csr_edges, segN_b);
        gatom(1, segN_b, 0u, At1b, nullptr, 256);
        for (int r = 0; r < 2; r++) {
            gatom(1, At1b, 32768u + (r * 2 + 0) * 16384, At2b, nullptr, 128);
            gatom(2, At2b, 32768u + (r * 2 + 1) * 16384, At1b, At1b, 128);
        }
        k_addscale<bf16t><<<(NATOM * 128 / 4 + 255) / 256, 256, 0, stream>>>(h, At1b, h, NATOM * 128 / 4);
        // ---- edge embedding refresh ----
        {
            dim3 grid(4, (EG + 127) / 128);
            mgemmA1<<<grid, 256, 0, stream>>>(ar + 98304, B2, EG, 256, 512, 512, h, idx_s, idx_t, B1, 256);
        }
        g256(1, B2, 229376u, B1, nullptr, 256);
        g256(2, B1, 294912u, B2, B2, 256);
        k_addscale<T><<<(EG * 256 / 4 + 255) / 256, 256, 0, stream>>>(m, B2, m, EG * 256 / 4);

        out_block(i + 1, 360448u, 393216u);
    }
    return true;
}

extern "C" void kernel_launch(void* const* d_in, const int* in_sizes, int n_in,
                              void* d_out, int out_size, void* d_ws, size_t ws_size,
                              hipStream_t stream)
{
    if (try_run(d_in, d_out, d_ws, ws_size, stream)) return;
    float v = 3000.0f + (float)(ws_size >> 20);
    k_fill<<<(NATOM * 128 + 255) / 256, 256, 0, stream>>>((float*)d_out, NATOM * 128, v);
}

// Round 10
// 2698.899 us; speedup vs baseline: 1.7524x; 1.0888x over previous
//
#include <hip/hip_runtime.h>

#define NATOM 10000
#define EG    120000
#define TT    600000

#define INV_SQRT2f 0.7071067811865476f

typedef unsigned short bf16t;
typedef __attribute__((ext_vector_type(8))) short s16x8;
typedef __attribute__((ext_vector_type(8))) unsigned short u16x8;
typedef __attribute__((ext_vector_type(4))) float f32x4;

__device__ __forceinline__ float ssilu(float x) {
    return x * (1.0f / (1.0f + __expf(-x))) * (1.0f / 0.6f);
}
__device__ __forceinline__ float bf2f(unsigned short u) {
    return __uint_as_float(((unsigned)u) << 16);
}
__device__ __forceinline__ unsigned short f2bf(float f) {
    unsigned b = __float_as_uint(f);
    unsigned r = (b + 0x7FFF + ((b >> 16) & 1)) >> 16;  // RNE
    return (unsigned short)r;
}
__device__ __forceinline__ u16x8 cvt8(const float4 va, const float4 vb) {
    u16x8 r{};
    r[0] = f2bf(va.x); r[1] = f2bf(va.y); r[2] = f2bf(va.z); r[3] = f2bf(va.w);
    r[4] = f2bf(vb.x); r[5] = f2bf(vb.y); r[6] = f2bf(vb.z); r[7] = f2bf(vb.w);
    return r;
}

// ---------------------------------------------------------------------------
__global__ __launch_bounds__(256) void k_fill(float* __restrict__ o, int n, float v) {
    int i = blockIdx.x * 256 + threadIdx.x;
    if (i < n) o[i] = v;
}

// ---------------------------------------------------------------------------
// sort infrastructure (built once; indices are launch-constant)
// ---------------------------------------------------------------------------
__global__ __launch_bounds__(256) void k_hist(
    const int* __restrict__ idx, int* __restrict__ cnt, int n)
{
    int i = blockIdx.x * 256 + threadIdx.x;
    if (i < n) atomicAdd(&cnt[idx[i]], 1);
}

__global__ __launch_bounds__(1024) void k_scan(
    const int* __restrict__ cnt, int* __restrict__ off, int n)
{
    __shared__ int wsum[16];
    __shared__ int carrySh;
    if (threadIdx.x == 0) carrySh = 0;
    __syncthreads();
    const int lane = threadIdx.x & 63, wid = threadIdx.x >> 6;
    for (int base = 0; base < n; base += 8192) {
        int v[8]; int s = 0;
        int i0 = base + threadIdx.x * 8;
#pragma unroll
        for (int j = 0; j < 8; j++) { int i = i0 + j; v[j] = (i < n) ? cnt[i] : 0; s += v[j]; }
        int sc = s;
#pragma unroll
        for (int d = 1; d < 64; d <<= 1) { int t = __shfl_up(sc, d); if (lane >= d) sc += t; }
        if (lane == 63) wsum[wid] = sc;
        __syncthreads();
        int wbase = 0;
        for (int w = 0; w < 16; w++) wbase += (w < wid) ? wsum[w] : 0;
        int carry = carrySh;
        int excl = carry + wbase + (sc - s);
#pragma unroll
        for (int j = 0; j < 8; j++) { int i = i0 + j; if (i < n) off[i] = excl; excl += v[j]; }
        __syncthreads();
        if (threadIdx.x == 1023) carrySh = carry + wbase + sc;
        __syncthreads();
    }
    if (threadIdx.x == 0) off[n] = carrySh;
}

__global__ __launch_bounds__(256) void k_rank_trip(
    const int* __restrict__ id3_ca, const int* __restrict__ id3_ba,
    const int* __restrict__ off, int* __restrict__ cnt2,
    int* __restrict__ rank, int* __restrict__ ba_s, int* __restrict__ ca_s, int n)
{
    int t = blockIdx.x * 256 + threadIdx.x;
    if (t >= n) return;
    int ca = id3_ca[t];
    int p = off[ca] + atomicAdd(&cnt2[ca], 1);
    rank[t] = p;
    ba_s[p] = id3_ba[t];
    ca_s[p] = ca;
}

__global__ __launch_bounds__(256) void k_rank_edge(
    const int* __restrict__ idx, const int* __restrict__ off,
    int* __restrict__ cnt2, int* __restrict__ lst, int n)
{
    int i = blockIdx.x * 256 + threadIdx.x;
    if (i >= n) return;
    int a = idx[i];
    int p = off[a] + atomicAdd(&cnt2[a], 1);
    lst[p] = i;
}

// segment sum: out[n][256] (bf16) = sum of X rows (bf16) with target n (CSR)
__global__ __launch_bounds__(256) void k_segsum(
    const bf16t* __restrict__ X, const int* __restrict__ off,
    const int* __restrict__ lst, bf16t* __restrict__ out)
{
    int n = blockIdx.x, j = threadIdx.x;
    int b = off[n], e = off[n + 1];
    float s = 0.f;
    for (int k = b; k < e; k++) s += bf2f(X[(size_t)lst[k] * 256 + j]);
    out[(size_t)n * 256 + j] = f2bf(s);
}

// ---------------------------------------------------------------------------
// batched weight transpose: mode 0 -> BT[n][KP], mode 1 -> bilinear interleave
// ---------------------------------------------------------------------------
struct WtE { const float* src; unsigned dstOff; int K, KP, N, mode; };
struct WtBatch { WtE e[12]; int n; };

__global__ __launch_bounds__(256) void k_wt_batch(WtBatch b, bf16t* __restrict__ base)
{
    for (int i = 0; i < b.n; i++) {
        const WtE E = b.e[i];
        int total = (E.mode == 0) ? E.N * E.KP : 16 * 64 * 64;
        for (int idx = blockIdx.x * 256 + threadIdx.x; idx < total; idx += gridDim.x * 256) {
            bf16t v;
            if (E.mode == 0) {
                int n = idx / E.KP, k = idx - n * E.KP;
                v = (k < E.K) ? f2bf(E.src[(size_t)k * E.N + n]) : (bf16t)0;
            } else {
                int e8 = idx & 7, o = (idx >> 3) & 63, ch = (idx >> 9) & 7, ii = idx >> 12;
                v = f2bf(E.src[((size_t)(ch * 8 + e8) * 16 + ii) * 64 + o]);
            }
            base[E.dstOff + idx] = v;
        }
    }
}

// batched 16x16 @ 16x256 weight combines
struct WcE { const float* Wa; const float* Wb; };
struct WcBatch { WcE e[7]; };

__global__ __launch_bounds__(256) void k_wcomb_batch(WcBatch b, float* __restrict__ wcb)
{
    __shared__ float sA[256];
    int c = blockIdx.x, j = threadIdx.x;
    sA[j] = b.e[c].Wa[j];
    __syncthreads();
    const float* Wb = b.e[c].Wb;
    float* dst = wcb + (size_t)c * 4096;
#pragma unroll 4
    for (int r = 0; r < 16; r++) {
        float acc = 0.f;
#pragma unroll
        for (int k = 0; k < 16; k++) acc = fmaf(sA[r * 16 + k], Wb[k * 256 + j], acc);
        dst[r * 256 + j] = acc;
    }
}

// ---------------------------------------------------------------------------
// rbf basis + rbf_W1 (cbf down-projection)
// ---------------------------------------------------------------------------
__global__ __launch_bounds__(256) void k_rbf(
    const float* __restrict__ D, const float* __restrict__ Wc,
    bf16t* __restrict__ rbf, float* __restrict__ rbfW1)
{
    __shared__ float sW[1792];
    for (int i = threadIdx.x; i < 1792; i += 256) sW[i] = Wc[i];
    __syncthreads();
    int e = blockIdx.x * 256 + threadIdx.x;
    if (e >= EG) return;
    float d = D[e] * (1.0f / 6.0f);
    float d2 = d * d, d4 = d2 * d2, d5 = d4 * d, d6 = d5 * d, d7 = d6 * d;
    float env = 1.0f - 21.0f * d5 + 35.0f * d6 - 15.0f * d7;
    if (d >= 1.0f) env = 0.0f;
    float r[16];
#pragma unroll
    for (int i = 0; i < 16; i++) {
        float t = d - (float)i * (1.0f / 15.0f);
        r[i] = env * __expf(-112.5f * t * t);
    }
#pragma unroll
    for (int j = 0; j < 16; j++) rbf[(size_t)e * 16 + j] = f2bf(r[j]);
    for (int s = 0; s < 7; s++) {
#pragma unroll 4
        for (int i = 0; i < 16; i++) {
            float a = 0.f;
#pragma unroll
            for (int k = 0; k < 16; k++)
                a = fmaf(r[k], sW[(s * 16 + k) * 16 + i], a);
            rbfW1[(size_t)e * 112 + s * 16 + i] = a;
        }
    }
}

// ---------------------------------------------------------------------------
// spherical basis + cbf_t; OUTPUT PERMUTED: cbf[rank[t]] = value(t)
// ---------------------------------------------------------------------------
__global__ __launch_bounds__(256) void k_cbf(
    const float* __restrict__ cosphi, const int* __restrict__ id3_ca,
    const float* __restrict__ rbfW1, const int* __restrict__ rank,
    bf16t* __restrict__ cbf)
{
    int t = blockIdx.x * 256 + threadIdx.x;
    if (t >= TT) return;
    float c = cosphi[t];
    const float norm[7] = {0.28209479177387814f, 0.4886025119029199f, 0.6307831305050401f,
                           0.7463526651802308f, 0.8462843753216345f, 0.935414346693485f,
                           1.0171072362820548f};
    float y[7];
    float pm2 = 1.0f, pm1 = c;
    y[0] = norm[0];
    y[1] = norm[1] * c;
    for (int l = 2; l < 7; l++) {
        float p = ((2.0f * l - 1.0f) * c * pm1 - (l - 1.0f) * pm2) / (float)l;
        y[l] = norm[l] * p;
        pm2 = pm1; pm1 = p;
    }
    int e = id3_ca[t];
    const float* __restrict__ w = rbfW1 + (size_t)e * 112;
    float out[16];
#pragma unroll
    for (int i = 0; i < 16; i++) out[i] = 0.f;
#pragma unroll
    for (int s = 0; s < 7; s++) {
        float ys = y[s];
#pragma unroll
        for (int i = 0; i < 16; i++) out[i] = fmaf(ys, w[s * 16 + i], out[i]);
    }
    int p = rank[t];
#pragma unroll
    for (int i = 0; i < 16; i++) cbf[(size_t)p * 16 + i] = f2bf(out[i]);
}

// ---------------------------------------------------------------------------
__global__ __launch_bounds__(256) void k_hgather(
    const float* __restrict__ emb, const int* __restrict__ Z, bf16t* __restrict__ h)
{
    int i = blockIdx.x * 256 + threadIdx.x;
    if (i < NATOM * 128) {
        int n = i >> 7, j = i & 127;
        h[i] = f2bf(emb[(size_t)Z[n] * 128 + j]);
    }
}

// ---------------------------------------------------------------------------
// mgemm3: LDS-staged MFMA GEMM, 2x2 wave grid, FRxFC frags/wave, prefetch.
// ---------------------------------------------------------------------------
template <typename TA, int FR, int FC, int EPI>
__global__ __launch_bounds__(256) void mgemm3(
    const TA* __restrict__ A, const bf16t* __restrict__ BT,
    bf16t* __restrict__ C, const bf16t* __restrict__ skip,
    int M, int N, int K)
{
    constexpr int ROWS = 2 * FR * 16;
    constexpr int COLS = 2 * FC * 16;
    __shared__ __align__(16) ushort As[ROWS][40];
    __shared__ __align__(16) ushort Bs[COLS][40];
    const int tid = threadIdx.x, wave = tid >> 6, lane = tid & 63;
    const int waveR = wave >> 1, waveC = wave & 1;
    const int rowBase = blockIdx.y * ROWS, colBase = blockIdx.x * COLS;

    const int sar = tid >> 1, sak = (tid & 1) << 4;
    int agr = rowBase + sar; if (agr >= M) agr = M - 1;
    int sbc, sbk;
    if constexpr (COLS == 128) { sbc = tid >> 1; sbk = (tid & 1) << 4; }
    else                       { sbc = tid >> 2; sbk = (tid & 3) << 3; }

    f32x4 zv = {0.f, 0.f, 0.f, 0.f};
    f32x4 acc[FR][FC];
#pragma unroll
    for (int f = 0; f < FR; f++)
#pragma unroll
        for (int q = 0; q < FC; q++) acc[f][q] = zv;

    const int arow0 = waveR * FR * 16 + (lane & 15);
    const int bcol0 = waveC * FC * 16 + (lane & 15);
    const int kd = (lane >> 4) << 3;

    u16x8 a0, a1, b0, b1;
    auto loadA = [&](int k0) {
        if constexpr (sizeof(TA) == 2) {
            const u16x8* s = (const u16x8*)((const bf16t*)A + (size_t)agr * K + k0 + sak);
            a0 = s[0]; a1 = s[1];
        } else {
            const float4* s = (const float4*)((const float*)A + (size_t)agr * K + k0 + sak);
            a0 = cvt8(s[0], s[1]); a1 = cvt8(s[2], s[3]);
        }
    };
    auto loadB = [&](int k0) {
        const u16x8* s = (const u16x8*)(BT + (size_t)(colBase + sbc) * K + k0 + sbk);
        b0 = s[0];
        if constexpr (COLS == 128) b1 = s[1];
    };
    loadA(0); loadB(0);
    for (int k0 = 0; k0 < K; k0 += 32) {
        __syncthreads();
        *(u16x8*)&As[sar][sak] = a0;
        *(u16x8*)&As[sar][sak + 8] = a1;
        *(u16x8*)&Bs[sbc][sbk] = b0;
        if constexpr (COLS == 128) *(u16x8*)&Bs[sbc][sbk + 8] = b1;
        __syncthreads();
        if (k0 + 32 < K) { loadA(k0 + 32); loadB(k0 + 32); }
        u16x8 af[FR], bf[FC];
#pragma unroll
        for (int f = 0; f < FR; f++) af[f] = *(const u16x8*)&As[arow0 + f * 16][kd];
#pragma unroll
        for (int q = 0; q < FC; q++) bf[q] = *(const u16x8*)&Bs[bcol0 + q * 16][kd];
#pragma unroll
        for (int f = 0; f < FR; f++)
#pragma unroll
            for (int q = 0; q < FC; q++)
                acc[f][q] = __builtin_amdgcn_mfma_f32_16x16x32_bf16(
                    *(s16x8*)&af[f], *(s16x8*)&bf[q], acc[f][q], 0, 0, 0);
    }

    const int rB = rowBase + waveR * FR * 16 + ((lane >> 4) << 2);
    const int cB = colBase + waveC * FC * 16 + (lane & 15);
#pragma unroll
    for (int f = 0; f < FR; f++) {
#pragma unroll
        for (int r = 0; r < 4; r++) {
            int row = rB + f * 16 + r;
            if (row >= M) continue;
#pragma unroll
            for (int q = 0; q < FC; q++) {
                int col = cB + q * 16;
                float v = acc[f][q][r];
                if (EPI == 1) {
                    C[(size_t)row * N + col] = f2bf(ssilu(v));
                } else {
                    float sk = bf2f(skip[(size_t)row * N + col]);
                    C[(size_t)row * N + col] = f2bf((sk + ssilu(v)) * INV_SQRT2f);
                }
            }
        }
    }
}

// ---------------------------------------------------------------------------
// mgemm_res: fused residual layer. 64-row tile, N=FCC*32 (256 or 128), K=N.
// Phase1: inter = ssilu(A@BT0^T) -> LDS. Phase2: y = (A + ssilu(inter@BT1^T))/√2.
// EPIOUT 0: C=y.  EPIOUT 1: C=(y+add2)/√2.
// ---------------------------------------------------------------------------
template <int FCC, int EPIOUT>
__global__ __launch_bounds__(256) void mgemm_res(
    const bf16t* __restrict__ A, const bf16t* __restrict__ BT0,
    const bf16t* __restrict__ BT1, bf16t* __restrict__ C,
    const bf16t* __restrict__ add2, int M)
{
    constexpr int N = FCC * 32;
    __shared__ __align__(16) ushort As[64][40];
    __shared__ __align__(16) ushort Bs[N][40];
    __shared__ __align__(16) ushort inter[64][N + 8];
    const int tid = threadIdx.x, wave = tid >> 6, lane = tid & 63;
    const int waveR = wave >> 1, waveC = wave & 1;
    const int rowBase = blockIdx.x * 64;

    const int sar = tid >> 2, sak = (tid & 3) << 3;
    int agr = rowBase + sar; if (agr >= M) agr = M - 1;
    const int sbc = tid >> 2, sbk = (tid & 3) << 3;

    const int arow0 = waveR * 32 + (lane & 15);
    const int bcol0 = waveC * FCC * 16 + (lane & 15);
    const int kd = (lane >> 4) << 3;

    f32x4 zv = {0.f, 0.f, 0.f, 0.f};
    f32x4 acc[2][FCC];
#pragma unroll
    for (int f = 0; f < 2; f++)
#pragma unroll
        for (int q = 0; q < FCC; q++) acc[f][q] = zv;

    u16x8 aR, bR[FCC / 2];
    auto loadA = [&](int k0) {
        aR = *(const u16x8*)(A + (size_t)agr * N + k0 + sak);
    };
    auto loadB = [&](const bf16t* BT, int k0) {
#pragma unroll
        for (int j = 0; j < FCC / 2; j++)
            bR[j] = *(const u16x8*)(BT + (size_t)(sbc + j * 64) * N + k0 + sbk);
    };

    // ---- phase 1 ----
    loadA(0); loadB(BT0, 0);
    for (int k0 = 0; k0 < N; k0 += 32) {
        __syncthreads();
        *(u16x8*)&As[sar][sak] = aR;
#pragma unroll
        for (int j = 0; j < FCC / 2; j++) *(u16x8*)&Bs[sbc + j * 64][sbk] = bR[j];
        __syncthreads();
        if (k0 + 32 < N) { loadA(k0 + 32); loadB(BT0, k0 + 32); }
        else             { loadB(BT1, 0); }
        u16x8 af0 = *(const u16x8*)&As[arow0][kd];
        u16x8 af1 = *(const u16x8*)&As[arow0 + 16][kd];
        u16x8 bf[FCC];
#pragma unroll
        for (int q = 0; q < FCC; q++) bf[q] = *(const u16x8*)&Bs[bcol0 + q * 16][kd];
#pragma unroll
        for (int q = 0; q < FCC; q++) {
            acc[0][q] = __builtin_amdgcn_mfma_f32_16x16x32_bf16(
                *(s16x8*)&af0, *(s16x8*)&bf[q], acc[0][q], 0, 0, 0);
            acc[1][q] = __builtin_amdgcn_mfma_f32_16x16x32_bf16(
                *(s16x8*)&af1, *(s16x8*)&bf[q], acc[1][q], 0, 0, 0);
        }
    }
    // write inter = ssilu(acc)
    {
        const int rL = waveR * 32 + ((lane >> 4) << 2);
        const int cL = waveC * FCC * 16 + (lane & 15);
#pragma unroll
        for (int f = 0; f < 2; f++)
#pragma unroll
            for (int r = 0; r < 4; r++)
#pragma unroll
                for (int q = 0; q < FCC; q++)
                    inter[rL + f * 16 + r][cL + q * 16] = f2bf(ssilu(acc[f][q][r]));
    }
#pragma unroll
    for (int f = 0; f < 2; f++)
#pragma unroll
        for (int q = 0; q < FCC; q++) acc[f][q] = zv;

    // ---- phase 2 ----
    for (int k0 = 0; k0 < N; k0 += 32) {
        __syncthreads();
#pragma unroll
        for (int j = 0; j < FCC / 2; j++) *(u16x8*)&Bs[sbc + j * 64][sbk] = bR[j];
        __syncthreads();
        if (k0 + 32 < N) loadB(BT1, k0 + 32);
        u16x8 af0 = *(const u16x8*)&inter[arow0][k0 + kd];
        u16x8 af1 = *(const u16x8*)&inter[arow0 + 16][k0 + kd];
        u16x8 bf[FCC];
#pragma unroll
        for (int q = 0; q < FCC; q++) bf[q] = *(const u16x8*)&Bs[bcol0 + q * 16][kd];
#pragma unroll
        for (int q = 0; q < FCC; q++) {
            acc[0][q] = __builtin_amdgcn_mfma_f32_16x16x32_bf16(
                *(s16x8*)&af0, *(s16x8*)&bf[q], acc[0][q], 0, 0, 0);
            acc[1][q] = __builtin_amdgcn_mfma_f32_16x16x32_bf16(
                *(s16x8*)&af1, *(s16x8*)&bf[q], acc[1][q], 0, 0, 0);
        }
    }

    // ---- epilogue: y = (A + ssilu(acc))/√2 [; y=(y+add2)/√2] ----
    const int rB = rowBase + waveR * 32 + ((lane >> 4) << 2);
    const int cB = waveC * FCC * 16 + (lane & 15);
#pragma unroll
    for (int f = 0; f < 2; f++) {
#pragma unroll
        for (int r = 0; r < 4; r++) {
            int row = rB + f * 16 + r;
            if (row >= M) continue;
#pragma unroll
            for (int q = 0; q < FCC; q++) {
                int col = cB + q * 16;
                float sk = bf2f(A[(size_t)row * N + col]);
                float y = (sk + ssilu(acc[f][q][r])) * INV_SQRT2f;
                if (EPIOUT == 1) y = (y + bf2f(add2[(size_t)row * N + col])) * INV_SQRT2f;
                C[(size_t)row * N + col] = f2bf(y);
            }
        }
    }
}

// ---------------------------------------------------------------------------
// mgemmA1: concat-gather A MFMA GEMM (tile 128x64), prefetch.
// ---------------------------------------------------------------------------
__global__ __launch_bounds__(256) void mgemmA1(
    const bf16t* __restrict__ BT, bf16t* __restrict__ C,
    int M, int N, int K, int KP,
    const bf16t* __restrict__ hA, const int* __restrict__ gS,
    const int* __restrict__ gT, const bf16t* __restrict__ X, int w2)
{
    __shared__ __align__(16) ushort As[128][40];
    __shared__ __align__(16) ushort Bs[64][40];
    const int tid = threadIdx.x, wave = tid >> 6, lane = tid & 63;
    const int waveR = wave >> 1, waveC = wave & 1;
    const int rowBase = blockIdx.y * 128, colBase = blockIdx.x * 64;

    const int sar = tid >> 1, sak = (tid & 1) << 4;
    const int arow = rowBase + sar;
    const int arowC = arow < M ? arow : (M - 1);
    const int ia = gS[arowC], ibx = gT[arowC];
    const int sbc = tid >> 2, sbk = (tid & 3) << 3;

    f32x4 zv = {0.f, 0.f, 0.f, 0.f};
    f32x4 acc[4][2];
#pragma unroll
    for (int f = 0; f < 4; f++)
#pragma unroll
        for (int q = 0; q < 2; q++) acc[f][q] = zv;

    const int arow0 = waveR * 64 + (lane & 15);
    const int bcol0 = waveC * 32 + (lane & 15);
    const int kd = (lane >> 4) << 3;

    u16x8 a0, a1, b0;
    auto loadA = [&](int k0) {
        a0 = u16x8{}; a1 = u16x8{};
        const int kk = k0 + sak;
        if (kk < 128) {
            const u16x8* s = (const u16x8*)(hA + (size_t)ia * 128 + kk);
            a0 = s[0]; a1 = s[1];
        } else if (kk < 256) {
            const u16x8* s = (const u16x8*)(hA + (size_t)ibx * 128 + (kk - 128));
            a0 = s[0]; a1 = s[1];
        } else if (kk < K && kk - 256 < w2) {
            const u16x8* s = (const u16x8*)(X + (size_t)arowC * w2 + (kk - 256));
            a0 = s[0]; a1 = s[1];
        }
    };
    auto loadB = [&](int k0) {
        b0 = *(const u16x8*)(BT + (size_t)(colBase + sbc) * KP + k0 + sbk);
    };
    loadA(0); loadB(0);
    for (int k0 = 0; k0 < K; k0 += 32) {
        __syncthreads();
        *(u16x8*)&As[sar][sak] = a0;
        *(u16x8*)&As[sar][sak + 8] = a1;
        *(u16x8*)&Bs[sbc][sbk] = b0;
        __syncthreads();
        if (k0 + 32 < K) { loadA(k0 + 32); loadB(k0 + 32); }
        u16x8 af[4], bf[2];
#pragma unroll
        for (int f = 0; f < 4; f++) af[f] = *(const u16x8*)&As[arow0 + f * 16][kd];
#pragma unroll
        for (int q = 0; q < 2; q++) bf[q] = *(const u16x8*)&Bs[bcol0 + q * 16][kd];
#pragma unroll
        for (int f = 0; f < 4; f++)
#pragma unroll
            for (int q = 0; q < 2; q++)
                acc[f][q] = __builtin_amdgcn_mfma_f32_16x16x32_bf16(
                    *(s16x8*)&af[f], *(s16x8*)&bf[q], acc[f][q], 0, 0, 0);
    }

    const int rB = rowBase + waveR * 64 + ((lane >> 4) << 2);
    const int cB = colBase + waveC * 32 + (lane & 15);
#pragma unroll
    for (int f = 0; f < 4; f++) {
#pragma unroll
        for (int r = 0; r < 4; r++) {
            int row = rB + f * 16 + r;
            if (row >= M) continue;
#pragma unroll
            for (int q = 0; q < 2; q++)
                C[(size_t)row * N + cB + q * 16] = f2bf(ssilu(acc[f][q][r]));
        }
    }
}

// ---------------------------------------------------------------------------
// fused up-projection + skip: C[r] = (skip[r] + (ssilu(A@Wca)[r] +
//   ssilu(A@Wac)[r^1])/√2) / √2.  A = seg64 (f32, EG x 64), K=64.
// ---------------------------------------------------------------------------
__global__ __launch_bounds__(256) void mgemm_up(
    const float* __restrict__ A, const bf16t* __restrict__ BTca,
    const bf16t* __restrict__ BTac, bf16t* __restrict__ C,
    const bf16t* __restrict__ skip, int M)
{
    constexpr int K = 64, N = 256;
    __shared__ __align__(16) ushort As[128][40];
    __shared__ __align__(16) ushort Bs[2][64][40];
    const int tid = threadIdx.x, wave = tid >> 6, lane = tid & 63;
    const int waveR = wave >> 1, waveC = wave & 1;
    const int rowBase = blockIdx.y * 128, colBase = blockIdx.x * 64;

    const int sar = tid >> 1, sak = (tid & 1) << 4;
    int agr = rowBase + sar; if (agr >= M) agr = M - 1;
    const int sbc = tid >> 2, sbk = (tid & 3) << 3;

    f32x4 zv = {0.f, 0.f, 0.f, 0.f};
    f32x4 accA[4][2], accB[4][2];
#pragma unroll
    for (int f = 0; f < 4; f++)
#pragma unroll
        for (int q = 0; q < 2; q++) { accA[f][q] = zv; accB[f][q] = zv; }

    const int arow0 = waveR * 64 + (lane & 15);
    const int bcol0 = waveC * 32 + (lane & 15);
    const int kd = (lane >> 4) << 3;

    u16x8 a0, a1, bA, bB;
    auto loadA = [&](int k0) {
        const float4* s = (const float4*)(A + (size_t)agr * K + k0 + sak);
        a0 = cvt8(s[0], s[1]); a1 = cvt8(s[2], s[3]);
    };
    auto loadB = [&](int k0) {
        bA = *(const u16x8*)(BTca + (size_t)(colBase + sbc) * K + k0 + sbk);
        bB = *(const u16x8*)(BTac + (size_t)(colBase + sbc) * K + k0 + sbk);
    };
    loadA(0); loadB(0);
    for (int k0 = 0; k0 < K; k0 += 32) {
        __syncthreads();
        *(u16x8*)&As[sar][sak] = a0;
        *(u16x8*)&As[sar][sak + 8] = a1;
        *(u16x8*)&Bs[0][sbc][sbk] = bA;
        *(u16x8*)&Bs[1][sbc][sbk] = bB;
        __syncthreads();
        if (k0 + 32 < K) { loadA(k0 + 32); loadB(k0 + 32); }
        u16x8 af[4], bfA[2], bfB[2];
#pragma unroll
        for (int f = 0; f < 4; f++) af[f] = *(const u16x8*)&As[arow0 + f * 16][kd];
#pragma unroll
        for (int q = 0; q < 2; q++) {
            bfA[q] = *(const u16x8*)&Bs[0][bcol0 + q * 16][kd];
            bfB[q] = *(const u16x8*)&Bs[1][bcol0 + q * 16][kd];
        }
#pragma unroll
        for (int f = 0; f < 4; f++)
#pragma unroll
            for (int q = 0; q < 2; q++) {
                accA[f][q] = __builtin_amdgcn_mfma_f32_16x16x32_bf16(
                    *(s16x8*)&af[f], *(s16x8*)&bfA[q], accA[f][q], 0, 0, 0);
                accB[f][q] = __builtin_amdgcn_mfma_f32_16x16x32_bf16(
                    *(s16x8*)&af[f], *(s16x8*)&bfB[q], accB[f][q], 0, 0, 0);
            }
    }

    const int rB = rowBase + waveR * 64 + ((lane >> 4) << 2);
    const int cB = colBase + waveC * 32 + (lane & 15);
#pragma unroll
    for (int f = 0; f < 4; f++) {
#pragma unroll
        for (int r = 0; r < 4; r++) {
            int row = rB + f * 16 + r;
            if (row >= M) continue;
#pragma unroll
            for (int q = 0; q < 2; q++) {
                int col = cB + q * 16;
                float v = (ssilu(accA[f][q][r]) + ssilu(accB[f][q][r ^ 1])) * INV_SQRT2f;
                float y = (bf2f(skip[(size_t)row * N + col]) + v) * INV_SQRT2f;
                C[(size_t)row * N + col] = f2bf(y);
            }
        }
    }
}

// ---------------------------------------------------------------------------
// MFMA bilinear (sorted triplets, chunk-interleaved W, reg prefetch)
// ---------------------------------------------------------------------------
__global__ __launch_bounds__(256) void k_bilinear_m(
    const bf16t* __restrict__ xtrip, const bf16t* __restrict__ cbf,
    const bf16t* __restrict__ WT,
    const int* __restrict__ ba_s, const int* __restrict__ ca_s,
    float* __restrict__ seg)
{
    __shared__ __align__(16) ushort xs[64][72];
    __shared__ ushort cbs[64][16];
    __shared__ int cas[64];
    __shared__ __align__(16) float ts[64][65];
    const int tid = threadIdx.x, wave = tid >> 6, lane = tid & 63;
    const int t0 = blockIdx.x * 64;
    {
        int r = tid >> 2, q = (tid & 3) << 4;
        int ba = ba_s[t0 + r];
        const u16x8* src = (const u16x8*)(xtrip + (size_t)ba * 64 + q);
        *(u16x8*)&xs[r][q] = src[0];
        *(u16x8*)&xs[r][q + 8] = src[1];
    }
    if (tid < 64) cas[tid] = ca_s[t0 + tid];
    {
        int e = tid << 2; int r = e >> 4, c = e & 15;
        *(ushort4*)&cbs[r][c] = *(const ushort4*)(cbf + (size_t)(t0 + r) * 16 + c);
    }
    __syncthreads();
    const int kd = (lane >> 4) << 3;
    u16x8 a0 = *(const u16x8*)(&xs[wave * 16 + (lane & 15)][kd]);
    u16x8 a1 = *(const u16x8*)(&xs[wave * 16 + (lane & 15)][32 + kd]);
    const int rowo = wave * 16 + ((lane >> 4) << 2);
    const int chb = lane >> 4, colw = lane & 15;
    auto waddr = [&](int i, int fc, int half) {
        return WT + (((size_t)(i * 8 + half * 4 + chb) * 64) + colw + fc * 16) * 8;
    };

    float tot[4][4];
#pragma unroll
    for (int a = 0; a < 4; a++)
#pragma unroll
        for (int b = 0; b < 4; b++) tot[a][b] = 0.f;

    u16x8 bw[8], bn[8];
#pragma unroll
    for (int fc = 0; fc < 4; fc++) {
        bw[fc * 2 + 0] = *(const u16x8*)waddr(0, fc, 0);
        bw[fc * 2 + 1] = *(const u16x8*)waddr(0, fc, 1);
    }
    for (int i = 0; i < 16; i++) {
        if (i < 15) {
#pragma unroll
            for (int fc = 0; fc < 4; fc++) {
                bn[fc * 2 + 0] = *(const u16x8*)waddr(i + 1, fc, 0);
                bn[fc * 2 + 1] = *(const u16x8*)waddr(i + 1, fc, 1);
            }
        }
        f32x4 zv = {0.f, 0.f, 0.f, 0.f};
        f32x4 p[4] = {zv, zv, zv, zv};
#pragma unroll
        for (int fc = 0; fc < 4; fc++) {
            p[fc] = __builtin_amdgcn_mfma_f32_16x16x32_bf16(
                *(s16x8*)&a0, *(s16x8*)&bw[fc * 2 + 0], p[fc], 0, 0, 0);
            p[fc] = __builtin_amdgcn_mfma_f32_16x16x32_bf16(
                *(s16x8*)&a1, *(s16x8*)&bw[fc * 2 + 1], p[fc], 0, 0, 0);
        }
#pragma unroll
        for (int r = 0; r < 4; r++) {
            float s = bf2f(cbs[rowo + r][i]);
#pragma unroll
            for (int fc = 0; fc < 4; fc++) tot[fc][r] += s * p[fc][r];
        }
#pragma unroll
        for (int q = 0; q < 8; q++) bw[q] = bn[q];
    }
#pragma unroll
    for (int r = 0; r < 4; r++)
#pragma unroll
        for (int fc = 0; fc < 4; fc++)
            ts[rowo + r][fc * 16 + (lane & 15)] = tot[fc][r];
    __syncthreads();
    {
        int q = tid >> 6, c = tid & 63;
        float s = 0.f;
        int cur = cas[q * 16];
#pragma unroll 1
        for (int r = q * 16; r < q * 16 + 16; r++) {
            int ca = cas[r];
            if (ca != cur) {
                atomicAdd(&seg[(size_t)cur * 64 + c], s);
                s = 0.f; cur = ca;
            }
            s += ts[r][c];
        }
        atomicAdd(&seg[(size_t)cur * 64 + c], s);
    }
}

// ---------------------------------------------------------------------------
// per-edge multiply by (rbf[e,16] @ Wc[16,256]) -> bf16 row
// ---------------------------------------------------------------------------
__global__ __launch_bounds__(256) void k_mulproj(
    const bf16t* __restrict__ in, const bf16t* __restrict__ rvec,
    const float* __restrict__ Wp, bf16t* __restrict__ out)
{
    int e = blockIdx.x;
    int j = threadIdx.x;
    __shared__ float r16[16];
    if (j < 16) r16[j] = bf2f(rvec[(size_t)e * 16 + j]);
    __syncthreads();
    float p = 0.f;
#pragma unroll
    for (int k = 0; k < 16; k++) p = fmaf(r16[k], Wp[k * 256 + j], p);
    out[(size_t)e * 256 + j] = f2bf(bf2f(in[(size_t)e * 256 + j]) * p);
}

// ---------------------------------------------------------------------------
// LN(m row) * (rbf[e,16] @ Wc[16,256]) -> bf16 row
// ---------------------------------------------------------------------------
__global__ __launch_bounds__(256) void k_ln_proj(
    const bf16t* __restrict__ m, const float* __restrict__ lnw,
    const float* __restrict__ lnb, const bf16t* __restrict__ rvec,
    const float* __restrict__ Wp, bf16t* __restrict__ out)
{
    int e = blockIdx.x;
    int j = threadIdx.x;
    __shared__ float red[8];
    __shared__ float r16[16];
    if (j < 16) r16[j] = bf2f(rvec[(size_t)e * 16 + j]);
    float v = bf2f(m[(size_t)e * 256 + j]);
    float s = v, s2 = v * v;
#pragma unroll
    for (int off = 32; off > 0; off >>= 1) {
        s += __shfl_xor(s, off);
        s2 += __shfl_xor(s2, off);
    }
    int wid = j >> 6, lane = j & 63;
    if (lane == 0) { red[wid] = s; red[4 + wid] = s2; }
    __syncthreads();
    float tot = red[0] + red[1] + red[2] + red[3];
    float tot2 = red[4] + red[5] + red[6] + red[7];
    float mu = tot * (1.f / 256.f);
    float var = tot2 * (1.f / 256.f) - mu * mu;
    float ln = (v - mu) * rsqrtf(var + 1e-5f) * lnw[j] + lnb[j];
    float p = 0.f;
#pragma unroll
    for (int k = 0; k < 16; k++) p = fmaf(r16[k], Wp[k * 256 + j], p);
    out[(size_t)e * 256 + j] = f2bf(ln * p);
}

// ---------------------------------------------------------------------------
__global__ __launch_bounds__(128) void k_ln_acc(
    const bf16t* __restrict__ x, const float* __restrict__ w,
    const float* __restrict__ b, float* __restrict__ out)
{
    int n = blockIdx.x;
    int j = threadIdx.x;
    __shared__ float red[4];
    float v = bf2f(x[(size_t)n * 128 + j]);
    float s = v, s2 = v * v;
#pragma unroll
    for (int off = 32; off > 0; off >>= 1) {
        s += __shfl_xor(s, off);
        s2 += __shfl_xor(s2, off);
    }
    int wid = j >> 6, lane = j & 63;
    if (lane == 0) { red[wid] = s; red[2 + wid] = s2; }
    __syncthreads();
    float tot = red[0] + red[1];
    float tot2 = red[2] + red[3];
    float mu = tot * (1.f / 128.f);
    float var = tot2 * (1.f / 128.f) - mu * mu;
    out[(size_t)n * 128 + j] += (v - mu) * rsqrtf(var + 1e-5f) * w[j] + b[j];
}

// ---------------------------------------------------------------------------
typedef bf16t T;
static bool try_run(void* const* d_in, void* d_out, void* d_ws, size_t ws_size, hipStream_t stream)
{
    const float* D            = (const float*)d_in[0];
    const float* cosphi       = (const float*)d_in[1];
    const float* atom_emb     = (const float*)d_in[2];
    const float* W_rbf3       = (const float*)d_in[3];
    const float* W_rbf_h      = (const float*)d_in[4];
    const float* W_rbf_out    = (const float*)d_in[5];
    const float* W_cbf_down   = (const float*)d_in[6];
    const float* W_edge_emb   = (const float*)d_in[7];
    const float* ib_dense_ca  = (const float*)d_in[8];
    const float* ib_trip_dense_ba = (const float*)d_in[9];
    const float* ib_trip_mlp_rbf  = (const float*)d_in[10];
    const float* ib_trip_down     = (const float*)d_in[11];
    const float* ib_trip_bilinear = (const float*)d_in[12];
    const float* ib_trip_up_ca    = (const float*)d_in[13];
    const float* ib_trip_up_ac    = (const float*)d_in[14];
    const float* ib_res_before    = (const float*)d_in[15];
    const float* ib_res_after     = (const float*)d_in[16];
    const float* ib_atom_dense_rbf = (const float*)d_in[17];
    const float* ib_atom_dense1    = (const float*)d_in[18];
    const float* ib_atom_res       = (const float*)d_in[19];
    const float* ib_concat_dense   = (const float*)d_in[20];
    const float* ib_res_m          = (const float*)d_in[21];
    const float* ob_dense_rbf      = (const float*)d_in[22];
    const float* ob_dense1         = (const float*)d_in[23];
    const float* ob_res            = (const float*)d_in[24];
    const float* ln_m_w            = (const float*)d_in[25];
    const float* ln_m_b            = (const float*)d_in[26];
    const float* ln_E_w            = (const float*)d_in[27];
    const float* ln_E_b            = (const float*)d_in[28];
    const int* Z       = (const int*)d_in[29];
    const int* idx_s   = (const int*)d_in[30];
    const int* idx_t   = (const int*)d_in[31];
    const int* id3_ba  = (const int*)d_in[32];
    const int* id3_ca  = (const int*)d_in[33];

    char* base = (char*)d_ws;
    size_t off = 0;
    auto alloc = [&](size_t bytes) -> char* {
        off = (off + 255) & ~(size_t)255;
        char* p = base + off;
        off += bytes;
        return p;
    };
    T* m      = (T*)alloc((size_t)EG * 256 * 2);
    T* B1     = (T*)alloc((size_t)EG * 256 * 2);
    T* B2     = (T*)alloc((size_t)EG * 256 * 2);
    float* rbfW1 = (float*)B1;                 // alias: dead before B1 first written
    int* rank    = (int*)B2;                   // alias: dead before B2 first written
    T* rbf    = (T*)alloc((size_t)EG * 16 * 2);
    T* cbf    = (T*)alloc((size_t)TT * 16 * 2);
    bf16t* h  = (bf16t*)alloc((size_t)NATOM * 128 * 2);
    T* xtrip  = (T*)alloc((size_t)EG * 64 * 2);
    // union: seg64 f32 (bilinear) | {segN_b, At1b} bf16 | setup counters
    char* ub  = alloc((size_t)EG * 64 * 4);
    float* seg64  = (float*)ub;
    bf16t* segN_b = (bf16t*)ub;
    bf16t* At1b   = (bf16t*)(ub + (size_t)NATOM * 256 * 2);
    int* cntT  = (int*)ub;
    int* cnt2T = (int*)(ub + (size_t)EG * 4);
    int* off_ca = (int*)(ub + (size_t)2 * EG * 4);
    float* wcb = (float*)alloc((size_t)7 * 4096 * 4);
    bf16t* ar  = (bf16t*)alloc((size_t)507904 * 2);
    int* off_atom  = (int*)alloc((size_t)(NATOM + 1) * 4);
    int* ba_s      = (int*)alloc((size_t)TT * 4);
    int* ca_s      = (int*)alloc((size_t)TT * 4);
    int* csr_edges = (int*)alloc((size_t)EG * 4);
    if (off > ws_size) return false;
    float* out = (float*)d_out;

    // ---- launch helpers ----
    auto g256 = [&](const T* A, unsigned wOff, T* C) {
        dim3 grid(2, (EG + 127) / 128);
        mgemm3<T, 4, 4, 1><<<grid, 256, 0, stream>>>(A, ar + wOff, C, nullptr, EG, 256, 256);
    };
    auto gatom1 = [&](const bf16t* A, unsigned wOff, bf16t* C) {
        dim3 grid(1, (NATOM + 127) / 128);
        mgemm3<bf16t, 4, 4, 1><<<grid, 256, 0, stream>>>(A, ar + wOff, C, nullptr, NATOM, 128, 256);
    };
    auto out_block = [&](int i, unsigned offD1, unsigned offRes) {
        k_ln_proj<<<EG, 256, 0, stream>>>(m, ln_m_w + (size_t)i * 256, ln_m_b + (size_t)i * 256,
                                          rbf, wcb + (size_t)(4 + i) * 4096, B2);
        k_segsum<<<NATOM, 256, 0, stream>>>(B2, off_atom, csr_edges, segN_b);
        gatom1(segN_b, offD1, At1b);
        mgemm_res<4, 0><<<(NATOM + 63) / 64, 256, 0, stream>>>(
            At1b, ar + offRes, ar + offRes + 16384, At1b, nullptr, NATOM);
        mgemm_res<4, 0><<<(NATOM + 63) / 64, 256, 0, stream>>>(
            At1b, ar + offRes + 32768, ar + offRes + 49152, At1b, nullptr, NATOM);
        k_ln_acc<<<NATOM, 128, 0, stream>>>(At1b, ln_E_w + (size_t)i * 128, ln_E_b + (size_t)i * 128, out);
    };

    // ---- sort setup (once) ----
    hipMemsetAsync(cntT, 0, (size_t)EG * 4, stream);
    k_hist<<<(TT + 255) / 256, 256, 0, stream>>>(id3_ca, cntT, TT);
    k_scan<<<1, 1024, 0, stream>>>(cntT, off_ca, EG);
    hipMemsetAsync(cnt2T, 0, (size_t)EG * 4, stream);
    k_rank_trip<<<(TT + 255) / 256, 256, 0, stream>>>(id3_ca, id3_ba, off_ca, cnt2T,
                                                      rank, ba_s, ca_s, TT);
    hipMemsetAsync(cntT, 0, (size_t)NATOM * 4, stream);
    k_hist<<<(EG + 255) / 256, 256, 0, stream>>>(idx_t, cntT, EG);
    k_scan<<<1, 1024, 0, stream>>>(cntT, off_atom, NATOM);
    hipMemsetAsync(cnt2T, 0, (size_t)NATOM * 4, stream);
    k_rank_edge<<<(EG + 255) / 256, 256, 0, stream>>>(idx_t, off_atom, cnt2T, csr_edges, EG);

    // ---- weight combines (all 7, once) ----
    {
        WcBatch wb;
        wb.e[0] = {W_rbf3, ib_trip_mlp_rbf};
        wb.e[1] = {W_rbf3, ib_trip_mlp_rbf + 4096};
        wb.e[2] = {W_rbf_h, ib_atom_dense_rbf};
        wb.e[3] = {W_rbf_h, ib_atom_dense_rbf + 4096};
        wb.e[4] = {W_rbf_out, ob_dense_rbf};
        wb.e[5] = {W_rbf_out, ob_dense_rbf + 4096};
        wb.e[6] = {W_rbf_out, ob_dense_rbf + 8192};
        k_wcomb_batch<<<7, 256, 0, stream>>>(wb, wcb);
    }
    // ---- setup weight batch: edge_emb + out_block(0) ----
    {
        WtBatch wt{};
        wt.e[0] = {W_edge_emb, 0u, 272, 288, 256, 0};
        wt.e[1] = {ob_dense1, 73728u, 256, 256, 128, 0};
        for (int j = 0; j < 4; j++)
            wt.e[2 + j] = {ob_res + (size_t)j * 16384, 106496u + j * 16384u, 128, 128, 128, 0};
        wt.n = 6;
        k_wt_batch<<<512, 256, 0, stream>>>(wt, ar);
    }

    hipMemsetAsync(out, 0, (size_t)NATOM * 128 * 4, stream);
    k_rbf<<<(EG + 255) / 256, 256, 0, stream>>>(D, W_cbf_down, rbf, rbfW1);
    k_cbf<<<(TT + 255) / 256, 256, 0, stream>>>(cosphi, id3_ca, rbfW1, rank, cbf);
    k_hgather<<<(NATOM * 128 + 255) / 256, 256, 0, stream>>>(atom_emb, Z, h);
    {
        dim3 grid(4, (EG + 127) / 128);
        mgemmA1<<<grid, 256, 0, stream>>>(ar, m, EG, 256, 272, 288, h, idx_s, idx_t, rbf, 16);
    }
    out_block(0, 73728u, 106496u);

    for (int i = 0; i < 2; i++) {
        // ---- L1 weight batch ----
        {
            WtBatch wt{};
            wt.e[0] = {ib_dense_ca + (size_t)i * 65536, 0u, 256, 256, 256, 0};
            wt.e[1] = {ib_trip_dense_ba + (size_t)i * 65536, 65536u, 256, 256, 256, 0};
            wt.e[2] = {ib_trip_down + (size_t)i * 16384, 131072u, 256, 256, 64, 0};
            wt.e[3] = {ib_trip_bilinear + (size_t)i * 65536, 147456u, 0, 0, 0, 1};
            wt.e[4] = {ib_trip_up_ca + (size_t)i * 16384, 212992u, 64, 64, 256, 0};
            wt.e[5] = {ib_trip_up_ac + (size_t)i * 16384, 229376u, 64, 64, 256, 0};
            wt.e[6] = {ib_res_before + (size_t)i * 131072, 245760u, 256, 256, 256, 0};
            wt.e[7] = {ib_res_before + (size_t)i * 131072 + 65536, 311296u, 256, 256, 256, 0};
            wt.e[8] = {ib_res_after + (size_t)i * 131072, 376832u, 256, 256, 256, 0};
            wt.e[9] = {ib_res_after + (size_t)i * 131072 + 65536, 442368u, 256, 256, 256, 0};
            wt.n = 10;
            k_wt_batch<<<512, 256, 0, stream>>>(wt, ar);
        }
        // ---- triplet interaction ----
        g256(m, 0u, B1);        // x_ca_skip
        g256(m, 65536u, B2);    // x_ba
        k_mulproj<<<EG, 256, 0, stream>>>(B2, rbf, wcb + (size_t)i * 4096, B2);
        {
            dim3 grid(1, (EG + 127) / 128);
            mgemm3<T, 4, 2, 1><<<grid, 256, 0, stream>>>(B2, ar + 131072, xtrip, nullptr, EG, 64, 256);
        }
        hipMemsetAsync(seg64, 0, (size_t)EG * 64 * 4, stream);
        k_bilinear_m<<<TT / 64, 256, 0, stream>>>(xtrip, cbf, ar + 147456, ba_s, ca_s, seg64);
        {
            // B1 = (x_ca_skip + x3)/√2, fused skip
            dim3 grid(4, (EG + 127) / 128);
            mgemm_up<<<grid, 256, 0, stream>>>(seg64, ar + 212992, ar + 229376, B1, B1, EG);
        }
        // ---- edge update: res_before (+m add), res_after ----
        mgemm_res<8, 1><<<EG / 64, 256, 0, stream>>>(B1, ar + 245760, ar + 311296, B1, m, EG);
        mgemm_res<8, 0><<<EG / 64, 256, 0, stream>>>(B1, ar + 376832, ar + 442368, B1, nullptr, EG);
        // ---- L2 weight batch ----
        {
            WtBatch wt{};
            wt.e[0] = {ib_atom_dense1 + (size_t)i * 32768, 0u, 256, 256, 128, 0};
            for (int j = 0; j < 4; j++)
                wt.e[1 + j] = {ib_atom_res + (size_t)i * 65536 + (size_t)j * 16384,
                               32768u + j * 16384u, 128, 128, 128, 0};
            wt.e[5] = {ib_concat_dense + (size_t)i * 131072, 98304u, 512, 512, 256, 0};
            wt.e[6] = {ib_res_m + (size_t)i * 131072, 229376u, 256, 256, 256, 0};
            wt.e[7] = {ib_res_m + (size_t)i * 131072 + 65536, 294912u, 256, 256, 256, 0};
            wt.e[8] = {ob_dense1 + (size_t)(i + 1) * 32768, 360448u, 256, 256, 128, 0};
            wt.n = 9;
            k_wt_batch<<<512, 256, 0, stream>>>(wt, ar);
            WtBatch wt2{};
            for (int j = 0; j < 4; j++)
                wt2.e[j] = {ob_res + (size_t)(i + 1) * 65536 + (size_t)j * 16384,
                            393216u + j * 16384u, 128, 128, 128, 0};
            wt2.n = 4;
            k_wt_batch<<<512, 256, 0, stream>>>(wt2, ar);
        }
        // ---- atom update ----
        k_mulproj<<<EG, 256, 0, stream>>>(B1, rbf, wcb + (size_t)(2 + i) * 4096, B2);
        k_segsum<<<NATOM, 256, 0, stream>>>(B2, off_atom, csr_edges, segN_b);
        gatom1(segN_b, 0u, At1b);
        mgemm_res<4, 0><<<(NATOM + 63) / 64, 256, 0, stream>>>(
            At1b, ar + 32768, ar + 49152, At1b, nullptr, NATOM);
        mgemm_res<4, 1><<<(NATOM + 63) / 64, 256, 0, stream>>>(
            At1b, ar + 65536, ar + 81920, h, h, NATOM);   // h = (h + xa)/√2
        // ---- edge embedding refresh ----
        {
            dim3 grid(4, (EG + 127) / 128);
            mgemmA1<<<grid, 256, 0, stream>>>(ar + 98304, B2, EG, 256, 512, 512, h, idx_s, idx_t, B1, 256);
        }
        // res_m residual + m update: m = (m + residual(B2))/√2
        mgemm_res<8, 1><<<EG / 64, 256, 0, stream>>>(B2, ar + 229376, ar + 294912, m, m, EG);

        out_block(i + 1, 360448u, 393216u);
    }
    return true;
}

extern "C" void kernel_launch(void* const* d_in, const int* in_sizes, int n_in,
                              void* d_out, int out_size, void* d_ws, size_t ws_size,
                              hipStream_t stream)
{
    if (try_run(d_in, d_out, d_ws, ws_size, stream)) return;
    float v = 3000.0f + (float)(ws_size >> 20);
    k_fill<<<(NATOM * 128 + 255) / 256, 256, 0, stream>>>((float*)d_out, NATOM * 128, v);
}

// Round 11
// 2638.929 us; speedup vs baseline: 1.7922x; 1.0227x over previous
//
#include <hip/hip_runtime.h>

#define NATOM 10000
#define EG    120000
#define TT    600000

#define INV_SQRT2f 0.7071067811865476f

typedef unsigned short bf16t;
typedef __attribute__((ext_vector_type(8))) short s16x8;
typedef __attribute__((ext_vector_type(8))) unsigned short u16x8;
typedef __attribute__((ext_vector_type(4))) float f32x4;

__device__ __forceinline__ float ssilu(float x) {
    return x * (1.0f / (1.0f + __expf(-x))) * (1.0f / 0.6f);
}
__device__ __forceinline__ float bf2f(unsigned short u) {
    return __uint_as_float(((unsigned)u) << 16);
}
__device__ __forceinline__ unsigned short f2bf(float f) {
    unsigned b = __float_as_uint(f);
    unsigned r = (b + 0x7FFF + ((b >> 16) & 1)) >> 16;  // RNE
    return (unsigned short)r;
}
__device__ __forceinline__ u16x8 cvt8(const float4 va, const float4 vb) {
    u16x8 r{};
    r[0] = f2bf(va.x); r[1] = f2bf(va.y); r[2] = f2bf(va.z); r[3] = f2bf(va.w);
    r[4] = f2bf(vb.x); r[5] = f2bf(vb.y); r[6] = f2bf(vb.z); r[7] = f2bf(vb.w);
    return r;
}

// ---------------------------------------------------------------------------
__global__ __launch_bounds__(256) void k_fill(float* __restrict__ o, int n, float v) {
    int i = blockIdx.x * 256 + threadIdx.x;
    if (i < n) o[i] = v;
}

// ---------------------------------------------------------------------------
// sort infrastructure (built once; indices are launch-constant)
// ---------------------------------------------------------------------------
__global__ __launch_bounds__(256) void k_hist(
    const int* __restrict__ idx, int* __restrict__ cnt, int n)
{
    int i = blockIdx.x * 256 + threadIdx.x;
    if (i < n) atomicAdd(&cnt[idx[i]], 1);
}

__global__ __launch_bounds__(1024) void k_scan(
    const int* __restrict__ cnt, int* __restrict__ off, int n)
{
    __shared__ int wsum[16];
    __shared__ int carrySh;
    if (threadIdx.x == 0) carrySh = 0;
    __syncthreads();
    const int lane = threadIdx.x & 63, wid = threadIdx.x >> 6;
    for (int base = 0; base < n; base += 8192) {
        int v[8]; int s = 0;
        int i0 = base + threadIdx.x * 8;
#pragma unroll
        for (int j = 0; j < 8; j++) { int i = i0 + j; v[j] = (i < n) ? cnt[i] : 0; s += v[j]; }
        int sc = s;
#pragma unroll
        for (int d = 1; d < 64; d <<= 1) { int t = __shfl_up(sc, d); if (lane >= d) sc += t; }
        if (lane == 63) wsum[wid] = sc;
        __syncthreads();
        int wbase = 0;
        for (int w = 0; w < 16; w++) wbase += (w < wid) ? wsum[w] : 0;
        int carry = carrySh;
        int excl = carry + wbase + (sc - s);
#pragma unroll
        for (int j = 0; j < 8; j++) { int i = i0 + j; if (i < n) off[i] = excl; excl += v[j]; }
        __syncthreads();
        if (threadIdx.x == 1023) carrySh = carry + wbase + sc;
        __syncthreads();
    }
    if (threadIdx.x == 0) off[n] = carrySh;
}

__global__ __launch_bounds__(256) void k_rank_trip(
    const int* __restrict__ id3_ca, const int* __restrict__ id3_ba,
    const int* __restrict__ off, int* __restrict__ cnt2,
    int* __restrict__ rank, int* __restrict__ ba_s, int* __restrict__ ca_s, int n)
{
    int t = blockIdx.x * 256 + threadIdx.x;
    if (t >= n) return;
    int ca = id3_ca[t];
    int p = off[ca] + atomicAdd(&cnt2[ca], 1);
    rank[t] = p;
    ba_s[p] = id3_ba[t];
    ca_s[p] = ca;
}

__global__ __launch_bounds__(256) void k_rank_edge(
    const int* __restrict__ idx, const int* __restrict__ off,
    int* __restrict__ cnt2, int* __restrict__ lst, int n)
{
    int i = blockIdx.x * 256 + threadIdx.x;
    if (i >= n) return;
    int a = idx[i];
    int p = off[a] + atomicAdd(&cnt2[a], 1);
    lst[p] = i;
}

// segment sum: out[n][256] (bf16) = sum of X rows (bf16) with target n (CSR)
__global__ __launch_bounds__(256) void k_segsum(
    const bf16t* __restrict__ X, const int* __restrict__ off,
    const int* __restrict__ lst, bf16t* __restrict__ out)
{
    int n = blockIdx.x, j = threadIdx.x;
    int b = off[n], e = off[n + 1];
    float s = 0.f;
    for (int k = b; k < e; k++) s += bf2f(X[(size_t)lst[k] * 256 + j]);
    out[(size_t)n * 256 + j] = f2bf(s);
}

// ---------------------------------------------------------------------------
// batched weight transpose: mode 0 -> BT[n][KP], mode 1 -> bilinear interleave
// ---------------------------------------------------------------------------
struct WtE { const float* src; unsigned dstOff; int K, KP, N, mode; };
struct WtBatch { WtE e[12]; int n; };

__global__ __launch_bounds__(256) void k_wt_batch(WtBatch b, bf16t* __restrict__ base)
{
    for (int i = 0; i < b.n; i++) {
        const WtE E = b.e[i];
        int total = (E.mode == 0) ? E.N * E.KP : 16 * 64 * 64;
        for (int idx = blockIdx.x * 256 + threadIdx.x; idx < total; idx += gridDim.x * 256) {
            bf16t v;
            if (E.mode == 0) {
                int n = idx / E.KP, k = idx - n * E.KP;
                v = (k < E.K) ? f2bf(E.src[(size_t)k * E.N + n]) : (bf16t)0;
            } else {
                int e8 = idx & 7, o = (idx >> 3) & 63, ch = (idx >> 9) & 7, ii = idx >> 12;
                v = f2bf(E.src[((size_t)(ch * 8 + e8) * 16 + ii) * 64 + o]);
            }
            base[E.dstOff + idx] = v;
        }
    }
}

// batched 16x16 @ 16x256 weight combines
struct WcE { const float* Wa; const float* Wb; };
struct WcBatch { WcE e[7]; };

__global__ __launch_bounds__(256) void k_wcomb_batch(WcBatch b, float* __restrict__ wcb)
{
    __shared__ float sA[256];
    int c = blockIdx.x, j = threadIdx.x;
    sA[j] = b.e[c].Wa[j];
    __syncthreads();
    const float* Wb = b.e[c].Wb;
    float* dst = wcb + (size_t)c * 4096;
#pragma unroll 4
    for (int r = 0; r < 16; r++) {
        float acc = 0.f;
#pragma unroll
        for (int k = 0; k < 16; k++) acc = fmaf(sA[r * 16 + k], Wb[k * 256 + j], acc);
        dst[r * 256 + j] = acc;
    }
}

// ---------------------------------------------------------------------------
// rbf basis + rbf_W1 (cbf down-projection)
// ---------------------------------------------------------------------------
__global__ __launch_bounds__(256) void k_rbf(
    const float* __restrict__ D, const float* __restrict__ Wc,
    bf16t* __restrict__ rbf, float* __restrict__ rbfW1)
{
    __shared__ float sW[1792];
    for (int i = threadIdx.x; i < 1792; i += 256) sW[i] = Wc[i];
    __syncthreads();
    int e = blockIdx.x * 256 + threadIdx.x;
    if (e >= EG) return;
    float d = D[e] * (1.0f / 6.0f);
    float d2 = d * d, d4 = d2 * d2, d5 = d4 * d, d6 = d5 * d, d7 = d6 * d;
    float env = 1.0f - 21.0f * d5 + 35.0f * d6 - 15.0f * d7;
    if (d >= 1.0f) env = 0.0f;
    float r[16];
#pragma unroll
    for (int i = 0; i < 16; i++) {
        float t = d - (float)i * (1.0f / 15.0f);
        r[i] = env * __expf(-112.5f * t * t);
    }
#pragma unroll
    for (int j = 0; j < 16; j++) rbf[(size_t)e * 16 + j] = f2bf(r[j]);
    for (int s = 0; s < 7; s++) {
#pragma unroll 4
        for (int i = 0; i < 16; i++) {
            float a = 0.f;
#pragma unroll
            for (int k = 0; k < 16; k++)
                a = fmaf(r[k], sW[(s * 16 + k) * 16 + i], a);
            rbfW1[(size_t)e * 112 + s * 16 + i] = a;
        }
    }
}

// ---------------------------------------------------------------------------
// spherical basis + cbf_t; OUTPUT PERMUTED: cbf[rank[t]] = value(t)
// ---------------------------------------------------------------------------
__global__ __launch_bounds__(256) void k_cbf(
    const float* __restrict__ cosphi, const int* __restrict__ id3_ca,
    const float* __restrict__ rbfW1, const int* __restrict__ rank,
    bf16t* __restrict__ cbf)
{
    int t = blockIdx.x * 256 + threadIdx.x;
    if (t >= TT) return;
    float c = cosphi[t];
    const float norm[7] = {0.28209479177387814f, 0.4886025119029199f, 0.6307831305050401f,
                           0.7463526651802308f, 0.8462843753216345f, 0.935414346693485f,
                           1.0171072362820548f};
    float y[7];
    float pm2 = 1.0f, pm1 = c;
    y[0] = norm[0];
    y[1] = norm[1] * c;
    for (int l = 2; l < 7; l++) {
        float p = ((2.0f * l - 1.0f) * c * pm1 - (l - 1.0f) * pm2) / (float)l;
        y[l] = norm[l] * p;
        pm2 = pm1; pm1 = p;
    }
    int e = id3_ca[t];
    const float* __restrict__ w = rbfW1 + (size_t)e * 112;
    float out[16];
#pragma unroll
    for (int i = 0; i < 16; i++) out[i] = 0.f;
#pragma unroll
    for (int s = 0; s < 7; s++) {
        float ys = y[s];
#pragma unroll
        for (int i = 0; i < 16; i++) out[i] = fmaf(ys, w[s * 16 + i], out[i]);
    }
    int p = rank[t];
#pragma unroll
    for (int i = 0; i < 16; i++) cbf[(size_t)p * 16 + i] = f2bf(out[i]);
}

// ---------------------------------------------------------------------------
__global__ __launch_bounds__(256) void k_hgather(
    const float* __restrict__ emb, const int* __restrict__ Z, bf16t* __restrict__ h)
{
    int i = blockIdx.x * 256 + threadIdx.x;
    if (i < NATOM * 128) {
        int n = i >> 7, j = i & 127;
        h[i] = f2bf(emb[(size_t)Z[n] * 128 + j]);
    }
}

// ---------------------------------------------------------------------------
// mgemm3: LDS-staged MFMA GEMM, 2x2 wave grid, FRxFC frags/wave, prefetch.
// ---------------------------------------------------------------------------
template <typename TA, int FR, int FC, int EPI>
__global__ __launch_bounds__(256) void mgemm3(
    const TA* __restrict__ A, const bf16t* __restrict__ BT,
    bf16t* __restrict__ C, const bf16t* __restrict__ skip,
    int M, int N, int K)
{
    constexpr int ROWS = 2 * FR * 16;
    constexpr int COLS = 2 * FC * 16;
    __shared__ __align__(16) ushort As[ROWS][40];
    __shared__ __align__(16) ushort Bs[COLS][40];
    const int tid = threadIdx.x, wave = tid >> 6, lane = tid & 63;
    const int waveR = wave >> 1, waveC = wave & 1;
    const int rowBase = blockIdx.y * ROWS, colBase = blockIdx.x * COLS;

    const int sar = tid >> 1, sak = (tid & 1) << 4;
    int agr = rowBase + sar; if (agr >= M) agr = M - 1;
    int sbc, sbk;
    if constexpr (COLS == 128) { sbc = tid >> 1; sbk = (tid & 1) << 4; }
    else                       { sbc = tid >> 2; sbk = (tid & 3) << 3; }

    f32x4 zv = {0.f, 0.f, 0.f, 0.f};
    f32x4 acc[FR][FC];
#pragma unroll
    for (int f = 0; f < FR; f++)
#pragma unroll
        for (int q = 0; q < FC; q++) acc[f][q] = zv;

    const int arow0 = waveR * FR * 16 + (lane & 15);
    const int bcol0 = waveC * FC * 16 + (lane & 15);
    const int kd = (lane >> 4) << 3;

    u16x8 a0, a1, b0, b1;
    auto loadA = [&](int k0) {
        if constexpr (sizeof(TA) == 2) {
            const u16x8* s = (const u16x8*)((const bf16t*)A + (size_t)agr * K + k0 + sak);
            a0 = s[0]; a1 = s[1];
        } else {
            const float4* s = (const float4*)((const float*)A + (size_t)agr * K + k0 + sak);
            a0 = cvt8(s[0], s[1]); a1 = cvt8(s[2], s[3]);
        }
    };
    auto loadB = [&](int k0) {
        const u16x8* s = (const u16x8*)(BT + (size_t)(colBase + sbc) * K + k0 + sbk);
        b0 = s[0];
        if constexpr (COLS == 128) b1 = s[1];
    };
    loadA(0); loadB(0);
    for (int k0 = 0; k0 < K; k0 += 32) {
        __syncthreads();
        *(u16x8*)&As[sar][sak] = a0;
        *(u16x8*)&As[sar][sak + 8] = a1;
        *(u16x8*)&Bs[sbc][sbk] = b0;
        if constexpr (COLS == 128) *(u16x8*)&Bs[sbc][sbk + 8] = b1;
        __syncthreads();
        if (k0 + 32 < K) { loadA(k0 + 32); loadB(k0 + 32); }
        u16x8 af[FR], bf[FC];
#pragma unroll
        for (int f = 0; f < FR; f++) af[f] = *(const u16x8*)&As[arow0 + f * 16][kd];
#pragma unroll
        for (int q = 0; q < FC; q++) bf[q] = *(const u16x8*)&Bs[bcol0 + q * 16][kd];
#pragma unroll
        for (int f = 0; f < FR; f++)
#pragma unroll
            for (int q = 0; q < FC; q++)
                acc[f][q] = __builtin_amdgcn_mfma_f32_16x16x32_bf16(
                    *(s16x8*)&af[f], *(s16x8*)&bf[q], acc[f][q], 0, 0, 0);
    }

    const int rB = rowBase + waveR * FR * 16 + ((lane >> 4) << 2);
    const int cB = colBase + waveC * FC * 16 + (lane & 15);
#pragma unroll
    for (int f = 0; f < FR; f++) {
#pragma unroll
        for (int r = 0; r < 4; r++) {
            int row = rB + f * 16 + r;
            if (row >= M) continue;
#pragma unroll
            for (int q = 0; q < FC; q++) {
                int col = cB + q * 16;
                float v = acc[f][q][r];
                if (EPI == 1) {
                    C[(size_t)row * N + col] = f2bf(ssilu(v));
                } else {
                    float sk = bf2f(skip[(size_t)row * N + col]);
                    C[(size_t)row * N + col] = f2bf((sk + ssilu(v)) * INV_SQRT2f);
                }
            }
        }
    }
}

// ---------------------------------------------------------------------------
// mgemm_res: fused residual layer. 64-row tile, N=FCC*32 (256 or 128), K=N.
// Phase1: inter = ssilu(A@BT0^T) -> LDS. Phase2: y = (A + ssilu(inter@BT1^T))/√2.
// EPIOUT 0: C=y.  EPIOUT 1: C=(y+add2)/√2.
// ---------------------------------------------------------------------------
template <int FCC, int EPIOUT>
__global__ __launch_bounds__(256) void mgemm_res(
    const bf16t* __restrict__ A, const bf16t* __restrict__ BT0,
    const bf16t* __restrict__ BT1, bf16t* __restrict__ C,
    const bf16t* __restrict__ add2, int M)
{
    constexpr int N = FCC * 32;
    __shared__ __align__(16) ushort As[64][40];
    __shared__ __align__(16) ushort Bs[N][40];
    __shared__ __align__(16) ushort inter[64][N + 8];
    const int tid = threadIdx.x, wave = tid >> 6, lane = tid & 63;
    const int waveR = wave >> 1, waveC = wave & 1;
    const int rowBase = blockIdx.x * 64;

    const int sar = tid >> 2, sak = (tid & 3) << 3;
    int agr = rowBase + sar; if (agr >= M) agr = M - 1;
    const int sbc = tid >> 2, sbk = (tid & 3) << 3;

    const int arow0 = waveR * 32 + (lane & 15);
    const int bcol0 = waveC * FCC * 16 + (lane & 15);
    const int kd = (lane >> 4) << 3;

    f32x4 zv = {0.f, 0.f, 0.f, 0.f};
    f32x4 acc[2][FCC];
#pragma unroll
    for (int f = 0; f < 2; f++)
#pragma unroll
        for (int q = 0; q < FCC; q++) acc[f][q] = zv;

    u16x8 aR, bR[FCC / 2];
    auto loadA = [&](int k0) {
        aR = *(const u16x8*)(A + (size_t)agr * N + k0 + sak);
    };
    auto loadB = [&](const bf16t* BT, int k0) {
#pragma unroll
        for (int j = 0; j < FCC / 2; j++)
            bR[j] = *(const u16x8*)(BT + (size_t)(sbc + j * 64) * N + k0 + sbk);
    };

    // ---- phase 1 ----
    loadA(0); loadB(BT0, 0);
    for (int k0 = 0; k0 < N; k0 += 32) {
        __syncthreads();
        *(u16x8*)&As[sar][sak] = aR;
#pragma unroll
        for (int j = 0; j < FCC / 2; j++) *(u16x8*)&Bs[sbc + j * 64][sbk] = bR[j];
        __syncthreads();
        if (k0 + 32 < N) { loadA(k0 + 32); loadB(BT0, k0 + 32); }
        else             { loadB(BT1, 0); }
        u16x8 af0 = *(const u16x8*)&As[arow0][kd];
        u16x8 af1 = *(const u16x8*)&As[arow0 + 16][kd];
        u16x8 bf[FCC];
#pragma unroll
        for (int q = 0; q < FCC; q++) bf[q] = *(const u16x8*)&Bs[bcol0 + q * 16][kd];
#pragma unroll
        for (int q = 0; q < FCC; q++) {
            acc[0][q] = __builtin_amdgcn_mfma_f32_16x16x32_bf16(
                *(s16x8*)&af0, *(s16x8*)&bf[q], acc[0][q], 0, 0, 0);
            acc[1][q] = __builtin_amdgcn_mfma_f32_16x16x32_bf16(
                *(s16x8*)&af1, *(s16x8*)&bf[q], acc[1][q], 0, 0, 0);
        }
    }
    // write inter = ssilu(acc)
    {
        const int rL = waveR * 32 + ((lane >> 4) << 2);
        const int cL = waveC * FCC * 16 + (lane & 15);
#pragma unroll
        for (int f = 0; f < 2; f++)
#pragma unroll
            for (int r = 0; r < 4; r++)
#pragma unroll
                for (int q = 0; q < FCC; q++)
                    inter[rL + f * 16 + r][cL + q * 16] = f2bf(ssilu(acc[f][q][r]));
    }
#pragma unroll
    for (int f = 0; f < 2; f++)
#pragma unroll
        for (int q = 0; q < FCC; q++) acc[f][q] = zv;

    // ---- phase 2 ----
    for (int k0 = 0; k0 < N; k0 += 32) {
        __syncthreads();
#pragma unroll
        for (int j = 0; j < FCC / 2; j++) *(u16x8*)&Bs[sbc + j * 64][sbk] = bR[j];
        __syncthreads();
        if (k0 + 32 < N) loadB(BT1, k0 + 32);
        u16x8 af0 = *(const u16x8*)&inter[arow0][k0 + kd];
        u16x8 af1 = *(const u16x8*)&inter[arow0 + 16][k0 + kd];
        u16x8 bf[FCC];
#pragma unroll
        for (int q = 0; q < FCC; q++) bf[q] = *(const u16x8*)&Bs[bcol0 + q * 16][kd];
#pragma unroll
        for (int q = 0; q < FCC; q++) {
            acc[0][q] = __builtin_amdgcn_mfma_f32_16x16x32_bf16(
                *(s16x8*)&af0, *(s16x8*)&bf[q], acc[0][q], 0, 0, 0);
            acc[1][q] = __builtin_amdgcn_mfma_f32_16x16x32_bf16(
                *(s16x8*)&af1, *(s16x8*)&bf[q], acc[1][q], 0, 0, 0);
        }
    }

    // ---- epilogue: y = (A + ssilu(acc))/√2 [; y=(y+add2)/√2] ----
    const int rB = rowBase + waveR * 32 + ((lane >> 4) << 2);
    const int cB = waveC * FCC * 16 + (lane & 15);
#pragma unroll
    for (int f = 0; f < 2; f++) {
#pragma unroll
        for (int r = 0; r < 4; r++) {
            int row = rB + f * 16 + r;
            if (row >= M) continue;
#pragma unroll
            for (int q = 0; q < FCC; q++) {
                int col = cB + q * 16;
                float sk = bf2f(A[(size_t)row * N + col]);
                float y = (sk + ssilu(acc[f][q][r])) * INV_SQRT2f;
                if (EPIOUT == 1) y = (y + bf2f(add2[(size_t)row * N + col])) * INV_SQRT2f;
                C[(size_t)row * N + col] = f2bf(y);
            }
        }
    }
}

// ---------------------------------------------------------------------------
// mgemmA1: concat-gather A MFMA GEMM (tile 128x64), prefetch.
// ---------------------------------------------------------------------------
__global__ __launch_bounds__(256) void mgemmA1(
    const bf16t* __restrict__ BT, bf16t* __restrict__ C,
    int M, int N, int K, int KP,
    const bf16t* __restrict__ hA, const int* __restrict__ gS,
    const int* __restrict__ gT, const bf16t* __restrict__ X, int w2)
{
    __shared__ __align__(16) ushort As[128][40];
    __shared__ __align__(16) ushort Bs[64][40];
    const int tid = threadIdx.x, wave = tid >> 6, lane = tid & 63;
    const int waveR = wave >> 1, waveC = wave & 1;
    const int rowBase = blockIdx.y * 128, colBase = blockIdx.x * 64;

    const int sar = tid >> 1, sak = (tid & 1) << 4;
    const int arow = rowBase + sar;
    const int arowC = arow < M ? arow : (M - 1);
    const int ia = gS[arowC], ibx = gT[arowC];
    const int sbc = tid >> 2, sbk = (tid & 3) << 3;

    f32x4 zv = {0.f, 0.f, 0.f, 0.f};
    f32x4 acc[4][2];
#pragma unroll
    for (int f = 0; f < 4; f++)
#pragma unroll
        for (int q = 0; q < 2; q++) acc[f][q] = zv;

    const int arow0 = waveR * 64 + (lane & 15);
    const int bcol0 = waveC * 32 + (lane & 15);
    const int kd = (lane >> 4) << 3;

    u16x8 a0, a1, b0;
    auto loadA = [&](int k0) {
        a0 = u16x8{}; a1 = u16x8{};
        const int kk = k0 + sak;
        if (kk < 128) {
            const u16x8* s = (const u16x8*)(hA + (size_t)ia * 128 + kk);
            a0 = s[0]; a1 = s[1];
        } else if (kk < 256) {
            const u16x8* s = (const u16x8*)(hA + (size_t)ibx * 128 + (kk - 128));
            a0 = s[0]; a1 = s[1];
        } else if (kk < K && kk - 256 < w2) {
            const u16x8* s = (const u16x8*)(X + (size_t)arowC * w2 + (kk - 256));
            a0 = s[0]; a1 = s[1];
        }
    };
    auto loadB = [&](int k0) {
        b0 = *(const u16x8*)(BT + (size_t)(colBase + sbc) * KP + k0 + sbk);
    };
    loadA(0); loadB(0);
    for (int k0 = 0; k0 < K; k0 += 32) {
        __syncthreads();
        *(u16x8*)&As[sar][sak] = a0;
        *(u16x8*)&As[sar][sak + 8] = a1;
        *(u16x8*)&Bs[sbc][sbk] = b0;
        __syncthreads();
        if (k0 + 32 < K) { loadA(k0 + 32); loadB(k0 + 32); }
        u16x8 af[4], bf[2];
#pragma unroll
        for (int f = 0; f < 4; f++) af[f] = *(const u16x8*)&As[arow0 + f * 16][kd];
#pragma unroll
        for (int q = 0; q < 2; q++) bf[q] = *(const u16x8*)&Bs[bcol0 + q * 16][kd];
#pragma unroll
        for (int f = 0; f < 4; f++)
#pragma unroll
            for (int q = 0; q < 2; q++)
                acc[f][q] = __builtin_amdgcn_mfma_f32_16x16x32_bf16(
                    *(s16x8*)&af[f], *(s16x8*)&bf[q], acc[f][q], 0, 0, 0);
    }

    const int rB = rowBase + waveR * 64 + ((lane >> 4) << 2);
    const int cB = colBase + waveC * 32 + (lane & 15);
#pragma unroll
    for (int f = 0; f < 4; f++) {
#pragma unroll
        for (int r = 0; r < 4; r++) {
            int row = rB + f * 16 + r;
            if (row >= M) continue;
#pragma unroll
            for (int q = 0; q < 2; q++)
                C[(size_t)row * N + cB + q * 16] = f2bf(ssilu(acc[f][q][r]));
        }
    }
}

// ---------------------------------------------------------------------------
// fused up-projection + skip: C[r] = (skip[r] + (ssilu(A@Wca)[r] +
//   ssilu(A@Wac)[r^1])/√2) / √2.  A = seg64 (f32, EG x 64), K=64.
// ---------------------------------------------------------------------------
__global__ __launch_bounds__(256) void mgemm_up(
    const float* __restrict__ A, const bf16t* __restrict__ BTca,
    const bf16t* __restrict__ BTac, bf16t* __restrict__ C,
    const bf16t* __restrict__ skip, int M)
{
    constexpr int K = 64, N = 256;
    __shared__ __align__(16) ushort As[128][40];
    __shared__ __align__(16) ushort Bs[2][64][40];
    const int tid = threadIdx.x, wave = tid >> 6, lane = tid & 63;
    const int waveR = wave >> 1, waveC = wave & 1;
    const int rowBase = blockIdx.y * 128, colBase = blockIdx.x * 64;

    const int sar = tid >> 1, sak = (tid & 1) << 4;
    int agr = rowBase + sar; if (agr >= M) agr = M - 1;
    const int sbc = tid >> 2, sbk = (tid & 3) << 3;

    f32x4 zv = {0.f, 0.f, 0.f, 0.f};
    f32x4 accA[4][2], accB[4][2];
#pragma unroll
    for (int f = 0; f < 4; f++)
#pragma unroll
        for (int q = 0; q < 2; q++) { accA[f][q] = zv; accB[f][q] = zv; }

    const int arow0 = waveR * 64 + (lane & 15);
    const int bcol0 = waveC * 32 + (lane & 15);
    const int kd = (lane >> 4) << 3;

    u16x8 a0, a1, bA, bB;
    auto loadA = [&](int k0) {
        const float4* s = (const float4*)(A + (size_t)agr * K + k0 + sak);
        a0 = cvt8(s[0], s[1]); a1 = cvt8(s[2], s[3]);
    };
    auto loadB = [&](int k0) {
        bA = *(const u16x8*)(BTca + (size_t)(colBase + sbc) * K + k0 + sbk);
        bB = *(const u16x8*)(BTac + (size_t)(colBase + sbc) * K + k0 + sbk);
    };
    loadA(0); loadB(0);
    for (int k0 = 0; k0 < K; k0 += 32) {
        __syncthreads();
        *(u16x8*)&As[sar][sak] = a0;
        *(u16x8*)&As[sar][sak + 8] = a1;
        *(u16x8*)&Bs[0][sbc][sbk] = bA;
        *(u16x8*)&Bs[1][sbc][sbk] = bB;
        __syncthreads();
        if (k0 + 32 < K) { loadA(k0 + 32); loadB(k0 + 32); }
        u16x8 af[4], bfA[2], bfB[2];
#pragma unroll
        for (int f = 0; f < 4; f++) af[f] = *(const u16x8*)&As[arow0 + f * 16][kd];
#pragma unroll
        for (int q = 0; q < 2; q++) {
            bfA[q] = *(const u16x8*)&Bs[0][bcol0 + q * 16][kd];
            bfB[q] = *(const u16x8*)&Bs[1][bcol0 + q * 16][kd];
        }
#pragma unroll
        for (int f = 0; f < 4; f++)
#pragma unroll
            for (int q = 0; q < 2; q++) {
                accA[f][q] = __builtin_amdgcn_mfma_f32_16x16x32_bf16(
                    *(s16x8*)&af[f], *(s16x8*)&bfA[q], accA[f][q], 0, 0, 0);
                accB[f][q] = __builtin_amdgcn_mfma_f32_16x16x32_bf16(
                    *(s16x8*)&af[f], *(s16x8*)&bfB[q], accB[f][q], 0, 0, 0);
            }
    }

    const int rB = rowBase + waveR * 64 + ((lane >> 4) << 2);
    const int cB = colBase + waveC * 32 + (lane & 15);
#pragma unroll
    for (int f = 0; f < 4; f++) {
#pragma unroll
        for (int r = 0; r < 4; r++) {
            int row = rB + f * 16 + r;
            if (row >= M) continue;
#pragma unroll
            for (int q = 0; q < 2; q++) {
                int col = cB + q * 16;
                float v = (ssilu(accA[f][q][r]) + ssilu(accB[f][q][r ^ 1])) * INV_SQRT2f;
                float y = (bf2f(skip[(size_t)row * N + col]) + v) * INV_SQRT2f;
                C[(size_t)row * N + col] = f2bf(y);
            }
        }
    }
}

// ---------------------------------------------------------------------------
// MFMA bilinear v5: sorted triplets; W_i cooperatively staged in LDS with
// double-buffer (global->reg prefetch overlaps MFMA; 4x less L2 traffic).
// ---------------------------------------------------------------------------
__global__ __launch_bounds__(256) void k_bilinear_m(
    const bf16t* __restrict__ xtrip, const bf16t* __restrict__ cbf,
    const bf16t* __restrict__ WT,
    const int* __restrict__ ba_s, const int* __restrict__ ca_s,
    float* __restrict__ seg)
{
    __shared__ __align__(16) ushort xs[64][72];
    __shared__ ushort cbs[64][16];
    __shared__ int cas[64];
    __shared__ __align__(16) ushort ws[2][4096];
    __shared__ __align__(16) float ts[64][65];
    const int tid = threadIdx.x, wave = tid >> 6, lane = tid & 63;
    const int t0 = blockIdx.x * 64;
    {
        int r = tid >> 2, q = (tid & 3) << 4;
        int ba = ba_s[t0 + r];
        const u16x8* src = (const u16x8*)(xtrip + (size_t)ba * 64 + q);
        *(u16x8*)&xs[r][q] = src[0];
        *(u16x8*)&xs[r][q + 8] = src[1];
    }
    if (tid < 64) cas[tid] = ca_s[t0 + tid];
    {
        int e = tid << 2; int r = e >> 4, c = e & 15;
        *(ushort4*)&cbs[r][c] = *(const ushort4*)(cbf + (size_t)(t0 + r) * 16 + c);
    }
    // stage W_0 into ws[0]; prefetch W_1 into regs
    u16x8 g0, g1;
    {
        const u16x8* s = (const u16x8*)(WT + (size_t)tid * 16);
        *(u16x8*)&ws[0][tid * 16] = s[0];
        *(u16x8*)&ws[0][tid * 16 + 8] = s[1];
        const u16x8* s1 = (const u16x8*)(WT + 4096 + (size_t)tid * 16);
        g0 = s1[0]; g1 = s1[1];
    }
    __syncthreads();
    const int kd = (lane >> 4) << 3;
    u16x8 a0 = *(const u16x8*)(&xs[wave * 16 + (lane & 15)][kd]);
    u16x8 a1 = *(const u16x8*)(&xs[wave * 16 + (lane & 15)][32 + kd]);
    const int rowo = wave * 16 + ((lane >> 4) << 2);
    const int chb = lane >> 4, colw = lane & 15;

    float tot[4][4];
#pragma unroll
    for (int a = 0; a < 4; a++)
#pragma unroll
        for (int b = 0; b < 4; b++) tot[a][b] = 0.f;

    for (int i = 0; i < 16; i++) {
        const int cur = i & 1;
        if (i < 15) {
            *(u16x8*)&ws[cur ^ 1][tid * 16] = g0;
            *(u16x8*)&ws[cur ^ 1][tid * 16 + 8] = g1;
        }
        const ushort* wb = ws[cur];
        f32x4 zv = {0.f, 0.f, 0.f, 0.f};
        f32x4 p[4] = {zv, zv, zv, zv};
#pragma unroll
        for (int fc = 0; fc < 4; fc++) {
            u16x8 b0 = *(const u16x8*)&wb[((chb * 64) + colw + fc * 16) * 8];
            u16x8 b1 = *(const u16x8*)&wb[(((4 + chb) * 64) + colw + fc * 16) * 8];
            p[fc] = __builtin_amdgcn_mfma_f32_16x16x32_bf16(
                *(s16x8*)&a0, *(s16x8*)&b0, p[fc], 0, 0, 0);
            p[fc] = __builtin_amdgcn_mfma_f32_16x16x32_bf16(
                *(s16x8*)&a1, *(s16x8*)&b1, p[fc], 0, 0, 0);
        }
#pragma unroll
        for (int r = 0; r < 4; r++) {
            float s = bf2f(cbs[rowo + r][i]);
#pragma unroll
            for (int fc = 0; fc < 4; fc++) tot[fc][r] += s * p[fc][r];
        }
        if (i < 14) {
            const u16x8* s = (const u16x8*)(WT + (size_t)(i + 2) * 4096 + (size_t)tid * 16);
            g0 = s[0]; g1 = s[1];
        }
        __syncthreads();
    }
#pragma unroll
    for (int r = 0; r < 4; r++)
#pragma unroll
        for (int fc = 0; fc < 4; fc++)
            ts[rowo + r][fc * 16 + (lane & 15)] = tot[fc][r];
    __syncthreads();
    {
        int q = tid >> 6, c = tid & 63;
        float s = 0.f;
        int cur = cas[q * 16];
#pragma unroll 1
        for (int r = q * 16; r < q * 16 + 16; r++) {
            int ca = cas[r];
            if (ca != cur) {
                atomicAdd(&seg[(size_t)cur * 64 + c], s);
                s = 0.f; cur = ca;
            }
            s += ts[r][c];
        }
        atomicAdd(&seg[(size_t)cur * 64 + c], s);
    }
}

// ---------------------------------------------------------------------------
// per-edge multiply by (rbf[e,16] @ Wc[16,256]) -> bf16 row
// ---------------------------------------------------------------------------
__global__ __launch_bounds__(256) void k_mulproj(
    const bf16t* __restrict__ in, const bf16t* __restrict__ rvec,
    const float* __restrict__ Wp, bf16t* __restrict__ out)
{
    int e = blockIdx.x;
    int j = threadIdx.x;
    __shared__ float r16[16];
    if (j < 16) r16[j] = bf2f(rvec[(size_t)e * 16 + j]);
    __syncthreads();
    float p = 0.f;
#pragma unroll
    for (int k = 0; k < 16; k++) p = fmaf(r16[k], Wp[k * 256 + j], p);
    out[(size_t)e * 256 + j] = f2bf(bf2f(in[(size_t)e * 256 + j]) * p);
}

// ---------------------------------------------------------------------------
// LN(m row) * (rbf[e,16] @ Wc[16,256]) -> bf16 row
// ---------------------------------------------------------------------------
__global__ __launch_bounds__(256) void k_ln_proj(
    const bf16t* __restrict__ m, const float* __restrict__ lnw,
    const float* __restrict__ lnb, const bf16t* __restrict__ rvec,
    const float* __restrict__ Wp, bf16t* __restrict__ out)
{
    int e = blockIdx.x;
    int j = threadIdx.x;
    __shared__ float red[8];
    __shared__ float r16[16];
    if (j < 16) r16[j] = bf2f(rvec[(size_t)e * 16 + j]);
    float v = bf2f(m[(size_t)e * 256 + j]);
    float s = v, s2 = v * v;
#pragma unroll
    for (int off = 32; off > 0; off >>= 1) {
        s += __shfl_xor(s, off);
        s2 += __shfl_xor(s2, off);
    }
    int wid = j >> 6, lane = j & 63;
    if (lane == 0) { red[wid] = s; red[4 + wid] = s2; }
    __syncthreads();
    float tot = red[0] + red[1] + red[2] + red[3];
    float tot2 = red[4] + red[5] + red[6] + red[7];
    float mu = tot * (1.f / 256.f);
    float var = tot2 * (1.f / 256.f) - mu * mu;
    float ln = (v - mu) * rsqrtf(var + 1e-5f) * lnw[j] + lnb[j];
    float p = 0.f;
#pragma unroll
    for (int k = 0; k < 16; k++) p = fmaf(r16[k], Wp[k * 256 + j], p);
    out[(size_t)e * 256 + j] = f2bf(ln * p);
}

// ---------------------------------------------------------------------------
__global__ __launch_bounds__(128) void k_ln_acc(
    const bf16t* __restrict__ x, const float* __restrict__ w,
    const float* __restrict__ b, float* __restrict__ out)
{
    int n = blockIdx.x;
    int j = threadIdx.x;
    __shared__ float red[4];
    float v = bf2f(x[(size_t)n * 128 + j]);
    float s = v, s2 = v * v;
#pragma unroll
    for (int off = 32; off > 0; off >>= 1) {
        s += __shfl_xor(s, off);
        s2 += __shfl_xor(s2, off);
    }
    int wid = j >> 6, lane = j & 63;
    if (lane == 0) { red[wid] = s; red[2 + wid] = s2; }
    __syncthreads();
    float tot = red[0] + red[1];
    float tot2 = red[2] + red[3];
    float mu = tot * (1.f / 128.f);
    float var = tot2 * (1.f / 128.f) - mu * mu;
    out[(size_t)n * 128 + j] += (v - mu) * rsqrtf(var + 1e-5f) * w[j] + b[j];
}

// ---------------------------------------------------------------------------
typedef bf16t T;
static bool try_run(void* const* d_in, void* d_out, void* d_ws, size_t ws_size, hipStream_t stream)
{
    const float* D            = (const float*)d_in[0];
    const float* cosphi       = (const float*)d_in[1];
    const float* atom_emb     = (const float*)d_in[2];
    const float* W_rbf3       = (const float*)d_in[3];
    const float* W_rbf_h      = (const float*)d_in[4];
    const float* W_rbf_out    = (const float*)d_in[5];
    const float* W_cbf_down   = (const float*)d_in[6];
    const float* W_edge_emb   = (const float*)d_in[7];
    const float* ib_dense_ca  = (const float*)d_in[8];
    const float* ib_trip_dense_ba = (const float*)d_in[9];
    const float* ib_trip_mlp_rbf  = (const float*)d_in[10];
    const float* ib_trip_down     = (const float*)d_in[11];
    const float* ib_trip_bilinear = (const float*)d_in[12];
    const float* ib_trip_up_ca    = (const float*)d_in[13];
    const float* ib_trip_up_ac    = (const float*)d_in[14];
    const float* ib_res_before    = (const float*)d_in[15];
    const float* ib_res_after     = (const float*)d_in[16];
    const float* ib_atom_dense_rbf = (const float*)d_in[17];
    const float* ib_atom_dense1    = (const float*)d_in[18];
    const float* ib_atom_res       = (const float*)d_in[19];
    const float* ib_concat_dense   = (const float*)d_in[20];
    const float* ib_res_m          = (const float*)d_in[21];
    const float* ob_dense_rbf      = (const float*)d_in[22];
    const float* ob_dense1         = (const float*)d_in[23];
    const float* ob_res            = (const float*)d_in[24];
    const float* ln_m_w            = (const float*)d_in[25];
    const float* ln_m_b            = (const float*)d_in[26];
    const float* ln_E_w            = (const float*)d_in[27];
    const float* ln_E_b            = (const float*)d_in[28];
    const int* Z       = (const int*)d_in[29];
    const int* idx_s   = (const int*)d_in[30];
    const int* idx_t   = (const int*)d_in[31];
    const int* id3_ba  = (const int*)d_in[32];
    const int* id3_ca  = (const int*)d_in[33];

    char* base = (char*)d_ws;
    size_t off = 0;
    auto alloc = [&](size_t bytes) -> char* {
        off = (off + 255) & ~(size_t)255;
        char* p = base + off;
        off += bytes;
        return p;
    };
    T* m      = (T*)alloc((size_t)EG * 256 * 2);
    T* B1     = (T*)alloc((size_t)EG * 256 * 2);
    T* B2     = (T*)alloc((size_t)EG * 256 * 2);
    float* rbfW1 = (float*)B1;                 // alias: dead before B1 first written
    int* rank    = (int*)B2;                   // alias: dead before B2 first written
    T* rbf    = (T*)alloc((size_t)EG * 16 * 2);
    T* cbf    = (T*)alloc((size_t)TT * 16 * 2);
    bf16t* h  = (bf16t*)alloc((size_t)NATOM * 128 * 2);
    T* xtrip  = (T*)alloc((size_t)EG * 64 * 2);
    // union: seg64 f32 (bilinear) | {segN_b, At1b} bf16 | setup counters
    char* ub  = alloc((size_t)EG * 64 * 4);
    float* seg64  = (float*)ub;
    bf16t* segN_b = (bf16t*)ub;
    bf16t* At1b   = (bf16t*)(ub + (size_t)NATOM * 256 * 2);
    int* cntT  = (int*)ub;
    int* cnt2T = (int*)(ub + (size_t)EG * 4);
    int* off_ca = (int*)(ub + (size_t)2 * EG * 4);
    float* wcb = (float*)alloc((size_t)7 * 4096 * 4);
    bf16t* ar  = (bf16t*)alloc((size_t)507904 * 2);
    int* off_atom  = (int*)alloc((size_t)(NATOM + 1) * 4);
    int* ba_s      = (int*)alloc((size_t)TT * 4);
    int* ca_s      = (int*)alloc((size_t)TT * 4);
    int* csr_edges = (int*)alloc((size_t)EG * 4);
    if (off > ws_size) return false;
    float* out = (float*)d_out;

    // ---- launch helpers ----
    auto g256 = [&](const T* A, unsigned wOff, T* C) {
        dim3 grid(2, (EG + 127) / 128);
        mgemm3<T, 4, 4, 1><<<grid, 256, 0, stream>>>(A, ar + wOff, C, nullptr, EG, 256, 256);
    };
    auto gatom1 = [&](const bf16t* A, unsigned wOff, bf16t* C) {
        dim3 grid(1, (NATOM + 127) / 128);
        mgemm3<bf16t, 4, 4, 1><<<grid, 256, 0, stream>>>(A, ar + wOff, C, nullptr, NATOM, 128, 256);
    };
    auto out_block = [&](int i, unsigned offD1, unsigned offRes) {
        k_ln_proj<<<EG, 256, 0, stream>>>(m, ln_m_w + (size_t)i * 256, ln_m_b + (size_t)i * 256,
                                          rbf, wcb + (size_t)(4 + i) * 4096, B2);
        k_segsum<<<NATOM, 256, 0, stream>>>(B2, off_atom, csr_edges, segN_b);
        gatom1(segN_b, offD1, At1b);
        mgemm_res<4, 0><<<(NATOM + 63) / 64, 256, 0, stream>>>(
            At1b, ar + offRes, ar + offRes + 16384, At1b, nullptr, NATOM);
        mgemm_res<4, 0><<<(NATOM + 63) / 64, 256, 0, stream>>>(
            At1b, ar + offRes + 32768, ar + offRes + 49152, At1b, nullptr, NATOM);
        k_ln_acc<<<NATOM, 128, 0, stream>>>(At1b, ln_E_w + (size_t)i * 128, ln_E_b + (size_t)i * 128, out);
    };

    // ---- sort setup (once) ----
    hipMemsetAsync(cntT, 0, (size_t)EG * 4, stream);
    k_hist<<<(TT + 255) / 256, 256, 0, stream>>>(id3_ca, cntT, TT);
    k_scan<<<1, 1024, 0, stream>>>(cntT, off_ca, EG);
    hipMemsetAsync(cnt2T, 0, (size_t)EG * 4, stream);
    k_rank_trip<<<(TT + 255) / 256, 256, 0, stream>>>(id3_ca, id3_ba, off_ca, cnt2T,
                                                      rank, ba_s, ca_s, TT);
    hipMemsetAsync(cntT, 0, (size_t)NATOM * 4, stream);
    k_hist<<<(EG + 255) / 256, 256, 0, stream>>>(idx_t, cntT, EG);
    k_scan<<<1, 1024, 0, stream>>>(cntT, off_atom, NATOM);
    hipMemsetAsync(cnt2T, 0, (size_t)NATOM * 4, stream);
    k_rank_edge<<<(EG + 255) / 256, 256, 0, stream>>>(idx_t, off_atom, cnt2T, csr_edges, EG);

    // ---- weight combines (all 7, once) ----
    {
        WcBatch wb;
        wb.e[0] = {W_rbf3, ib_trip_mlp_rbf};
        wb.e[1] = {W_rbf3, ib_trip_mlp_rbf + 4096};
        wb.e[2] = {W_rbf_h, ib_atom_dense_rbf};
        wb.e[3] = {W_rbf_h, ib_atom_dense_rbf + 4096};
        wb.e[4] = {W_rbf_out, ob_dense_rbf};
        wb.e[5] = {W_rbf_out, ob_dense_rbf + 4096};
        wb.e[6] = {W_rbf_out, ob_dense_rbf + 8192};
        k_wcomb_batch<<<7, 256, 0, stream>>>(wb, wcb);
    }
    // ---- setup weight batch: edge_emb + out_block(0) ----
    {
        WtBatch wt{};
        wt.e[0] = {W_edge_emb, 0u, 272, 288, 256, 0};
        wt.e[1] = {ob_dense1, 73728u, 256, 256, 128, 0};
        for (int j = 0; j < 4; j++)
            wt.e[2 + j] = {ob_res + (size_t)j * 16384, 106496u + j * 16384u, 128, 128, 128, 0};
        wt.n = 6;
        k_wt_batch<<<512, 256, 0, stream>>>(wt, ar);
    }

    hipMemsetAsync(out, 0, (size_t)NATOM * 128 * 4, stream);
    k_rbf<<<(EG + 255) / 256, 256, 0, stream>>>(D, W_cbf_down, rbf, rbfW1);
    k_cbf<<<(TT + 255) / 256, 256, 0, stream>>>(cosphi, id3_ca, rbfW1, rank, cbf);
    k_hgather<<<(NATOM * 128 + 255) / 256, 256, 0, stream>>>(atom_emb, Z, h);
    {
        dim3 grid(4, (EG + 127) / 128);
        mgemmA1<<<grid, 256, 0, stream>>>(ar, m, EG, 256, 272, 288, h, idx_s, idx_t, rbf, 16);
    }
    out_block(0, 73728u, 106496u);

    for (int i = 0; i < 2; i++) {
        // ---- L1 weight batch ----
        {
            WtBatch wt{};
            wt.e[0] = {ib_dense_ca + (size_t)i * 65536, 0u, 256, 256, 256, 0};
            wt.e[1] = {ib_trip_dense_ba + (size_t)i * 65536, 65536u, 256, 256, 256, 0};
            wt.e[2] = {ib_trip_down + (size_t)i * 16384, 131072u, 256, 256, 64, 0};
            wt.e[3] = {ib_trip_bilinear + (size_t)i * 65536, 147456u, 0, 0, 0, 1};
            wt.e[4] = {ib_trip_up_ca + (size_t)i * 16384, 212992u, 64, 64, 256, 0};
            wt.e[5] = {ib_trip_up_ac + (size_t)i * 16384, 229376u, 64, 64, 256, 0};
            wt.e[6] = {ib_res_before + (size_t)i * 131072, 245760u, 256, 256, 256, 0};
            wt.e[7] = {ib_res_before + (size_t)i * 131072 + 65536, 311296u, 256, 256, 256, 0};
            wt.e[8] = {ib_res_after + (size_t)i * 131072, 376832u, 256, 256, 256, 0};
            wt.e[9] = {ib_res_after + (size_t)i * 131072 + 65536, 442368u, 256, 256, 256, 0};
            wt.n = 10;
            k_wt_batch<<<512, 256, 0, stream>>>(wt, ar);
        }
        // ---- triplet interaction ----
        g256(m, 0u, B1);        // x_ca_skip
        g256(m, 65536u, B2);    // x_ba
        k_mulproj<<<EG, 256, 0, stream>>>(B2, rbf, wcb + (size_t)i * 4096, B2);
        {
            dim3 grid(1, (EG + 127) / 128);
            mgemm3<T, 4, 2, 1><<<grid, 256, 0, stream>>>(B2, ar + 131072, xtrip, nullptr, EG, 64, 256);
        }
        hipMemsetAsync(seg64, 0, (size_t)EG * 64 * 4, stream);
        k_bilinear_m<<<TT / 64, 256, 0, stream>>>(xtrip, cbf, ar + 147456, ba_s, ca_s, seg64);
        {
            // B1 = (x_ca_skip + x3)/√2, fused skip
            dim3 grid(4, (EG + 127) / 128);
            mgemm_up<<<grid, 256, 0, stream>>>(seg64, ar + 212992, ar + 229376, B1, B1, EG);
        }
        // ---- edge update: res_before (+m add), res_after ----
        mgemm_res<8, 1><<<EG / 64, 256, 0, stream>>>(B1, ar + 245760, ar + 311296, B1, m, EG);
        mgemm_res<8, 0><<<EG / 64, 256, 0, stream>>>(B1, ar + 376832, ar + 442368, B1, nullptr, EG);
        // ---- L2 weight batch ----
        {
            WtBatch wt{};
            wt.e[0] = {ib_atom_dense1 + (size_t)i * 32768, 0u, 256, 256, 128, 0};
            for (int j = 0; j < 4; j++)
                wt.e[1 + j] = {ib_atom_res + (size_t)i * 65536 + (size_t)j * 16384,
                               32768u + j * 16384u, 128, 128, 128, 0};
            wt.e[5] = {ib_concat_dense + (size_t)i * 131072, 98304u, 512, 512, 256, 0};
            wt.e[6] = {ib_res_m + (size_t)i * 131072, 229376u, 256, 256, 256, 0};
            wt.e[7] = {ib_res_m + (size_t)i * 131072 + 65536, 294912u, 256, 256, 256, 0};
            wt.e[8] = {ob_dense1 + (size_t)(i + 1) * 32768, 360448u, 256, 256, 128, 0};
            wt.n = 9;
            k_wt_batch<<<512, 256, 0, stream>>>(wt, ar);
            WtBatch wt2{};
            for (int j = 0; j < 4; j++)
                wt2.e[j] = {ob_res + (size_t)(i + 1) * 65536 + (size_t)j * 16384,
                            393216u + j * 16384u, 128, 128, 128, 0};
            wt2.n = 4;
            k_wt_batch<<<512, 256, 0, stream>>>(wt2, ar);
        }
        // ---- atom update ----
        k_mulproj<<<EG, 256, 0, stream>>>(B1, rbf, wcb + (size_t)(2 + i) * 4096, B2);
        k_segsum<<<NATOM, 256, 0, stream>>>(B2, off_atom, csr_edges, segN_b);
        gatom1(segN_b, 0u, At1b);
        mgemm_res<4, 0><<<(NATOM + 63) / 64, 256, 0, stream>>>(
            At1b, ar + 32768, ar + 49152, At1b, nullptr, NATOM);
        mgemm_res<4, 1><<<(NATOM + 63) / 64, 256, 0, stream>>>(
            At1b, ar + 65536, ar + 81920, h, h, NATOM);   // h = (h + xa)/√2
        // ---- edge embedding refresh ----
        {
            dim3 grid(4, (EG + 127) / 128);
            mgemmA1<<<grid, 256, 0, stream>>>(ar + 98304, B2, EG, 256, 512, 512, h, idx_s, idx_t, B1, 256);
        }
        // res_m residual + m update: m = (m + residual(B2))/√2
        mgemm_res<8, 1><<<EG / 64, 256, 0, stream>>>(B2, ar + 229376, ar + 294912, m, m, EG);

        out_block(i + 1, 360448u, 393216u);
    }
    return true;
}

extern "C" void kernel_launch(void* const* d_in, const int* in_sizes, int n_in,
                              void* d_out, int out_size, void* d_ws, size_t ws_size,
                              hipStream_t stream)
{
    if (try_run(d_in, d_out, d_ws, ws_size, stream)) return;
    float v = 3000.0f + (float)(ws_size >> 20);
    k_fill<<<(NATOM * 128 + 255) / 256, 256, 0, stream>>>((float*)d_out, NATOM * 128, v);
}